// Round 1
// baseline (1097.258 us; speedup 1.0000x reference)
//
#include <hip/hip_runtime.h>
#include <hip/hip_bf16.h>
#include <stdint.h>

typedef __attribute__((ext_vector_type(8))) short short8;
typedef __attribute__((ext_vector_type(4))) float floatx4;

__device__ __forceinline__ unsigned short f2b(float f) {
  unsigned u = __builtin_bit_cast(unsigned, f);
  unsigned r = u + 0x7fffu + ((u >> 16) & 1u);
  return (unsigned short)(r >> 16);
}
__device__ __forceinline__ float b2f(unsigned short h) {
  unsigned u = ((unsigned)h) << 16;
  return __builtin_bit_cast(float, u);
}

// ---------------------------------------------------------------------------
// Generic TN GEMM: C[M,N] = A[M,K] * B[N,K]^T, bf16 in, fp32 accum.
// 128x128 tile, 4 waves (2x2), BK=32, global_load_lds staging (linear LDS).
// M, N multiples of 128; K multiple of 32. Epilogue selected by EPI.
// ---------------------------------------------------------------------------
struct GemmP {
  const unsigned short* A;
  const unsigned short* B;
  long sAb, sBb;          // batch strides (elements)
  int lda, ldb, K;
  unsigned short* C; long sCb; int ldc;   // EPI 0: bf16 row-major store
  const float* bias;                      // EPI 2/3
  unsigned short *Q0, *K0, *V0t, *Q1, *K1, *V1t; // EPI 2/3 scatter targets
};

template<int EPI>
__global__ __launch_bounds__(256) void gemm_tn(GemmP p) {
  __shared__ __align__(16) unsigned short As[128 * 32];
  __shared__ __align__(16) unsigned short Bs[128 * 32];
  const int tid = threadIdx.x;
  const int w = tid >> 6, lane = tid & 63;
  const int wm = w >> 1, wn = w & 1;
  const int g = lane >> 4, l16 = lane & 15;
  const int bz = blockIdx.z;
  const int m0 = blockIdx.y * 128, n0 = blockIdx.x * 128;
  const unsigned short* Ab = p.A + (long)bz * p.sAb + (long)m0 * p.lda;
  const unsigned short* Bb = p.B + (long)bz * p.sBb + (long)n0 * p.ldb;
  const int srow = tid >> 2;
  const int sc8 = (tid & 3) * 8;

  floatx4 acc[4][4];
  const floatx4 z4 = {0.f, 0.f, 0.f, 0.f};
#pragma unroll
  for (int i = 0; i < 4; ++i)
#pragma unroll
    for (int j = 0; j < 4; ++j) acc[i][j] = z4;

  for (int k0 = 0; k0 < p.K; k0 += 32) {
    __syncthreads();
#pragma unroll
    for (int r = 0; r < 2; ++r) {
      const unsigned short* ga = Ab + (long)(r * 64 + srow) * p.lda + k0 + sc8;
      __builtin_amdgcn_global_load_lds(
          (const __attribute__((address_space(1))) void*)ga,
          (__attribute__((address_space(3))) void*)(As + (r * 4 + w) * 512), 16, 0, 0);
      const unsigned short* gb = Bb + (long)(r * 64 + srow) * p.ldb + k0 + sc8;
      __builtin_amdgcn_global_load_lds(
          (const __attribute__((address_space(1))) void*)gb,
          (__attribute__((address_space(3))) void*)(Bs + (r * 4 + w) * 512), 16, 0, 0);
    }
    __syncthreads();
    short8 af[4], bf[4];
#pragma unroll
    for (int mi = 0; mi < 4; ++mi)
      af[mi] = *(const short8*)(As + (wm * 64 + mi * 16 + l16) * 32 + g * 8);
#pragma unroll
    for (int ni = 0; ni < 4; ++ni)
      bf[ni] = *(const short8*)(Bs + (wn * 64 + ni * 16 + l16) * 32 + g * 8);
#pragma unroll
    for (int mi = 0; mi < 4; ++mi)
#pragma unroll
      for (int ni = 0; ni < 4; ++ni)
        acc[mi][ni] = __builtin_amdgcn_mfma_f32_16x16x32_bf16(af[mi], bf[ni], acc[mi][ni], 0, 0, 0);
  }

  if constexpr (EPI == 0) {
    unsigned short* C = p.C + (long)bz * p.sCb;
#pragma unroll
    for (int mi = 0; mi < 4; ++mi) {
#pragma unroll
      for (int ni = 0; ni < 4; ++ni) {
        const int col = n0 + wn * 64 + ni * 16 + l16;
#pragma unroll
        for (int r4 = 0; r4 < 4; ++r4) {
          const int row = m0 + wm * 64 + mi * 16 + g * 4 + r4;
          C[(long)row * p.ldc + col] = f2b(acc[mi][ni][r4]);
        }
      }
    }
  } else if constexpr (EPI == 2) {   // QKV lo scatter: co in [0,3072), pix in [0,1024)
    const int b = bz >> 2, t = bz & 3;
#pragma unroll
    for (int mi = 0; mi < 4; ++mi) {
#pragma unroll
      for (int r4 = 0; r4 < 4; ++r4) {
        const int co = m0 + wm * 64 + mi * 16 + g * 4 + r4;
        const int sel = co >> 10;
        const int ch = co & 1023;
        const float bv = p.bias[co];
#pragma unroll
        for (int ni = 0; ni < 4; ++ni) {
          const int pix = n0 + wn * 64 + ni * 16 + l16;
          const int y = pix >> 5, x = pix & 31;
          float v = acc[mi][ni][r4] + bv;
          if (ch < 512) {                       // cfg0: 4x4 patches, d=8192
            if (sel == 0) v *= 0.011048543456039806f;   // 1/sqrt(8192)
            const int nseq = (t * 8 + (y >> 2)) * 8 + (x >> 2);
            const int f = (ch * 4 + (y & 3)) * 4 + (x & 3);
            const unsigned short hv = f2b(v);
            if (sel == 0)      p.Q0[((long)(b * 512 + nseq)) * 8192 + f] = hv;
            else if (sel == 1) p.K0[((long)(b * 512 + nseq)) * 8192 + f] = hv;
            else               p.V0t[((long)(b * 8192 + f)) * 512 + nseq] = hv;
          } else {                              // cfg1: 2x2 patches, d=2048
            if (sel == 0) v *= 0.02209708691207961f;    // 1/sqrt(2048)
            const int c2 = ch - 512;
            const int nseq = (t * 16 + (y >> 1)) * 16 + (x >> 1);
            const int f = (c2 * 2 + (y & 1)) * 2 + (x & 1);
            const unsigned short hv = f2b(v);
            if (sel == 0)      p.Q1[((long)(b * 2048 + nseq)) * 2048 + f] = hv;
            else if (sel == 1) p.K1[((long)(b * 2048 + nseq)) * 2048 + f] = hv;
            else               p.V1t[((long)(b * 2048 + f)) * 2048 + nseq] = hv;
          }
        }
      }
    }
  } else if constexpr (EPI == 3) {   // QKV hi scatter: co in [0,768), pix in [0,4096)
    const int b = bz >> 2, t = bz & 3;
#pragma unroll
    for (int mi = 0; mi < 4; ++mi) {
#pragma unroll
      for (int r4 = 0; r4 < 4; ++r4) {
        const int co = m0 + wm * 64 + mi * 16 + g * 4 + r4;
        const int sel = co >> 8;
        const int ch = co & 255;
        const float bv = p.bias[co];
#pragma unroll
        for (int ni = 0; ni < 4; ++ni) {
          const int pix = n0 + wn * 64 + ni * 16 + l16;
          const int y = pix >> 6, x = pix & 63;
          float v = acc[mi][ni][r4] + bv;
          if (ch < 128) {                       // cfg0: 8x8 patches
            if (sel == 0) v *= 0.011048543456039806f;
            const int nseq = 256 + (t * 8 + (y >> 3)) * 8 + (x >> 3);
            const int f = (ch * 8 + (y & 7)) * 8 + (x & 7);
            const unsigned short hv = f2b(v);
            if (sel == 0)      p.Q0[((long)(b * 512 + nseq)) * 8192 + f] = hv;
            else if (sel == 1) p.K0[((long)(b * 512 + nseq)) * 8192 + f] = hv;
            else               p.V0t[((long)(b * 8192 + f)) * 512 + nseq] = hv;
          } else {                              // cfg1: 4x4 patches
            if (sel == 0) v *= 0.02209708691207961f;
            const int c2 = ch - 128;
            const int nseq = 1024 + (t * 16 + (y >> 2)) * 16 + (x >> 2);
            const int f = (c2 * 4 + (y & 3)) * 4 + (x & 3);
            const unsigned short hv = f2b(v);
            if (sel == 0)      p.Q1[((long)(b * 2048 + nseq)) * 2048 + f] = hv;
            else if (sel == 1) p.K1[((long)(b * 2048 + nseq)) * 2048 + f] = hv;
            else               p.V1t[((long)(b * 2048 + f)) * 2048 + nseq] = hv;
          }
        }
      }
    }
  }
}

// ---------------------------------------------------------------------------
// Row softmax in-place on bf16 rows of length L. One wave per row.
// ---------------------------------------------------------------------------
template<int L>
__global__ __launch_bounds__(256) void softmax_rows(unsigned short* S) {
  const int w = threadIdx.x >> 6, lane = threadIdx.x & 63;
  const long row = (long)blockIdx.x * 4 + w;
  unsigned short* R = S + row * L;
  constexpr int NC = L / 64;
  float v[NC];
  float m = -1e30f;
#pragma unroll
  for (int i = 0; i < NC; ++i) { v[i] = b2f(R[i * 64 + lane]); m = fmaxf(m, v[i]); }
#pragma unroll
  for (int off = 32; off; off >>= 1) m = fmaxf(m, __shfl_xor(m, off, 64));
  float s = 0.f;
#pragma unroll
  for (int i = 0; i < NC; ++i) { v[i] = __expf(v[i] - m); s += v[i]; }
#pragma unroll
  for (int off = 32; off; off >>= 1) s += __shfl_xor(s, off, 64);
  const float inv = 1.0f / s;
#pragma unroll
  for (int i = 0; i < NC; ++i) R[i * 64 + lane] = f2b(v[i] * inv);
}

// ---------------------------------------------------------------------------
// x [16][256][NPIX] fp32 (NCHW) -> xt [16][NPIX][256] bf16 (pixel-major)
// ---------------------------------------------------------------------------
__global__ __launch_bounds__(256) void xt_kernel(const float* __restrict__ x,
                                                 unsigned short* __restrict__ xt, int NPIX) {
  __shared__ unsigned short tile[64 * 65];
  const int tid = threadIdx.x;
  const int bt = blockIdx.z, ch0 = blockIdx.y * 64;
  const long pix0 = (long)blockIdx.x * 64;
  const float* src = x + ((long)bt * 256 + ch0) * NPIX + pix0;
#pragma unroll
  for (int i = 0; i < 16; ++i) {
    const int lin = i * 256 + tid;
    const int ch = lin >> 6, px = lin & 63;
    tile[ch * 65 + px] = f2b(src[(long)ch * NPIX + px]);
  }
  __syncthreads();
  unsigned short* dst = xt + ((long)bt * NPIX + pix0) * 256 + ch0;
#pragma unroll
  for (int i = 0; i < 16; ++i) {
    const int lin = i * 256 + tid;
    const int px = lin >> 6, ch = lin & 63;
    dst[(long)px * 256 + ch] = tile[ch * 65 + px];
  }
}

// ---------------------------------------------------------------------------
// Weight prep
// ---------------------------------------------------------------------------
__global__ void prep_qkv_w(const float* wq, const float* wk, const float* wv,
                           const float* bq, const float* bk, const float* bv,
                           unsigned short* Wcat, float* Bcat, int CO) {
  const int idx = blockIdx.x * 256 + threadIdx.x;
  const int n = 3 * CO * 256;
  if (idx < n) {
    const int sel = idx / (CO * 256);
    const int r = idx - sel * CO * 256;
    const float* wsel = sel == 0 ? wq : (sel == 1 ? wk : wv);
    Wcat[idx] = f2b(wsel[r]);
  }
  if (idx < 3 * CO) {
    const int sel = idx / CO;
    const int r = idx - sel * CO;
    const float* bsel = sel == 0 ? bq : (sel == 1 ? bk : bv);
    Bcat[idx] = bsel[r];
  }
}

__global__ void prep_conv_w(const float* wo, unsigned short* Wt, int CIN) {
  const int idx = blockIdx.x * 256 + threadIdx.x;
  const int n = 9 * 256 * CIN;
  if (idx < n) {
    const int t9 = idx / (256 * CIN);
    const int rem = idx - t9 * 256 * CIN;
    const int o = rem / CIN, i = rem - o * CIN;
    Wt[idx] = f2b(wo[((long)o * CIN + i) * 9 + t9]);   // [9][256][CIN]
  }
}

// ---------------------------------------------------------------------------
// Repack attention outputs Y (patch-major) -> NHWC conv inputs
// ---------------------------------------------------------------------------
__global__ __launch_bounds__(256) void repack_lo(const unsigned short* __restrict__ Y0,
                                                 const unsigned short* __restrict__ Y1,
                                                 unsigned short* __restrict__ out) {
  const int tid = threadIdx.x;
  const int blk = blockIdx.x;
  if (blk < 1024) {          // cfg0: 16px x 512ch per row
    const int b = blk >> 8, n = blk & 255;
    const int t = n >> 6, oh = (n >> 3) & 7, ow = n & 7;
    const unsigned short* row = Y0 + ((long)(b * 512 + n)) * 8192;
    const int bt = b * 4 + t;
#pragma unroll
    for (int j = 0; j < 32; ++j) {
      const int idx = j * 256 + tid;
      const int pp = idx >> 9, ch = idx & 511;
      const int py = pp >> 2, px = pp & 3;
      out[(((long)bt * 32 + oh * 4 + py) * 32 + ow * 4 + px) * 1024 + ch] = row[ch * 16 + pp];
    }
  } else {                   // cfg1: 4px x 512ch per row
    const int q = blk - 1024;
    const int b = q >> 10, n = q & 1023;
    const int t = n >> 8, oh = (n >> 4) & 15, ow = n & 15;
    const unsigned short* row = Y1 + ((long)(b * 2048 + n)) * 2048;
    const int bt = b * 4 + t;
#pragma unroll
    for (int j = 0; j < 8; ++j) {
      const int idx = j * 256 + tid;
      const int pp = idx >> 9, ch = idx & 511;
      const int py = pp >> 1, px = pp & 1;
      out[(((long)bt * 32 + oh * 2 + py) * 32 + ow * 2 + px) * 1024 + 512 + ch] = row[ch * 4 + pp];
    }
  }
}

__global__ __launch_bounds__(256) void repack_hi(const unsigned short* __restrict__ Y0,
                                                 const unsigned short* __restrict__ Y1,
                                                 unsigned short* __restrict__ out) {
  const int tid = threadIdx.x;
  const int blk = blockIdx.x;
  if (blk < 1024) {          // cfg0: 64px x 128ch per row
    const int b = blk >> 8, n = blk & 255;
    const int t = n >> 6, oh = (n >> 3) & 7, ow = n & 7;
    const unsigned short* row = Y0 + ((long)(b * 512 + 256 + n)) * 8192;
    const int bt = b * 4 + t;
#pragma unroll
    for (int j = 0; j < 32; ++j) {
      const int idx = j * 256 + tid;
      const int pp = idx >> 7, ch = idx & 127;
      const int py = pp >> 3, px = pp & 7;
      out[(((long)bt * 64 + oh * 8 + py) * 64 + ow * 8 + px) * 256 + ch] = row[ch * 64 + pp];
    }
  } else {                   // cfg1: 16px x 128ch per row
    const int q = blk - 1024;
    const int b = q >> 10, n = q & 1023;
    const int t = n >> 8, oh = (n >> 4) & 15, ow = n & 15;
    const unsigned short* row = Y1 + ((long)(b * 2048 + 1024 + n)) * 2048;
    const int bt = b * 4 + t;
#pragma unroll
    for (int j = 0; j < 8; ++j) {
      const int idx = j * 256 + tid;
      const int pp = idx >> 7, ch = idx & 127;
      const int py = pp >> 2, px = pp & 3;
      out[(((long)bt * 64 + oh * 4 + py) * 64 + ow * 4 + px) * 256 + 128 + ch] = row[ch * 16 + pp];
    }
  }
}

// ---------------------------------------------------------------------------
// 3x3 conv, pad=1, NHWC bf16 input, [9][256][CIN] bf16 weights, fp32 bias,
// leaky-relu 0.2, NCHW fp32 out. 128x128 tile; halo slab in LDS (ch-pad 40).
// ---------------------------------------------------------------------------
template<int H, int W, int CIN>
__global__ __launch_bounds__(256) void conv3x3(const unsigned short* __restrict__ Cin,
                                               const unsigned short* __restrict__ Wt,
                                               const float* __restrict__ bias,
                                               float* __restrict__ out) {
  constexpr int ROWS = 128 / W;
  constexpr int SLABW = W + 2;
  constexpr int SLABR = ROWS + 2;
  constexpr int CP = 40;
  constexpr int RUNS = SLABR * SLABW * 4;
  __shared__ __align__(16) unsigned short slab[SLABR * SLABW * CP];
  const int tid = threadIdx.x;
  const int w = tid >> 6, lane = tid & 63;
  const int wm = w >> 1, wn = w & 1;
  const int g = lane >> 4, l16 = lane & 15;
  const int bt = blockIdx.z;
  const int m0 = blockIdx.y * 128;
  const int y0 = blockIdx.x * ROWS;

  floatx4 acc[4][4];
  const floatx4 z4 = {0.f, 0.f, 0.f, 0.f};
#pragma unroll
  for (int i = 0; i < 4; ++i)
#pragma unroll
    for (int j = 0; j < 4; ++j) acc[i][j] = z4;

  for (int ch0 = 0; ch0 < CIN; ch0 += 32) {
    __syncthreads();
#pragma unroll
    for (int it = 0; it < (RUNS + 255) / 256; ++it) {
      const int run = it * 256 + tid;
      if (run < RUNS) {
        const int c8 = (run & 3) * 8;
        const int xy = run >> 2;
        const int cx = xy % SLABW, ry = xy / SLABW;
        const int yy = y0 + ry - 1, xx = cx - 1;
        short8 val = {0, 0, 0, 0, 0, 0, 0, 0};
        if (yy >= 0 && yy < H && xx >= 0 && xx < W)
          val = *(const short8*)(Cin + (((long)bt * H + yy) * W + xx) * CIN + ch0 + c8);
        *(short8*)(slab + (ry * SLABW + cx) * CP + c8) = val;
      }
    }
    __syncthreads();
#pragma unroll
    for (int t9 = 0; t9 < 9; ++t9) {
      const int ky = t9 / 3, kx = t9 % 3;
      short8 af[4], bf[4];
#pragma unroll
      for (int mi = 0; mi < 4; ++mi)
        af[mi] = *(const short8*)(Wt + ((long)t9 * 256 + m0 + wm * 64 + mi * 16 + l16) * CIN + ch0 + g * 8);
#pragma unroll
      for (int ni = 0; ni < 4; ++ni) {
        const int pn = wn * 64 + ni * 16;
        const int yt = pn / W, xb = pn % W;
        bf[ni] = *(const short8*)(slab + ((yt + ky) * SLABW + xb + l16 + kx) * CP + g * 8);
      }
#pragma unroll
      for (int mi = 0; mi < 4; ++mi)
#pragma unroll
        for (int ni = 0; ni < 4; ++ni)
          acc[mi][ni] = __builtin_amdgcn_mfma_f32_16x16x32_bf16(af[mi], bf[ni], acc[mi][ni], 0, 0, 0);
    }
  }

#pragma unroll
  for (int mi = 0; mi < 4; ++mi) {
#pragma unroll
    for (int ni = 0; ni < 4; ++ni) {
      const int pn = wn * 64 + ni * 16 + l16;
      const int y = y0 + pn / W, x = pn % W;
#pragma unroll
      for (int r4 = 0; r4 < 4; ++r4) {
        const int co = m0 + wm * 64 + mi * 16 + g * 4 + r4;
        float v = acc[mi][ni][r4] + bias[co];
        v = v > 0.f ? v : 0.2f * v;
        out[(((long)bt * 256 + co) * H + y) * W + x] = v;
      }
    }
  }
}

// ---------------------------------------------------------------------------
extern "C" void kernel_launch(void* const* d_in, const int* in_sizes, int n_in,
                              void* d_out, int out_size, void* d_ws, size_t ws_size,
                              hipStream_t stream) {
  (void)in_sizes; (void)n_in; (void)out_size; (void)ws_size;
  const float* x_lo = (const float*)d_in[0];
  const float* x_hi = (const float*)d_in[1];
  const float* wq_lo = (const float*)d_in[3];
  const float* bq_lo = (const float*)d_in[4];
  const float* wk_lo = (const float*)d_in[5];
  const float* bk_lo = (const float*)d_in[6];
  const float* wv_lo = (const float*)d_in[7];
  const float* bv_lo = (const float*)d_in[8];
  const float* wq_hi = (const float*)d_in[9];
  const float* bq_hi = (const float*)d_in[10];
  const float* wk_hi = (const float*)d_in[11];
  const float* bk_hi = (const float*)d_in[12];
  const float* wv_hi = (const float*)d_in[13];
  const float* bv_hi = (const float*)d_in[14];
  const float* wo_lo = (const float*)d_in[15];
  const float* bo_lo = (const float*)d_in[16];
  const float* wo_hi = (const float*)d_in[17];
  const float* bo_hi = (const float*)d_in[18];
  float* out = (float*)d_out;

  char* ws = (char*)d_ws;
  const long B0 = 33554432;  // 16.78M bf16 elements
  unsigned short* Qp0 = (unsigned short*)(ws);            // later aliased: Y0
  unsigned short* Kp0 = (unsigned short*)(ws + B0);       // later: S1, then Cin_lo
  unsigned short* V0t = (unsigned short*)(ws + 2 * B0);
  unsigned short* Qp1 = (unsigned short*)(ws + 3 * B0);   // later aliased: Y1
  unsigned short* Kp1 = (unsigned short*)(ws + 4 * B0);   // later: Cin_hi
  unsigned short* V1t = (unsigned short*)(ws + 5 * B0);
  char* ptr = ws + 6 * B0;
  unsigned short* S0 = (unsigned short*)ptr;     ptr += 2097152;
  unsigned short* Xt_lo = (unsigned short*)ptr;  ptr += 8388608;
  unsigned short* Xt_hi = (unsigned short*)ptr;  ptr += 33554432;
  unsigned short* Wcat_lo = (unsigned short*)ptr; ptr += 1572864;
  unsigned short* Wcat_hi = (unsigned short*)ptr; ptr += 393216;
  float* Bcat_lo = (float*)ptr;                  ptr += 12288;
  float* Bcat_hi = (float*)ptr;                  ptr += 3072;
  unsigned short* Wt_lo = (unsigned short*)ptr;  ptr += 4718592;
  unsigned short* Wt_hi = (unsigned short*)ptr;  ptr += 1179648;
  unsigned short* S1 = Kp0;
  unsigned short* Y0 = Qp0;
  unsigned short* Y1 = Qp1;
  unsigned short* Cin_lo = Kp0;
  unsigned short* Cin_hi = Kp1;

  // --- weight/input prep ---
  prep_qkv_w<<<(3 * 1024 * 256 + 255) / 256, 256, 0, stream>>>(
      wq_lo, wk_lo, wv_lo, bq_lo, bk_lo, bv_lo, Wcat_lo, Bcat_lo, 1024);
  prep_qkv_w<<<(3 * 256 * 256 + 255) / 256, 256, 0, stream>>>(
      wq_hi, wk_hi, wv_hi, bq_hi, bk_hi, bv_hi, Wcat_hi, Bcat_hi, 256);
  prep_conv_w<<<(9 * 256 * 1024 + 255) / 256, 256, 0, stream>>>(wo_lo, Wt_lo, 1024);
  prep_conv_w<<<(9 * 256 * 256 + 255) / 256, 256, 0, stream>>>(wo_hi, Wt_hi, 256);
  xt_kernel<<<dim3(16, 4, 16), 256, 0, stream>>>(x_lo, Xt_lo, 1024);
  xt_kernel<<<dim3(64, 4, 16), 256, 0, stream>>>(x_hi, Xt_hi, 4096);

  // --- QKV projections (1x1 conv as TN-GEMM), scattered to patch layout ---
  {
    GemmP p{};
    p.A = Wcat_lo; p.B = Xt_lo; p.sAb = 0; p.sBb = 1024L * 256;
    p.lda = 256; p.ldb = 256; p.K = 256;
    p.bias = Bcat_lo;
    p.Q0 = Qp0; p.K0 = Kp0; p.V0t = V0t; p.Q1 = Qp1; p.K1 = Kp1; p.V1t = V1t;
    gemm_tn<2><<<dim3(8, 24, 16), 256, 0, stream>>>(p);
    p.A = Wcat_hi; p.B = Xt_hi; p.sBb = 4096L * 256; p.bias = Bcat_hi;
    gemm_tn<3><<<dim3(32, 6, 16), 256, 0, stream>>>(p);
  }

  // --- attention cfg0: n=512, d=8192 ---
  {
    GemmP s{};
    s.A = Qp0; s.B = Kp0; s.sAb = 512L * 8192; s.sBb = 512L * 8192;
    s.lda = 8192; s.ldb = 8192; s.K = 8192;
    s.C = S0; s.sCb = 512L * 512; s.ldc = 512;
    gemm_tn<0><<<dim3(4, 4, 4), 256, 0, stream>>>(s);
    softmax_rows<512><<<512, 256, 0, stream>>>(S0);
    GemmP pv{};
    pv.A = S0; pv.B = V0t; pv.sAb = 512L * 512; pv.sBb = 8192L * 512;
    pv.lda = 512; pv.ldb = 512; pv.K = 512;
    pv.C = Y0; pv.sCb = 512L * 8192; pv.ldc = 8192;
    gemm_tn<0><<<dim3(64, 4, 4), 256, 0, stream>>>(pv);
  }

  // --- attention cfg1: n=2048, d=2048 ---
  {
    GemmP s{};
    s.A = Qp1; s.B = Kp1; s.sAb = 2048L * 2048; s.sBb = 2048L * 2048;
    s.lda = 2048; s.ldb = 2048; s.K = 2048;
    s.C = S1; s.sCb = 2048L * 2048; s.ldc = 2048;
    gemm_tn<0><<<dim3(16, 16, 4), 256, 0, stream>>>(s);
    softmax_rows<2048><<<2048, 256, 0, stream>>>(S1);
    GemmP pv{};
    pv.A = S1; pv.B = V1t; pv.sAb = 2048L * 2048; pv.sBb = 2048L * 2048;
    pv.lda = 2048; pv.ldb = 2048; pv.K = 2048;
    pv.C = Y1; pv.sCb = 2048L * 2048; pv.ldc = 2048;
    gemm_tn<0><<<dim3(16, 16, 4), 256, 0, stream>>>(pv);
  }

  // --- from_patches + channel concat -> NHWC conv inputs ---
  repack_lo<<<5120, 256, 0, stream>>>(Y0, Y1, Cin_lo);
  repack_hi<<<5120, 256, 0, stream>>>(Y0, Y1, Cin_hi);

  // --- 3x3 convs + bias + leaky relu -> fp32 outputs ---
  conv3x3<32, 32, 1024><<<dim3(8, 2, 16), 256, 0, stream>>>(Cin_lo, Wt_lo, bo_lo, out);
  conv3x3<64, 64, 256><<<dim3(32, 2, 16), 256, 0, stream>>>(Cin_hi, Wt_hi, bo_hi, out + 4194304);
}

// Round 2
// 957.001 us; speedup vs baseline: 1.1466x; 1.1466x over previous
//
#include <hip/hip_runtime.h>
#include <hip/hip_bf16.h>
#include <stdint.h>

typedef __attribute__((ext_vector_type(8))) short short8;
typedef __attribute__((ext_vector_type(4))) float floatx4;

__device__ __forceinline__ unsigned short f2b(float f) {
  unsigned u = __builtin_bit_cast(unsigned, f);
  unsigned r = u + 0x7fffu + ((u >> 16) & 1u);
  return (unsigned short)(r >> 16);
}
__device__ __forceinline__ float b2f(unsigned short h) {
  unsigned u = ((unsigned)h) << 16;
  return __builtin_bit_cast(float, u);
}

// ---------------------------------------------------------------------------
// Generic TN GEMM: C[M,N] = A[M,K] * B[N,K]^T, bf16 in, fp32 accum.
// 128x128 tile, 4 waves (2x2), BK=32, global_load_lds staging (linear LDS).
// EPI 0: bf16 C store. EPI 1: split-K(8) fp32 partial store.
// EPI 2/3: QKV lo/hi scatter epilogues.
// ---------------------------------------------------------------------------
struct GemmP {
  const unsigned short* A;
  const unsigned short* B;
  long sAb, sBb;          // batch strides (elements)
  int lda, ldb, K;
  unsigned short* C; long sCb; int ldc;   // EPI 0
  float* Cp;                              // EPI 1 (sCb/ldc reused as float strides)
  const float* bias;                      // EPI 2/3
  unsigned short *Q0, *K0, *V0t, *Q1, *K1, *V1t; // EPI 2/3 scatter targets
};

template<int EPI>
__global__ __launch_bounds__(256) void gemm_tn(GemmP p) {
  __shared__ __align__(16) unsigned short As[128 * 32];
  __shared__ __align__(16) unsigned short Bs[128 * 32];
  const int tid = threadIdx.x;
  const int w = tid >> 6, lane = tid & 63;
  const int wm = w >> 1, wn = w & 1;
  const int g = lane >> 4, l16 = lane & 15;
  const int bz = blockIdx.z;
  const int m0 = blockIdx.y * 128, n0 = blockIdx.x * 128;

  int bb = bz, koff = 0, Keff = p.K;
  if constexpr (EPI == 1) {          // split-K 8
    bb = bz >> 3;
    koff = (bz & 7) * (p.K >> 3);
    Keff = p.K >> 3;
  }
  const unsigned short* Ab = p.A + (long)bb * p.sAb + (long)m0 * p.lda + koff;
  const unsigned short* Bb = p.B + (long)bb * p.sBb + (long)n0 * p.ldb + koff;
  const int srow = tid >> 2;
  const int sc8 = (tid & 3) * 8;

  floatx4 acc[4][4];
  const floatx4 z4 = {0.f, 0.f, 0.f, 0.f};
#pragma unroll
  for (int i = 0; i < 4; ++i)
#pragma unroll
    for (int j = 0; j < 4; ++j) acc[i][j] = z4;

  for (int k0 = 0; k0 < Keff; k0 += 32) {
    __syncthreads();
#pragma unroll
    for (int r = 0; r < 2; ++r) {
      const unsigned short* ga = Ab + (long)(r * 64 + srow) * p.lda + k0 + sc8;
      __builtin_amdgcn_global_load_lds(
          (const __attribute__((address_space(1))) void*)ga,
          (__attribute__((address_space(3))) void*)(As + (r * 4 + w) * 512), 16, 0, 0);
      const unsigned short* gb = Bb + (long)(r * 64 + srow) * p.ldb + k0 + sc8;
      __builtin_amdgcn_global_load_lds(
          (const __attribute__((address_space(1))) void*)gb,
          (__attribute__((address_space(3))) void*)(Bs + (r * 4 + w) * 512), 16, 0, 0);
    }
    __syncthreads();
    short8 af[4], bf[4];
#pragma unroll
    for (int mi = 0; mi < 4; ++mi)
      af[mi] = *(const short8*)(As + (wm * 64 + mi * 16 + l16) * 32 + g * 8);
#pragma unroll
    for (int ni = 0; ni < 4; ++ni)
      bf[ni] = *(const short8*)(Bs + (wn * 64 + ni * 16 + l16) * 32 + g * 8);
#pragma unroll
    for (int mi = 0; mi < 4; ++mi)
#pragma unroll
      for (int ni = 0; ni < 4; ++ni)
        acc[mi][ni] = __builtin_amdgcn_mfma_f32_16x16x32_bf16(af[mi], bf[ni], acc[mi][ni], 0, 0, 0);
  }

  if constexpr (EPI == 0) {
    unsigned short* C = p.C + (long)bz * p.sCb;
#pragma unroll
    for (int mi = 0; mi < 4; ++mi) {
#pragma unroll
      for (int ni = 0; ni < 4; ++ni) {
        const int col = n0 + wn * 64 + ni * 16 + l16;
#pragma unroll
        for (int r4 = 0; r4 < 4; ++r4) {
          const int row = m0 + wm * 64 + mi * 16 + g * 4 + r4;
          C[(long)row * p.ldc + col] = f2b(acc[mi][ni][r4]);
        }
      }
    }
  } else if constexpr (EPI == 1) {   // fp32 partial, slab per (b,ks)=bz
    float* C = p.Cp + (long)bz * p.sCb;
#pragma unroll
    for (int mi = 0; mi < 4; ++mi) {
#pragma unroll
      for (int ni = 0; ni < 4; ++ni) {
        const int col = n0 + wn * 64 + ni * 16 + l16;
#pragma unroll
        for (int r4 = 0; r4 < 4; ++r4) {
          const int row = m0 + wm * 64 + mi * 16 + g * 4 + r4;
          C[(long)row * p.ldc + col] = acc[mi][ni][r4];
        }
      }
    }
  } else if constexpr (EPI == 2) {   // QKV lo scatter: co in [0,3072), pix in [0,1024)
    const int b = bz >> 2, t = bz & 3;
#pragma unroll
    for (int mi = 0; mi < 4; ++mi) {
#pragma unroll
      for (int r4 = 0; r4 < 4; ++r4) {
        const int co = m0 + wm * 64 + mi * 16 + g * 4 + r4;
        const int sel = co >> 10;
        const int ch = co & 1023;
        const float bv = p.bias[co];
#pragma unroll
        for (int ni = 0; ni < 4; ++ni) {
          const int pix = n0 + wn * 64 + ni * 16 + l16;
          const int y = pix >> 5, x = pix & 31;
          float v = acc[mi][ni][r4] + bv;
          if (ch < 512) {                       // cfg0: 4x4 patches, d=8192
            if (sel == 0) v *= 0.011048543456039806f;   // 1/sqrt(8192)
            const int nseq = (t * 8 + (y >> 2)) * 8 + (x >> 2);
            const int f = (ch * 4 + (y & 3)) * 4 + (x & 3);
            const unsigned short hv = f2b(v);
            if (sel == 0)      p.Q0[((long)(b * 512 + nseq)) * 8192 + f] = hv;
            else if (sel == 1) p.K0[((long)(b * 512 + nseq)) * 8192 + f] = hv;
            else               p.V0t[((long)(b * 8192 + f)) * 512 + nseq] = hv;
          } else {                              // cfg1: 2x2 patches, d=2048
            if (sel == 0) v *= 0.02209708691207961f;    // 1/sqrt(2048)
            const int c2 = ch - 512;
            const int nseq = (t * 16 + (y >> 1)) * 16 + (x >> 1);
            const int f = (c2 * 2 + (y & 1)) * 2 + (x & 1);
            const unsigned short hv = f2b(v);
            if (sel == 0)      p.Q1[((long)(b * 2048 + nseq)) * 2048 + f] = hv;
            else if (sel == 1) p.K1[((long)(b * 2048 + nseq)) * 2048 + f] = hv;
            else               p.V1t[((long)(b * 2048 + f)) * 2048 + nseq] = hv;
          }
        }
      }
    }
  } else if constexpr (EPI == 3) {   // QKV hi scatter: co in [0,768), pix in [0,4096)
    const int b = bz >> 2, t = bz & 3;
#pragma unroll
    for (int mi = 0; mi < 4; ++mi) {
#pragma unroll
      for (int r4 = 0; r4 < 4; ++r4) {
        const int co = m0 + wm * 64 + mi * 16 + g * 4 + r4;
        const int sel = co >> 8;
        const int ch = co & 255;
        const float bv = p.bias[co];
#pragma unroll
        for (int ni = 0; ni < 4; ++ni) {
          const int pix = n0 + wn * 64 + ni * 16 + l16;
          const int y = pix >> 6, x = pix & 63;
          float v = acc[mi][ni][r4] + bv;
          if (ch < 128) {                       // cfg0: 8x8 patches
            if (sel == 0) v *= 0.011048543456039806f;
            const int nseq = 256 + (t * 8 + (y >> 3)) * 8 + (x >> 3);
            const int f = (ch * 8 + (y & 7)) * 8 + (x & 7);
            const unsigned short hv = f2b(v);
            if (sel == 0)      p.Q0[((long)(b * 512 + nseq)) * 8192 + f] = hv;
            else if (sel == 1) p.K0[((long)(b * 512 + nseq)) * 8192 + f] = hv;
            else               p.V0t[((long)(b * 8192 + f)) * 512 + nseq] = hv;
          } else {                              // cfg1: 4x4 patches
            if (sel == 0) v *= 0.02209708691207961f;
            const int c2 = ch - 128;
            const int nseq = 1024 + (t * 16 + (y >> 2)) * 16 + (x >> 2);
            const int f = (c2 * 4 + (y & 3)) * 4 + (x & 3);
            const unsigned short hv = f2b(v);
            if (sel == 0)      p.Q1[((long)(b * 2048 + nseq)) * 2048 + f] = hv;
            else if (sel == 1) p.K1[((long)(b * 2048 + nseq)) * 2048 + f] = hv;
            else               p.V1t[((long)(b * 2048 + f)) * 2048 + nseq] = hv;
          }
        }
      }
    }
  }
}

// ---------------------------------------------------------------------------
// Row softmax in-place on bf16 rows of length L. One wave per row.
// ---------------------------------------------------------------------------
template<int L>
__global__ __launch_bounds__(256) void softmax_rows(unsigned short* S) {
  const int w = threadIdx.x >> 6, lane = threadIdx.x & 63;
  const long row = (long)blockIdx.x * 4 + w;
  unsigned short* R = S + row * L;
  constexpr int NC = L / 64;
  float v[NC];
  float m = -1e30f;
#pragma unroll
  for (int i = 0; i < NC; ++i) { v[i] = b2f(R[i * 64 + lane]); m = fmaxf(m, v[i]); }
#pragma unroll
  for (int off = 32; off; off >>= 1) m = fmaxf(m, __shfl_xor(m, off, 64));
  float s = 0.f;
#pragma unroll
  for (int i = 0; i < NC; ++i) { v[i] = __expf(v[i] - m); s += v[i]; }
#pragma unroll
  for (int off = 32; off; off >>= 1) s += __shfl_xor(s, off, 64);
  const float inv = 1.0f / s;
#pragma unroll
  for (int i = 0; i < NC; ++i) R[i * 64 + lane] = f2b(v[i] * inv);
}

// ---------------------------------------------------------------------------
// S0: sum 8 fp32 split-K slabs [b*8+ks][512][512] -> softmax -> bf16 [b][512][512]
// ---------------------------------------------------------------------------
__global__ __launch_bounds__(256) void softmax_red8(const float* __restrict__ P,
                                                    unsigned short* __restrict__ S) {
  const int w = threadIdx.x >> 6, lane = threadIdx.x & 63;
  const int rowg = blockIdx.x * 4 + w;            // 0..2047
  const int b = rowg >> 9, n = rowg & 511;
  const float* base = P + ((long)b * 8) * 262144 + (long)n * 512 + lane;
  float v[8];
#pragma unroll
  for (int i = 0; i < 8; ++i) {
    float s = 0.f;
#pragma unroll
    for (int ks = 0; ks < 8; ++ks) s += base[(long)ks * 262144 + i * 64];
    v[i] = s;
  }
  float m = -1e30f;
#pragma unroll
  for (int i = 0; i < 8; ++i) m = fmaxf(m, v[i]);
#pragma unroll
  for (int off = 32; off; off >>= 1) m = fmaxf(m, __shfl_xor(m, off, 64));
  float s = 0.f;
#pragma unroll
  for (int i = 0; i < 8; ++i) { v[i] = __expf(v[i] - m); s += v[i]; }
#pragma unroll
  for (int off = 32; off; off >>= 1) s += __shfl_xor(s, off, 64);
  const float inv = 1.0f / s;
  unsigned short* R = S + (long)rowg * 512;
#pragma unroll
  for (int i = 0; i < 8; ++i) R[i * 64 + lane] = f2b(v[i] * inv);
}

// ---------------------------------------------------------------------------
// x [16][256][NPIX] fp32 (NCHW) -> xt [16][NPIX][256] bf16 (pixel-major)
// ---------------------------------------------------------------------------
__global__ __launch_bounds__(256) void xt_kernel(const float* __restrict__ x,
                                                 unsigned short* __restrict__ xt, int NPIX) {
  __shared__ unsigned short tile[64 * 65];
  const int tid = threadIdx.x;
  const int bt = blockIdx.z, ch0 = blockIdx.y * 64;
  const long pix0 = (long)blockIdx.x * 64;
  const float* src = x + ((long)bt * 256 + ch0) * NPIX + pix0;
#pragma unroll
  for (int i = 0; i < 16; ++i) {
    const int lin = i * 256 + tid;
    const int ch = lin >> 6, px = lin & 63;
    tile[ch * 65 + px] = f2b(src[(long)ch * NPIX + px]);
  }
  __syncthreads();
  unsigned short* dst = xt + ((long)bt * NPIX + pix0) * 256 + ch0;
#pragma unroll
  for (int i = 0; i < 16; ++i) {
    const int lin = i * 256 + tid;
    const int px = lin >> 6, ch = lin & 63;
    dst[(long)px * 256 + ch] = tile[ch * 65 + px];
  }
}

// ---------------------------------------------------------------------------
// Weight prep
// ---------------------------------------------------------------------------
__global__ void prep_qkv_w(const float* wq, const float* wk, const float* wv,
                           const float* bq, const float* bk, const float* bv,
                           unsigned short* Wcat, float* Bcat, int CO) {
  const int idx = blockIdx.x * 256 + threadIdx.x;
  const int n = 3 * CO * 256;
  if (idx < n) {
    const int sel = idx / (CO * 256);
    const int r = idx - sel * CO * 256;
    const float* wsel = sel == 0 ? wq : (sel == 1 ? wk : wv);
    Wcat[idx] = f2b(wsel[r]);
  }
  if (idx < 3 * CO) {
    const int sel = idx / CO;
    const int r = idx - sel * CO;
    const float* bsel = sel == 0 ? bq : (sel == 1 ? bk : bv);
    Bcat[idx] = bsel[r];
  }
}

__global__ void prep_conv_w(const float* wo, unsigned short* Wt, int CIN) {
  const int idx = blockIdx.x * 256 + threadIdx.x;
  const int n = 9 * 256 * CIN;
  if (idx < n) {
    const int t9 = idx / (256 * CIN);
    const int rem = idx - t9 * 256 * CIN;
    const int o = rem / CIN, i = rem - o * CIN;
    Wt[idx] = f2b(wo[((long)o * CIN + i) * 9 + t9]);   // [9][256][CIN]
  }
}

// ---------------------------------------------------------------------------
// Repack attention outputs Y (patch-major) -> NHWC conv inputs
// ---------------------------------------------------------------------------
__global__ __launch_bounds__(256) void repack_lo(const unsigned short* __restrict__ Y0,
                                                 const unsigned short* __restrict__ Y1,
                                                 unsigned short* __restrict__ out) {
  const int tid = threadIdx.x;
  const int blk = blockIdx.x;
  if (blk < 1024) {          // cfg0: 16px x 512ch per row
    const int b = blk >> 8, n = blk & 255;
    const int t = n >> 6, oh = (n >> 3) & 7, ow = n & 7;
    const unsigned short* row = Y0 + ((long)(b * 512 + n)) * 8192;
    const int bt = b * 4 + t;
#pragma unroll
    for (int j = 0; j < 32; ++j) {
      const int idx = j * 256 + tid;
      const int pp = idx >> 9, ch = idx & 511;
      const int py = pp >> 2, px = pp & 3;
      out[(((long)bt * 32 + oh * 4 + py) * 32 + ow * 4 + px) * 1024 + ch] = row[ch * 16 + pp];
    }
  } else {                   // cfg1: 4px x 512ch per row
    const int q = blk - 1024;
    const int b = q >> 10, n = q & 1023;
    const int t = n >> 8, oh = (n >> 4) & 15, ow = n & 15;
    const unsigned short* row = Y1 + ((long)(b * 2048 + n)) * 2048;
    const int bt = b * 4 + t;
#pragma unroll
    for (int j = 0; j < 8; ++j) {
      const int idx = j * 256 + tid;
      const int pp = idx >> 9, ch = idx & 511;
      const int py = pp >> 1, px = pp & 1;
      out[(((long)bt * 32 + oh * 2 + py) * 32 + ow * 2 + px) * 1024 + 512 + ch] = row[ch * 4 + pp];
    }
  }
}

__global__ __launch_bounds__(256) void repack_hi(const unsigned short* __restrict__ Y0,
                                                 const unsigned short* __restrict__ Y1,
                                                 unsigned short* __restrict__ out) {
  const int tid = threadIdx.x;
  const int blk = blockIdx.x;
  if (blk < 1024) {          // cfg0: 64px x 128ch per row
    const int b = blk >> 8, n = blk & 255;
    const int t = n >> 6, oh = (n >> 3) & 7, ow = n & 7;
    const unsigned short* row = Y0 + ((long)(b * 512 + 256 + n)) * 8192;
    const int bt = b * 4 + t;
#pragma unroll
    for (int j = 0; j < 32; ++j) {
      const int idx = j * 256 + tid;
      const int pp = idx >> 7, ch = idx & 127;
      const int py = pp >> 3, px = pp & 7;
      out[(((long)bt * 64 + oh * 8 + py) * 64 + ow * 8 + px) * 256 + ch] = row[ch * 64 + pp];
    }
  } else {                   // cfg1: 16px x 128ch per row
    const int q = blk - 1024;
    const int b = q >> 10, n = q & 1023;
    const int t = n >> 8, oh = (n >> 4) & 15, ow = n & 15;
    const unsigned short* row = Y1 + ((long)(b * 2048 + 1024 + n)) * 2048;
    const int bt = b * 4 + t;
#pragma unroll
    for (int j = 0; j < 8; ++j) {
      const int idx = j * 256 + tid;
      const int pp = idx >> 7, ch = idx & 127;
      const int py = pp >> 2, px = pp & 3;
      out[(((long)bt * 64 + oh * 4 + py) * 64 + ow * 4 + px) * 256 + 128 + ch] = row[ch * 16 + pp];
    }
  }
}

// ---------------------------------------------------------------------------
// 3x3 conv, pad=1, NHWC bf16 input, [9][256][CIN] bf16 weights.
// Split-K over input channels (KS slabs) + double-buffered reg->LDS staging.
// KS==1: bias + leaky-relu + NCHW fp32 store.  KS==4: fp32 partial store.
// ---------------------------------------------------------------------------
template<int H, int W, int CIN, int KS>
__global__ __launch_bounds__(256) void conv3x3(const unsigned short* __restrict__ Cin,
                                               const unsigned short* __restrict__ Wt,
                                               const float* __restrict__ bias,
                                               float* __restrict__ out,
                                               float* __restrict__ P0,
                                               float* __restrict__ P1) {
  constexpr int ROWS = 128 / W;
  constexpr int SLABW = W + 2;
  constexpr int SLABR = ROWS + 2;
  constexpr int CP = 40;
  constexpr int RUNS = SLABR * SLABW * 4;
  constexpr int NLD = (RUNS + 255) / 256;
  constexpr int SLABSZ = SLABR * SLABW * CP;
  constexpr int CC = CIN / KS;
  constexpr int NSTEP = CC / 32;
  __shared__ __align__(16) unsigned short slab[2][SLABSZ];
  const int tid = threadIdx.x;
  const int w = tid >> 6, lane = tid & 63;
  const int wm = w >> 1, wn = w & 1;
  const int g = lane >> 4, l16 = lane & 15;
  const int bz = blockIdx.z;
  const int bt = bz / KS, ks = bz % KS;
  const int chbase = ks * CC;
  const int m0 = blockIdx.y * 128;
  const int y0 = blockIdx.x * ROWS;

  short8 rv[NLD];
  auto LOADR = [&](int ch0) {
#pragma unroll
    for (int it = 0; it < NLD; ++it) {
      const int run = it * 256 + tid;
      short8 val = {0, 0, 0, 0, 0, 0, 0, 0};
      if (run < RUNS) {
        const int c8 = (run & 3) * 8;
        const int xy = run >> 2;
        const int cx = xy % SLABW, ry = xy / SLABW;
        const int yy = y0 + ry - 1, xx = cx - 1;
        if (yy >= 0 && yy < H && xx >= 0 && xx < W)
          val = *(const short8*)(Cin + (((long)bt * H + yy) * W + xx) * CIN + ch0 + c8);
      }
      rv[it] = val;
    }
  };
  auto WRITER = [&](int cur) {
    unsigned short* sb = &slab[cur][0];
#pragma unroll
    for (int it = 0; it < NLD; ++it) {
      const int run = it * 256 + tid;
      if (run < RUNS) {
        const int c8 = (run & 3) * 8;
        const int xy = run >> 2;
        *(short8*)(sb + xy * CP + c8) = rv[it];
      }
    }
  };

  floatx4 acc[4][4];
  const floatx4 z4 = {0.f, 0.f, 0.f, 0.f};
#pragma unroll
  for (int i = 0; i < 4; ++i)
#pragma unroll
    for (int j = 0; j < 4; ++j) acc[i][j] = z4;

  LOADR(chbase);
  WRITER(0);
  __syncthreads();

  for (int step = 0; step < NSTEP; ++step) {
    const int cur = step & 1;
    if (step + 1 < NSTEP) LOADR(chbase + (step + 1) * 32);
    const unsigned short* sb = &slab[cur][0];
    const int chw = chbase + step * 32;
#pragma unroll
    for (int t9 = 0; t9 < 9; ++t9) {
      const int ky = t9 / 3, kx = t9 % 3;
      short8 af[4], bf[4];
#pragma unroll
      for (int mi = 0; mi < 4; ++mi)
        af[mi] = *(const short8*)(Wt + ((long)t9 * 256 + m0 + wm * 64 + mi * 16 + l16) * CIN + chw + g * 8);
#pragma unroll
      for (int ni = 0; ni < 4; ++ni) {
        const int pn = wn * 64 + ni * 16;
        const int yt = pn / W, xb = pn % W;
        bf[ni] = *(const short8*)(sb + ((yt + ky) * SLABW + xb + l16 + kx) * CP + g * 8);
      }
#pragma unroll
      for (int mi = 0; mi < 4; ++mi)
#pragma unroll
        for (int ni = 0; ni < 4; ++ni)
          acc[mi][ni] = __builtin_amdgcn_mfma_f32_16x16x32_bf16(af[mi], bf[ni], acc[mi][ni], 0, 0, 0);
    }
    if (step + 1 < NSTEP) WRITER(cur ^ 1);
    __syncthreads();
  }

  if constexpr (KS == 1) {
#pragma unroll
    for (int mi = 0; mi < 4; ++mi) {
#pragma unroll
      for (int ni = 0; ni < 4; ++ni) {
        const int pn = wn * 64 + ni * 16 + l16;
        const int y = y0 + pn / W, x = pn % W;
#pragma unroll
        for (int r4 = 0; r4 < 4; ++r4) {
          const int co = m0 + wm * 64 + mi * 16 + g * 4 + r4;
          float v = acc[mi][ni][r4] + bias[co];
          v = v > 0.f ? v : 0.2f * v;
          out[(((long)bt * 256 + co) * H + y) * W + x] = v;
        }
      }
    }
  } else {
    float* pout = (ks < 2 ? P0 : P1) + (long)(ks & 1) * (16L * 256 * H * W);
#pragma unroll
    for (int mi = 0; mi < 4; ++mi) {
#pragma unroll
      for (int ni = 0; ni < 4; ++ni) {
        const int pn = wn * 64 + ni * 16 + l16;
        const int y = y0 + pn / W, x = pn % W;
#pragma unroll
        for (int r4 = 0; r4 < 4; ++r4) {
          const int co = m0 + wm * 64 + mi * 16 + g * 4 + r4;
          pout[(((long)bt * 256 + co) * H + y) * W + x] = acc[mi][ni][r4];
        }
      }
    }
  }
}

// ---------------------------------------------------------------------------
// Sum 4 conv partial slabs (2 in P0, 2 in P1) + bias + leaky-relu -> out
// ---------------------------------------------------------------------------
__global__ __launch_bounds__(256) void reduce_lrelu(const floatx4* __restrict__ P0,
                                                    const floatx4* __restrict__ P1,
                                                    const float* __restrict__ bias,
                                                    floatx4* __restrict__ out) {
  const long i = (long)blockIdx.x * 256 + threadIdx.x;  // float4 index; 1048576 total
  constexpr long SL = 1048576;
  floatx4 a = P0[i], b = P0[SL + i], c = P1[i], d = P1[SL + i];
  const int co = ((int)(i >> 8)) & 255;
  const float bv = bias[co];
  floatx4 r;
#pragma unroll
  for (int j = 0; j < 4; ++j) {
    float v = a[j] + b[j] + c[j] + d[j] + bv;
    r[j] = v > 0.f ? v : 0.2f * v;
  }
  out[i] = r;
}

// ---------------------------------------------------------------------------
extern "C" void kernel_launch(void* const* d_in, const int* in_sizes, int n_in,
                              void* d_out, int out_size, void* d_ws, size_t ws_size,
                              hipStream_t stream) {
  (void)in_sizes; (void)n_in; (void)out_size; (void)ws_size;
  const float* x_lo = (const float*)d_in[0];
  const float* x_hi = (const float*)d_in[1];
  const float* wq_lo = (const float*)d_in[3];
  const float* bq_lo = (const float*)d_in[4];
  const float* wk_lo = (const float*)d_in[5];
  const float* bk_lo = (const float*)d_in[6];
  const float* wv_lo = (const float*)d_in[7];
  const float* bv_lo = (const float*)d_in[8];
  const float* wq_hi = (const float*)d_in[9];
  const float* bq_hi = (const float*)d_in[10];
  const float* wk_hi = (const float*)d_in[11];
  const float* bk_hi = (const float*)d_in[12];
  const float* wv_hi = (const float*)d_in[13];
  const float* bv_hi = (const float*)d_in[14];
  const float* wo_lo = (const float*)d_in[15];
  const float* bo_lo = (const float*)d_in[16];
  const float* wo_hi = (const float*)d_in[17];
  const float* bo_hi = (const float*)d_in[18];
  float* out = (float*)d_out;

  char* ws = (char*)d_ws;
  const long B0 = 33554432;  // 16.78M bf16 elements / 8.39M floats per region
  unsigned short* Qp0 = (unsigned short*)(ws);            // later: Y0, then conv partials P0
  unsigned short* Kp0 = (unsigned short*)(ws + B0);       // later: S1, then Cin_lo
  unsigned short* V0t = (unsigned short*)(ws + 2 * B0);
  unsigned short* Qp1 = (unsigned short*)(ws + 3 * B0);   // later: Y1, then conv partials P1
  unsigned short* Kp1 = (unsigned short*)(ws + 4 * B0);   // later: Cin_hi
  unsigned short* V1t = (unsigned short*)(ws + 5 * B0);
  char* ptr = ws + 6 * B0;
  unsigned short* S0 = (unsigned short*)ptr;     ptr += 2097152;
  unsigned short* Xt_lo = (unsigned short*)ptr;  ptr += 8388608;
  unsigned short* Xt_hi = (unsigned short*)ptr;  ptr += 33554432;   // later: S0 fp32 partials
  unsigned short* Wcat_lo = (unsigned short*)ptr; ptr += 1572864;
  unsigned short* Wcat_hi = (unsigned short*)ptr; ptr += 393216;
  float* Bcat_lo = (float*)ptr;                  ptr += 12288;
  float* Bcat_hi = (float*)ptr;                  ptr += 3072;
  unsigned short* Wt_lo = (unsigned short*)ptr;  ptr += 4718592;
  unsigned short* Wt_hi = (unsigned short*)ptr;  ptr += 1179648;
  unsigned short* S1 = Kp0;
  unsigned short* Y0 = Qp0;
  unsigned short* Y1 = Qp1;
  unsigned short* Cin_lo = Kp0;
  unsigned short* Cin_hi = Kp1;
  float* S0p = (float*)Xt_hi;       // 32 slabs x 262144 floats = 33.5 MB
  float* PC0 = (float*)Qp0;         // conv_lo partial slabs 0,1 (Y0 dead by then)
  float* PC1 = (float*)Qp1;         // conv_lo partial slabs 2,3 (Y1 dead by then)

  // --- weight/input prep ---
  prep_qkv_w<<<(3 * 1024 * 256 + 255) / 256, 256, 0, stream>>>(
      wq_lo, wk_lo, wv_lo, bq_lo, bk_lo, bv_lo, Wcat_lo, Bcat_lo, 1024);
  prep_qkv_w<<<(3 * 256 * 256 + 255) / 256, 256, 0, stream>>>(
      wq_hi, wk_hi, wv_hi, bq_hi, bk_hi, bv_hi, Wcat_hi, Bcat_hi, 256);
  prep_conv_w<<<(9 * 256 * 1024 + 255) / 256, 256, 0, stream>>>(wo_lo, Wt_lo, 1024);
  prep_conv_w<<<(9 * 256 * 256 + 255) / 256, 256, 0, stream>>>(wo_hi, Wt_hi, 256);
  xt_kernel<<<dim3(16, 4, 16), 256, 0, stream>>>(x_lo, Xt_lo, 1024);
  xt_kernel<<<dim3(64, 4, 16), 256, 0, stream>>>(x_hi, Xt_hi, 4096);

  // --- QKV projections (1x1 conv as TN-GEMM), scattered to patch layout ---
  {
    GemmP p{};
    p.A = Wcat_lo; p.B = Xt_lo; p.sAb = 0; p.sBb = 1024L * 256;
    p.lda = 256; p.ldb = 256; p.K = 256;
    p.bias = Bcat_lo;
    p.Q0 = Qp0; p.K0 = Kp0; p.V0t = V0t; p.Q1 = Qp1; p.K1 = Kp1; p.V1t = V1t;
    gemm_tn<2><<<dim3(8, 24, 16), 256, 0, stream>>>(p);
    p.A = Wcat_hi; p.B = Xt_hi; p.sBb = 4096L * 256; p.bias = Bcat_hi;
    gemm_tn<3><<<dim3(32, 6, 16), 256, 0, stream>>>(p);
  }

  // --- attention cfg0: n=512, d=8192 (split-K 8 + fused reduce softmax) ---
  {
    GemmP s{};
    s.A = Qp0; s.B = Kp0; s.sAb = 512L * 8192; s.sBb = 512L * 8192;
    s.lda = 8192; s.ldb = 8192; s.K = 8192;
    s.Cp = S0p; s.sCb = 512L * 512; s.ldc = 512;
    gemm_tn<1><<<dim3(4, 4, 32), 256, 0, stream>>>(s);
    softmax_red8<<<512, 256, 0, stream>>>(S0p, S0);
    GemmP pv{};
    pv.A = S0; pv.B = V0t; pv.sAb = 512L * 512; pv.sBb = 8192L * 512;
    pv.lda = 512; pv.ldb = 512; pv.K = 512;
    pv.C = Y0; pv.sCb = 512L * 8192; pv.ldc = 8192;
    gemm_tn<0><<<dim3(64, 4, 4), 256, 0, stream>>>(pv);
  }

  // --- attention cfg1: n=2048, d=2048 ---
  {
    GemmP s{};
    s.A = Qp1; s.B = Kp1; s.sAb = 2048L * 2048; s.sBb = 2048L * 2048;
    s.lda = 2048; s.ldb = 2048; s.K = 2048;
    s.C = S1; s.sCb = 2048L * 2048; s.ldc = 2048;
    gemm_tn<0><<<dim3(16, 16, 4), 256, 0, stream>>>(s);
    softmax_rows<2048><<<2048, 256, 0, stream>>>(S1);
    GemmP pv{};
    pv.A = S1; pv.B = V1t; pv.sAb = 2048L * 2048; pv.sBb = 2048L * 2048;
    pv.lda = 2048; pv.ldb = 2048; pv.K = 2048;
    pv.C = Y1; pv.sCb = 2048L * 2048; pv.ldc = 2048;
    gemm_tn<0><<<dim3(16, 16, 4), 256, 0, stream>>>(pv);
  }

  // --- from_patches + channel concat -> NHWC conv inputs ---
  repack_lo<<<5120, 256, 0, stream>>>(Y0, Y1, Cin_lo);
  repack_hi<<<5120, 256, 0, stream>>>(Y0, Y1, Cin_hi);

  // --- 3x3 convs + bias + leaky relu -> fp32 outputs ---
  conv3x3<32, 32, 1024, 4><<<dim3(8, 2, 64), 256, 0, stream>>>(
      Cin_lo, Wt_lo, bo_lo, out, PC0, PC1);
  reduce_lrelu<<<4096, 256, 0, stream>>>((const floatx4*)PC0, (const floatx4*)PC1, bo_lo,
                                         (floatx4*)out);
  conv3x3<64, 64, 256, 1><<<dim3(32, 2, 16), 256, 0, stream>>>(
      Cin_hi, Wt_hi, bo_hi, out + 4194304, nullptr, nullptr);
}

// Round 3
// 871.112 us; speedup vs baseline: 1.2596x; 1.0986x over previous
//
#include <hip/hip_runtime.h>
#include <hip/hip_bf16.h>
#include <stdint.h>

typedef __attribute__((ext_vector_type(8))) short short8;
typedef __attribute__((ext_vector_type(4))) float floatx4;

__device__ __forceinline__ unsigned short f2b(float f) {
  unsigned u = __builtin_bit_cast(unsigned, f);
  unsigned r = u + 0x7fffu + ((u >> 16) & 1u);
  return (unsigned short)(r >> 16);
}
__device__ __forceinline__ float b2f(unsigned short h) {
  unsigned u = ((unsigned)h) << 16;
  return __builtin_bit_cast(float, u);
}

// ---------------------------------------------------------------------------
// Generic TN GEMM: C[M,N] = A[M,K] * B[N,K]^T, bf16 in, fp32 accum.
// 128x128 tile, 4 waves (2x2), BK=32, global_load_lds staging (linear LDS).
// EPI 0: bf16 C store. EPI 1: split-K(8) fp32 partial store.
// EPI 2/3: QKV lo/hi scatter epilogues.
// ---------------------------------------------------------------------------
struct GemmP {
  const unsigned short* A;
  const unsigned short* B;
  long sAb, sBb;          // batch strides (elements)
  int lda, ldb, K;
  unsigned short* C; long sCb; int ldc;   // EPI 0
  float* Cp;                              // EPI 1
  const float* bias;                      // EPI 2/3
  unsigned short *Q0, *K0, *V0t, *Q1, *K1, *V1t; // EPI 2/3 scatter targets
};

template<int EPI>
__global__ __launch_bounds__(256) void gemm_tn(GemmP p) {
  __shared__ __align__(16) unsigned short As[128 * 32];
  __shared__ __align__(16) unsigned short Bs[128 * 32];
  const int tid = threadIdx.x;
  const int w = tid >> 6, lane = tid & 63;
  const int wm = w >> 1, wn = w & 1;
  const int g = lane >> 4, l16 = lane & 15;
  const int bz = blockIdx.z;
  const int m0 = blockIdx.y * 128, n0 = blockIdx.x * 128;

  int bb = bz, koff = 0, Keff = p.K;
  if constexpr (EPI == 1) {          // split-K 8
    bb = bz >> 3;
    koff = (bz & 7) * (p.K >> 3);
    Keff = p.K >> 3;
  }
  const unsigned short* Ab = p.A + (long)bb * p.sAb + (long)m0 * p.lda + koff;
  const unsigned short* Bb = p.B + (long)bb * p.sBb + (long)n0 * p.ldb + koff;
  const int srow = tid >> 2;
  const int sc8 = (tid & 3) * 8;

  floatx4 acc[4][4];
  const floatx4 z4 = {0.f, 0.f, 0.f, 0.f};
#pragma unroll
  for (int i = 0; i < 4; ++i)
#pragma unroll
    for (int j = 0; j < 4; ++j) acc[i][j] = z4;

  for (int k0 = 0; k0 < Keff; k0 += 32) {
    __syncthreads();
#pragma unroll
    for (int r = 0; r < 2; ++r) {
      const unsigned short* ga = Ab + (long)(r * 64 + srow) * p.lda + k0 + sc8;
      __builtin_amdgcn_global_load_lds(
          (const __attribute__((address_space(1))) void*)ga,
          (__attribute__((address_space(3))) void*)(As + (r * 4 + w) * 512), 16, 0, 0);
      const unsigned short* gb = Bb + (long)(r * 64 + srow) * p.ldb + k0 + sc8;
      __builtin_amdgcn_global_load_lds(
          (const __attribute__((address_space(1))) void*)gb,
          (__attribute__((address_space(3))) void*)(Bs + (r * 4 + w) * 512), 16, 0, 0);
    }
    __syncthreads();
    short8 af[4], bf[4];
#pragma unroll
    for (int mi = 0; mi < 4; ++mi)
      af[mi] = *(const short8*)(As + (wm * 64 + mi * 16 + l16) * 32 + g * 8);
#pragma unroll
    for (int ni = 0; ni < 4; ++ni)
      bf[ni] = *(const short8*)(Bs + (wn * 64 + ni * 16 + l16) * 32 + g * 8);
#pragma unroll
    for (int mi = 0; mi < 4; ++mi)
#pragma unroll
      for (int ni = 0; ni < 4; ++ni)
        acc[mi][ni] = __builtin_amdgcn_mfma_f32_16x16x32_bf16(af[mi], bf[ni], acc[mi][ni], 0, 0, 0);
  }

  if constexpr (EPI == 0) {
    unsigned short* C = p.C + (long)bz * p.sCb;
#pragma unroll
    for (int mi = 0; mi < 4; ++mi) {
#pragma unroll
      for (int ni = 0; ni < 4; ++ni) {
        const int col = n0 + wn * 64 + ni * 16 + l16;
#pragma unroll
        for (int r4 = 0; r4 < 4; ++r4) {
          const int row = m0 + wm * 64 + mi * 16 + g * 4 + r4;
          C[(long)row * p.ldc + col] = f2b(acc[mi][ni][r4]);
        }
      }
    }
  } else if constexpr (EPI == 1) {   // fp32 partial, slab per (b,ks)=bz
    float* C = p.Cp + (long)bz * p.sCb;
#pragma unroll
    for (int mi = 0; mi < 4; ++mi) {
#pragma unroll
      for (int ni = 0; ni < 4; ++ni) {
        const int col = n0 + wn * 64 + ni * 16 + l16;
#pragma unroll
        for (int r4 = 0; r4 < 4; ++r4) {
          const int row = m0 + wm * 64 + mi * 16 + g * 4 + r4;
          C[(long)row * p.ldc + col] = acc[mi][ni][r4];
        }
      }
    }
  } else if constexpr (EPI == 2) {   // QKV lo scatter: co in [0,3072), pix in [0,1024)
    const int b = bz >> 2, t = bz & 3;
#pragma unroll
    for (int mi = 0; mi < 4; ++mi) {
#pragma unroll
      for (int r4 = 0; r4 < 4; ++r4) {
        const int co = m0 + wm * 64 + mi * 16 + g * 4 + r4;
        const int sel = co >> 10;
        const int ch = co & 1023;
        const float bv = p.bias[co];
#pragma unroll
        for (int ni = 0; ni < 4; ++ni) {
          const int pix = n0 + wn * 64 + ni * 16 + l16;
          const int y = pix >> 5, x = pix & 31;
          float v = acc[mi][ni][r4] + bv;
          if (ch < 512) {                       // cfg0: 4x4 patches, d=8192
            if (sel == 0) v *= 0.011048543456039806f;   // 1/sqrt(8192)
            const int nseq = (t * 8 + (y >> 2)) * 8 + (x >> 2);
            const int f = (ch * 4 + (y & 3)) * 4 + (x & 3);
            const unsigned short hv = f2b(v);
            if (sel == 0)      p.Q0[((long)(b * 512 + nseq)) * 8192 + f] = hv;
            else if (sel == 1) p.K0[((long)(b * 512 + nseq)) * 8192 + f] = hv;
            else               p.V0t[((long)(b * 8192 + f)) * 512 + nseq] = hv;
          } else {                              // cfg1: 2x2 patches, d=2048
            if (sel == 0) v *= 0.02209708691207961f;    // 1/sqrt(2048)
            const int c2 = ch - 512;
            const int nseq = (t * 16 + (y >> 1)) * 16 + (x >> 1);
            const int f = (c2 * 2 + (y & 1)) * 2 + (x & 1);
            const unsigned short hv = f2b(v);
            if (sel == 0)      p.Q1[((long)(b * 2048 + nseq)) * 2048 + f] = hv;
            else if (sel == 1) p.K1[((long)(b * 2048 + nseq)) * 2048 + f] = hv;
            else               p.V1t[((long)(b * 2048 + f)) * 2048 + nseq] = hv;
          }
        }
      }
    }
  } else if constexpr (EPI == 3) {   // QKV hi scatter: co in [0,768), pix in [0,4096)
    const int b = bz >> 2, t = bz & 3;
#pragma unroll
    for (int mi = 0; mi < 4; ++mi) {
#pragma unroll
      for (int r4 = 0; r4 < 4; ++r4) {
        const int co = m0 + wm * 64 + mi * 16 + g * 4 + r4;
        const int sel = co >> 8;
        const int ch = co & 255;
        const float bv = p.bias[co];
#pragma unroll
        for (int ni = 0; ni < 4; ++ni) {
          const int pix = n0 + wn * 64 + ni * 16 + l16;
          const int y = pix >> 6, x = pix & 63;
          float v = acc[mi][ni][r4] + bv;
          if (ch < 128) {                       // cfg0: 8x8 patches
            if (sel == 0) v *= 0.011048543456039806f;
            const int nseq = 256 + (t * 8 + (y >> 3)) * 8 + (x >> 3);
            const int f = (ch * 8 + (y & 7)) * 8 + (x & 7);
            const unsigned short hv = f2b(v);
            if (sel == 0)      p.Q0[((long)(b * 512 + nseq)) * 8192 + f] = hv;
            else if (sel == 1) p.K0[((long)(b * 512 + nseq)) * 8192 + f] = hv;
            else               p.V0t[((long)(b * 8192 + f)) * 512 + nseq] = hv;
          } else {                              // cfg1: 4x4 patches
            if (sel == 0) v *= 0.02209708691207961f;
            const int c2 = ch - 128;
            const int nseq = 1024 + (t * 16 + (y >> 2)) * 16 + (x >> 2);
            const int f = (c2 * 4 + (y & 3)) * 4 + (x & 3);
            const unsigned short hv = f2b(v);
            if (sel == 0)      p.Q1[((long)(b * 2048 + nseq)) * 2048 + f] = hv;
            else if (sel == 1) p.K1[((long)(b * 2048 + nseq)) * 2048 + f] = hv;
            else               p.V1t[((long)(b * 2048 + f)) * 2048 + nseq] = hv;
          }
        }
      }
    }
  }
}

// ---------------------------------------------------------------------------
// Row softmax in-place on bf16 rows of length L. One wave per row.
// ---------------------------------------------------------------------------
template<int L>
__global__ __launch_bounds__(256) void softmax_rows(unsigned short* S) {
  const int w = threadIdx.x >> 6, lane = threadIdx.x & 63;
  const long row = (long)blockIdx.x * 4 + w;
  unsigned short* R = S + row * L;
  constexpr int NC = L / 64;
  float v[NC];
  float m = -1e30f;
#pragma unroll
  for (int i = 0; i < NC; ++i) { v[i] = b2f(R[i * 64 + lane]); m = fmaxf(m, v[i]); }
#pragma unroll
  for (int off = 32; off; off >>= 1) m = fmaxf(m, __shfl_xor(m, off, 64));
  float s = 0.f;
#pragma unroll
  for (int i = 0; i < NC; ++i) { v[i] = __expf(v[i] - m); s += v[i]; }
#pragma unroll
  for (int off = 32; off; off >>= 1) s += __shfl_xor(s, off, 64);
  const float inv = 1.0f / s;
#pragma unroll
  for (int i = 0; i < NC; ++i) R[i * 64 + lane] = f2b(v[i] * inv);
}

// ---------------------------------------------------------------------------
// S0: sum 8 fp32 split-K slabs [b*8+ks][512][512] -> softmax -> bf16 [b][512][512]
// ---------------------------------------------------------------------------
__global__ __launch_bounds__(256) void softmax_red8(const float* __restrict__ P,
                                                    unsigned short* __restrict__ S) {
  const int w = threadIdx.x >> 6, lane = threadIdx.x & 63;
  const int rowg = blockIdx.x * 4 + w;            // 0..2047
  const int b = rowg >> 9, n = rowg & 511;
  const float* base = P + ((long)b * 8) * 262144 + (long)n * 512 + lane;
  float v[8];
#pragma unroll
  for (int i = 0; i < 8; ++i) {
    float s = 0.f;
#pragma unroll
    for (int ks = 0; ks < 8; ++ks) s += base[(long)ks * 262144 + i * 64];
    v[i] = s;
  }
  float m = -1e30f;
#pragma unroll
  for (int i = 0; i < 8; ++i) m = fmaxf(m, v[i]);
#pragma unroll
  for (int off = 32; off; off >>= 1) m = fmaxf(m, __shfl_xor(m, off, 64));
  float s = 0.f;
#pragma unroll
  for (int i = 0; i < 8; ++i) { v[i] = __expf(v[i] - m); s += v[i]; }
#pragma unroll
  for (int off = 32; off; off >>= 1) s += __shfl_xor(s, off, 64);
  const float inv = 1.0f / s;
  unsigned short* R = S + (long)rowg * 512;
#pragma unroll
  for (int i = 0; i < 8; ++i) R[i * 64 + lane] = f2b(v[i] * inv);
}

// ---------------------------------------------------------------------------
// x [16][256][NPIX] fp32 (NCHW) -> xt [16][NPIX][256] bf16 (pixel-major)
// ---------------------------------------------------------------------------
__global__ __launch_bounds__(256) void xt_kernel(const float* __restrict__ x,
                                                 unsigned short* __restrict__ xt, int NPIX) {
  __shared__ unsigned short tile[64 * 65];
  const int tid = threadIdx.x;
  const int bt = blockIdx.z, ch0 = blockIdx.y * 64;
  const long pix0 = (long)blockIdx.x * 64;
  const float* src = x + ((long)bt * 256 + ch0) * NPIX + pix0;
#pragma unroll
  for (int i = 0; i < 16; ++i) {
    const int lin = i * 256 + tid;
    const int ch = lin >> 6, px = lin & 63;
    tile[ch * 65 + px] = f2b(src[(long)ch * NPIX + px]);
  }
  __syncthreads();
  unsigned short* dst = xt + ((long)bt * NPIX + pix0) * 256 + ch0;
#pragma unroll
  for (int i = 0; i < 16; ++i) {
    const int lin = i * 256 + tid;
    const int px = lin >> 6, ch = lin & 63;
    dst[(long)px * 256 + ch] = tile[ch * 65 + px];
  }
}

// ---------------------------------------------------------------------------
// Weight prep
// ---------------------------------------------------------------------------
__global__ void prep_qkv_w(const float* wq, const float* wk, const float* wv,
                           const float* bq, const float* bk, const float* bv,
                           unsigned short* Wcat, float* Bcat, int CO) {
  const int idx = blockIdx.x * 256 + threadIdx.x;
  const int n = 3 * CO * 256;
  if (idx < n) {
    const int sel = idx / (CO * 256);
    const int r = idx - sel * CO * 256;
    const float* wsel = sel == 0 ? wq : (sel == 1 ? wk : wv);
    Wcat[idx] = f2b(wsel[r]);
  }
  if (idx < 3 * CO) {
    const int sel = idx / CO;
    const int r = idx - sel * CO;
    const float* bsel = sel == 0 ? bq : (sel == 1 ? bk : bv);
    Bcat[idx] = bsel[r];
  }
}

__global__ void prep_conv_w(const float* wo, unsigned short* Wt, int CIN) {
  const int idx = blockIdx.x * 256 + threadIdx.x;
  const int n = 9 * 256 * CIN;
  if (idx < n) {
    const int t9 = idx / (256 * CIN);
    const int rem = idx - t9 * 256 * CIN;
    const int o = rem / CIN, i = rem - o * CIN;
    Wt[idx] = f2b(wo[((long)o * CIN + i) * 9 + t9]);   // [9][256][CIN]
  }
}

// ---------------------------------------------------------------------------
// Zero the 1-px halo border of a padded NHWC buffer [16][HP][WP][C]
// ---------------------------------------------------------------------------
__global__ __launch_bounds__(256) void zero_border(unsigned short* buf, int HP, int WP, int C) {
  const long i = (long)blockIdx.x * 256 + threadIdx.x;   // short8 units
  const int per_px = C >> 3;
  const int strip = 2 * WP + 2 * (HP - 2);
  const long tot = (long)16 * strip * per_px;
  if (i >= tot) return;
  const int c8 = (int)(i % per_px);
  const long r = i / per_px;
  const int s = (int)(r % strip);
  const int bt = (int)(r / strip);
  int y, x;
  if (s < WP) { y = 0; x = s; }
  else if (s < 2 * WP) { y = HP - 1; x = s - WP; }
  else if (s < 2 * WP + (HP - 2)) { y = s - 2 * WP + 1; x = 0; }
  else { y = s - 2 * WP - (HP - 2) + 1; x = WP - 1; }
  const short8 z = {0, 0, 0, 0, 0, 0, 0, 0};
  *(short8*)(buf + (((long)bt * HP + y) * WP + x) * C + c8 * 8) = z;
}

// ---------------------------------------------------------------------------
// Repack attention outputs Y (patch-major) -> padded NHWC conv inputs
// ---------------------------------------------------------------------------
__global__ __launch_bounds__(256) void repack_lo(const unsigned short* __restrict__ Y0,
                                                 const unsigned short* __restrict__ Y1,
                                                 unsigned short* __restrict__ out) {
  const int tid = threadIdx.x;
  const int blk = blockIdx.x;
  if (blk < 1024) {          // cfg0: 16px x 512ch per row
    const int b = blk >> 8, n = blk & 255;
    const int t = n >> 6, oh = (n >> 3) & 7, ow = n & 7;
    const unsigned short* row = Y0 + ((long)(b * 512 + n)) * 8192;
    const int bt = b * 4 + t;
#pragma unroll
    for (int j = 0; j < 32; ++j) {
      const int idx = j * 256 + tid;
      const int pp = idx >> 9, ch = idx & 511;
      const int py = pp >> 2, px = pp & 3;
      out[(((long)bt * 34 + oh * 4 + py + 1) * 34 + ow * 4 + px + 1) * 1024 + ch] = row[ch * 16 + pp];
    }
  } else {                   // cfg1: 4px x 512ch per row
    const int q = blk - 1024;
    const int b = q >> 10, n = q & 1023;
    const int t = n >> 8, oh = (n >> 4) & 15, ow = n & 15;
    const unsigned short* row = Y1 + ((long)(b * 2048 + n)) * 2048;
    const int bt = b * 4 + t;
#pragma unroll
    for (int j = 0; j < 8; ++j) {
      const int idx = j * 256 + tid;
      const int pp = idx >> 9, ch = idx & 511;
      const int py = pp >> 1, px = pp & 1;
      out[(((long)bt * 34 + oh * 2 + py + 1) * 34 + ow * 2 + px + 1) * 1024 + 512 + ch] = row[ch * 4 + pp];
    }
  }
}

__global__ __launch_bounds__(256) void repack_hi(const unsigned short* __restrict__ Y0,
                                                 const unsigned short* __restrict__ Y1,
                                                 unsigned short* __restrict__ out) {
  const int tid = threadIdx.x;
  const int blk = blockIdx.x;
  if (blk < 1024) {          // cfg0: 64px x 128ch per row
    const int b = blk >> 8, n = blk & 255;
    const int t = n >> 6, oh = (n >> 3) & 7, ow = n & 7;
    const unsigned short* row = Y0 + ((long)(b * 512 + 256 + n)) * 8192;
    const int bt = b * 4 + t;
#pragma unroll
    for (int j = 0; j < 32; ++j) {
      const int idx = j * 256 + tid;
      const int pp = idx >> 7, ch = idx & 127;
      const int py = pp >> 3, px = pp & 7;
      out[(((long)bt * 66 + oh * 8 + py + 1) * 66 + ow * 8 + px + 1) * 256 + ch] = row[ch * 64 + pp];
    }
  } else {                   // cfg1: 16px x 128ch per row
    const int q = blk - 1024;
    const int b = q >> 10, n = q & 1023;
    const int t = n >> 8, oh = (n >> 4) & 15, ow = n & 15;
    const unsigned short* row = Y1 + ((long)(b * 2048 + 1024 + n)) * 2048;
    const int bt = b * 4 + t;
#pragma unroll
    for (int j = 0; j < 8; ++j) {
      const int idx = j * 256 + tid;
      const int pp = idx >> 7, ch = idx & 127;
      const int py = pp >> 2, px = pp & 3;
      out[(((long)bt * 66 + oh * 4 + py + 1) * 66 + ow * 4 + px + 1) * 256 + 128 + ch] = row[ch * 16 + pp];
    }
  }
}

// ---------------------------------------------------------------------------
// 3x3 conv as im2col GEMM. Input: padded NHWC [16][H+2][W+2][CIN] bf16.
// Weights [9][256][CIN] bf16. K = 9*CIN/KS per block, tap-major; both operands
// staged via global_load_lds, 2-barrier K-loop (m97 structure), 16 KB LDS.
// PARTIAL=false: bias + leaky-relu + NCHW fp32 store. true: fp32 partials.
// ---------------------------------------------------------------------------
template<int H, int W, int CIN, int KS, bool PARTIAL>
__global__ __launch_bounds__(256) void conv_gemm(const unsigned short* __restrict__ Cinp,
                                                 const unsigned short* __restrict__ Wt,
                                                 const float* __restrict__ bias,
                                                 float* __restrict__ out,
                                                 float* __restrict__ P0,
                                                 float* __restrict__ P1) {
  constexpr int HP = H + 2, WP = W + 2;
  constexpr int CC = CIN / KS;           // channels per split-K slab
  __shared__ __align__(16) unsigned short As[128 * 32];
  __shared__ __align__(16) unsigned short Bs[128 * 32];
  const int tid = threadIdx.x;
  const int w = tid >> 6, lane = tid & 63;
  const int wm = w >> 1, wn = w & 1;
  const int g = lane >> 4, l16 = lane & 15;
  const int bz = blockIdx.z;
  const int bt = bz / KS, ks = bz % KS;
  const int m0 = blockIdx.y * 128;
  const int y0 = blockIdx.x * (128 / W);
  const int srow = tid >> 2;
  const int sc8 = (tid & 3) * 8;

  floatx4 acc[4][4];
  const floatx4 z4 = {0.f, 0.f, 0.f, 0.f};
#pragma unroll
  for (int i = 0; i < 4; ++i)
#pragma unroll
    for (int j = 0; j < 4; ++j) acc[i][j] = z4;

  const unsigned short* Cb = Cinp + (long)bt * HP * WP * CIN + ks * CC;

#pragma unroll 1
  for (int t9 = 0; t9 < 9; ++t9) {
    const int ky = t9 / 3, kx = t9 % 3;
    const unsigned short* Wr = Wt + ((long)t9 * 256 + m0) * CIN + ks * CC;
#pragma unroll 1
    for (int c0 = 0; c0 < CC; c0 += 32) {
      __syncthreads();
#pragma unroll
      for (int r = 0; r < 2; ++r) {
        const int row = r * 64 + srow;
        const unsigned short* ga = Wr + (long)row * CIN + c0 + sc8;
        __builtin_amdgcn_global_load_lds(
            (const __attribute__((address_space(1))) void*)ga,
            (__attribute__((address_space(3))) void*)(As + (r * 4 + w) * 512), 16, 0, 0);
        const int py = row / W, px = row % W;
        const unsigned short* gb = Cb + (((long)(y0 + py + ky)) * WP + px + kx) * CIN + c0 + sc8;
        __builtin_amdgcn_global_load_lds(
            (const __attribute__((address_space(1))) void*)gb,
            (__attribute__((address_space(3))) void*)(Bs + (r * 4 + w) * 512), 16, 0, 0);
      }
      __syncthreads();
      short8 af[4], bf[4];
#pragma unroll
      for (int mi = 0; mi < 4; ++mi)
        af[mi] = *(const short8*)(As + (wm * 64 + mi * 16 + l16) * 32 + g * 8);
#pragma unroll
      for (int ni = 0; ni < 4; ++ni)
        bf[ni] = *(const short8*)(Bs + (wn * 64 + ni * 16 + l16) * 32 + g * 8);
#pragma unroll
      for (int mi = 0; mi < 4; ++mi)
#pragma unroll
        for (int ni = 0; ni < 4; ++ni)
          acc[mi][ni] = __builtin_amdgcn_mfma_f32_16x16x32_bf16(af[mi], bf[ni], acc[mi][ni], 0, 0, 0);
    }
  }

  if constexpr (!PARTIAL) {
#pragma unroll
    for (int mi = 0; mi < 4; ++mi) {
#pragma unroll
      for (int ni = 0; ni < 4; ++ni) {
        const int pn = wn * 64 + ni * 16 + l16;
        const int y = y0 + pn / W, x = pn % W;
#pragma unroll
        for (int r4 = 0; r4 < 4; ++r4) {
          const int co = m0 + wm * 64 + mi * 16 + g * 4 + r4;
          float v = acc[mi][ni][r4] + bias[co];
          v = v > 0.f ? v : 0.2f * v;
          out[(((long)bt * 256 + co) * H + y) * W + x] = v;
        }
      }
    }
  } else {
    float* pout = (ks < 2 ? P0 : P1) + (long)(ks & 1) * (16L * 256 * H * W);
#pragma unroll
    for (int mi = 0; mi < 4; ++mi) {
#pragma unroll
      for (int ni = 0; ni < 4; ++ni) {
        const int pn = wn * 64 + ni * 16 + l16;
        const int y = y0 + pn / W, x = pn % W;
#pragma unroll
        for (int r4 = 0; r4 < 4; ++r4) {
          const int co = m0 + wm * 64 + mi * 16 + g * 4 + r4;
          pout[(((long)bt * 256 + co) * H + y) * W + x] = acc[mi][ni][r4];
        }
      }
    }
  }
}

// ---------------------------------------------------------------------------
// Sum 4 conv partial slabs (2 in P0, 2 in P1) + bias + leaky-relu -> out
// ---------------------------------------------------------------------------
__global__ __launch_bounds__(256) void reduce_lrelu(const floatx4* __restrict__ P0,
                                                    const floatx4* __restrict__ P1,
                                                    const float* __restrict__ bias,
                                                    floatx4* __restrict__ out) {
  const long i = (long)blockIdx.x * 256 + threadIdx.x;  // float4 index; 1048576 total
  constexpr long SL = 1048576;
  floatx4 a = P0[i], b = P0[SL + i], c = P1[i], d = P1[SL + i];
  const int co = ((int)(i >> 8)) & 255;
  const float bv = bias[co];
  floatx4 r;
#pragma unroll
  for (int j = 0; j < 4; ++j) {
    float v = a[j] + b[j] + c[j] + d[j] + bv;
    r[j] = v > 0.f ? v : 0.2f * v;
  }
  out[i] = r;
}

// ---------------------------------------------------------------------------
extern "C" void kernel_launch(void* const* d_in, const int* in_sizes, int n_in,
                              void* d_out, int out_size, void* d_ws, size_t ws_size,
                              hipStream_t stream) {
  (void)in_sizes; (void)n_in; (void)out_size; (void)ws_size;
  const float* x_lo = (const float*)d_in[0];
  const float* x_hi = (const float*)d_in[1];
  const float* wq_lo = (const float*)d_in[3];
  const float* bq_lo = (const float*)d_in[4];
  const float* wk_lo = (const float*)d_in[5];
  const float* bk_lo = (const float*)d_in[6];
  const float* wv_lo = (const float*)d_in[7];
  const float* bv_lo = (const float*)d_in[8];
  const float* wq_hi = (const float*)d_in[9];
  const float* bq_hi = (const float*)d_in[10];
  const float* wk_hi = (const float*)d_in[11];
  const float* bk_hi = (const float*)d_in[12];
  const float* wv_hi = (const float*)d_in[13];
  const float* bv_hi = (const float*)d_in[14];
  const float* wo_lo = (const float*)d_in[15];
  const float* bo_lo = (const float*)d_in[16];
  const float* wo_hi = (const float*)d_in[17];
  const float* bo_hi = (const float*)d_in[18];
  float* out = (float*)d_out;

  char* ws = (char*)d_ws;
  const long B0 = 33554432;  // 33.5 MB per region
  unsigned short* Qp0 = (unsigned short*)(ws);            // later: Y0, then conv partials P0
  unsigned short* Kp0 = (unsigned short*)(ws + B0);       // later: S1, then CinP_lo (spills into V0t)
  unsigned short* V0t = (unsigned short*)(ws + 2 * B0);
  unsigned short* Qp1 = (unsigned short*)(ws + 3 * B0);   // later: Y1, then conv partials P1
  unsigned short* Kp1 = (unsigned short*)(ws + 4 * B0);   // later: CinP_hi (spills into V1t)
  unsigned short* V1t = (unsigned short*)(ws + 5 * B0);
  char* ptr = ws + 6 * B0;
  unsigned short* S0 = (unsigned short*)ptr;     ptr += 2097152;
  unsigned short* Xt_lo = (unsigned short*)ptr;  ptr += 8388608;
  unsigned short* Xt_hi = (unsigned short*)ptr;  ptr += 33554432;   // later: S0 fp32 partials
  unsigned short* Wcat_lo = (unsigned short*)ptr; ptr += 1572864;
  unsigned short* Wcat_hi = (unsigned short*)ptr; ptr += 393216;
  float* Bcat_lo = (float*)ptr;                  ptr += 12288;
  float* Bcat_hi = (float*)ptr;                  ptr += 3072;
  unsigned short* Wt_lo = (unsigned short*)ptr;  ptr += 4718592;
  unsigned short* Wt_hi = (unsigned short*)ptr;  ptr += 1179648;
  unsigned short* S1 = Kp0;
  unsigned short* Y0 = Qp0;
  unsigned short* Y1 = Qp1;
  unsigned short* CinP_lo = Kp0;    // [16][34][34][1024] bf16 = 37.9 MB (uses V0t tail; dead)
  unsigned short* CinP_hi = Kp1;    // [16][66][66][256]  bf16 = 35.7 MB (uses V1t tail; dead)
  float* S0p = (float*)Xt_hi;       // 32 slabs x 262144 floats = 33.5 MB
  float* PC0 = (float*)Qp0;         // conv_lo partial slabs 0,1 (Y0 dead by then)
  float* PC1 = (float*)Qp1;         // conv_lo partial slabs 2,3 (Y1 dead by then)

  // --- weight/input prep ---
  prep_qkv_w<<<(3 * 1024 * 256 + 255) / 256, 256, 0, stream>>>(
      wq_lo, wk_lo, wv_lo, bq_lo, bk_lo, bv_lo, Wcat_lo, Bcat_lo, 1024);
  prep_qkv_w<<<(3 * 256 * 256 + 255) / 256, 256, 0, stream>>>(
      wq_hi, wk_hi, wv_hi, bq_hi, bk_hi, bv_hi, Wcat_hi, Bcat_hi, 256);
  prep_conv_w<<<(9 * 256 * 1024 + 255) / 256, 256, 0, stream>>>(wo_lo, Wt_lo, 1024);
  prep_conv_w<<<(9 * 256 * 256 + 255) / 256, 256, 0, stream>>>(wo_hi, Wt_hi, 256);
  xt_kernel<<<dim3(16, 4, 16), 256, 0, stream>>>(x_lo, Xt_lo, 1024);
  xt_kernel<<<dim3(64, 4, 16), 256, 0, stream>>>(x_hi, Xt_hi, 4096);

  // --- QKV projections (1x1 conv as TN-GEMM), scattered to patch layout ---
  {
    GemmP p{};
    p.A = Wcat_lo; p.B = Xt_lo; p.sAb = 0; p.sBb = 1024L * 256;
    p.lda = 256; p.ldb = 256; p.K = 256;
    p.bias = Bcat_lo;
    p.Q0 = Qp0; p.K0 = Kp0; p.V0t = V0t; p.Q1 = Qp1; p.K1 = Kp1; p.V1t = V1t;
    gemm_tn<2><<<dim3(8, 24, 16), 256, 0, stream>>>(p);
    p.A = Wcat_hi; p.B = Xt_hi; p.sBb = 4096L * 256; p.bias = Bcat_hi;
    gemm_tn<3><<<dim3(32, 6, 16), 256, 0, stream>>>(p);
  }

  // --- attention cfg0: n=512, d=8192 (split-K 8 + fused reduce softmax) ---
  {
    GemmP s{};
    s.A = Qp0; s.B = Kp0; s.sAb = 512L * 8192; s.sBb = 512L * 8192;
    s.lda = 8192; s.ldb = 8192; s.K = 8192;
    s.Cp = S0p; s.sCb = 512L * 512; s.ldc = 512;
    gemm_tn<1><<<dim3(4, 4, 32), 256, 0, stream>>>(s);
    softmax_red8<<<512, 256, 0, stream>>>(S0p, S0);
    GemmP pv{};
    pv.A = S0; pv.B = V0t; pv.sAb = 512L * 512; pv.sBb = 8192L * 512;
    pv.lda = 512; pv.ldb = 512; pv.K = 512;
    pv.C = Y0; pv.sCb = 512L * 8192; pv.ldc = 8192;
    gemm_tn<0><<<dim3(64, 4, 4), 256, 0, stream>>>(pv);
  }

  // --- attention cfg1: n=2048, d=2048 ---
  {
    GemmP s{};
    s.A = Qp1; s.B = Kp1; s.sAb = 2048L * 2048; s.sBb = 2048L * 2048;
    s.lda = 2048; s.ldb = 2048; s.K = 2048;
    s.C = S1; s.sCb = 2048L * 2048; s.ldc = 2048;
    gemm_tn<0><<<dim3(16, 16, 4), 256, 0, stream>>>(s);
    softmax_rows<2048><<<2048, 256, 0, stream>>>(S1);
    GemmP pv{};
    pv.A = S1; pv.B = V1t; pv.sAb = 2048L * 2048; pv.sBb = 2048L * 2048;
    pv.lda = 2048; pv.ldb = 2048; pv.K = 2048;
    pv.C = Y1; pv.sCb = 2048L * 2048; pv.ldc = 2048;
    gemm_tn<0><<<dim3(16, 16, 4), 256, 0, stream>>>(pv);
  }

  // --- halo zeroing + from_patches repack into padded NHWC conv inputs ---
  zero_border<<<1056, 256, 0, stream>>>(CinP_lo, 34, 34, 1024);
  zero_border<<<520, 256, 0, stream>>>(CinP_hi, 66, 66, 256);
  repack_lo<<<5120, 256, 0, stream>>>(Y0, Y1, CinP_lo);
  repack_hi<<<5120, 256, 0, stream>>>(Y0, Y1, CinP_hi);

  // --- 3x3 convs as im2col GEMM + bias + leaky relu -> fp32 outputs ---
  conv_gemm<32, 32, 1024, 4, true><<<dim3(8, 2, 64), 256, 0, stream>>>(
      CinP_lo, Wt_lo, bo_lo, out, PC0, PC1);
  reduce_lrelu<<<4096, 256, 0, stream>>>((const floatx4*)PC0, (const floatx4*)PC1, bo_lo,
                                         (floatx4*)out);
  conv_gemm<64, 64, 256, 1, false><<<dim3(32, 2, 16), 256, 0, stream>>>(
      CinP_hi, Wt_hi, bo_hi, out + 4194304, nullptr, nullptr);
}

// Round 4
// 744.319 us; speedup vs baseline: 1.4742x; 1.1703x over previous
//
#include <hip/hip_runtime.h>
#include <hip/hip_bf16.h>
#include <stdint.h>

typedef __attribute__((ext_vector_type(8))) short short8;
typedef __attribute__((ext_vector_type(4))) float floatx4;

__device__ __forceinline__ unsigned short f2b(float f) {
  unsigned u = __builtin_bit_cast(unsigned, f);
  unsigned r = u + 0x7fffu + ((u >> 16) & 1u);
  return (unsigned short)(r >> 16);
}
__device__ __forceinline__ float b2f(unsigned short h) {
  unsigned u = ((unsigned)h) << 16;
  return __builtin_bit_cast(float, u);
}
__device__ __forceinline__ void glds16(const unsigned short* src, unsigned short* dst) {
  __builtin_amdgcn_global_load_lds((const __attribute__((address_space(1))) void*)src,
                                   (__attribute__((address_space(3))) void*)dst, 16, 0, 0);
}

// ---------------------------------------------------------------------------
// 256x256-tile TN GEMM: C[M,N] = A[M,K]*B[N,K]^T, bf16 in, fp32 accum.
// 512 threads = 8 waves (2M x 4N); per-wave output 128x64 (acc[8][4]).
// BK=32; 4-buffer LDS ring (128 KiB); counted vmcnt(8) (3 K-tiles in flight);
// raw s_barrier + sched_barrier(0); setprio around MFMA clusters; XOR swizzle
// (chunk ^= row&3) applied on pre-swizzled global source AND ds_read address.
// Phase P0: read B(4)+A-half0(4), stage (t+3).A;  P1: read A-half1(4), stage (t+3).B.
// EPI 0: bf16 C. EPI 1: split-K(8) fp32 partials. EPI 2/3: QKV scatter.
// ---------------------------------------------------------------------------
struct GemmP {
  const unsigned short* A;
  const unsigned short* B;
  long sAb, sBb;
  int lda, ldb, K;
  unsigned short* C; long sCb; int ldc;   // EPI 0
  float* Cp;                              // EPI 1
  const float* bias;                      // EPI 2/3
  unsigned short *Q0, *K0, *V0t, *Q1, *K1, *V1t;
};

template<int EPI>
__global__ __launch_bounds__(512) void gemm256(GemmP p) {
  __shared__ __align__(16) unsigned short LDS[65536];
  const int tid = threadIdx.x;
  const int wv = tid >> 6, lane = tid & 63;
  const int wm = wv >> 2, wn = wv & 3;
  const int g = lane >> 4, l16 = lane & 15;
  const int bz = blockIdx.z;
  const int m0 = blockIdx.y * 256, n0 = blockIdx.x * 256;

  int bb = bz, koff = 0, Keff = p.K;
  if constexpr (EPI == 1) { bb = bz >> 3; koff = (bz & 7) * (p.K >> 3); Keff = p.K >> 3; }
  const unsigned short* Ab = p.A + (long)bb * p.sAb + (long)m0 * p.lda + koff;
  const unsigned short* Bb = p.B + (long)bb * p.sBb + (long)n0 * p.ldb + koff;
  const int NT = Keff >> 5;

  // staging: thread covers rows r0 and r0+128; 16B chunk cs = (tid&3) ^ (r0&3)
  const int r0 = tid >> 2;
  const int cs = (tid & 3) ^ (r0 & 3);
  const unsigned short* aS0 = Ab + (long)r0 * p.lda + cs * 8;
  const unsigned short* aS1 = aS0 + (long)128 * p.lda;
  const unsigned short* bS0 = Bb + (long)r0 * p.ldb + cs * 8;
  const unsigned short* bS1 = bS0 + (long)128 * p.ldb;
  unsigned short* const lds0 = (unsigned short*)LDS;
  const int wbase = wv * 512;   // wave-uniform LDS dest (shorts)

  auto STAGE_A = [&](int t) {
    unsigned short* d = lds0 + (t & 3) * 16384;
    const long ko = (long)t * 32;
    glds16(aS0 + ko, d + wbase);
    glds16(aS1 + ko, d + 4096 + wbase);
  };
  auto STAGE_B = [&](int t) {
    unsigned short* d = lds0 + (t & 3) * 16384 + 8192;
    const long ko = (long)t * 32;
    glds16(bS0 + ko, d + wbase);
    glds16(bS1 + ko, d + 4096 + wbase);
  };

  STAGE_A(0); STAGE_B(0); STAGE_A(1); STAGE_B(1); STAGE_A(2); STAGE_B(2);

  floatx4 acc[8][4];
  const floatx4 z4 = {0.f, 0.f, 0.f, 0.f};
#pragma unroll
  for (int i = 0; i < 8; ++i)
#pragma unroll
    for (int j = 0; j < 4; ++j) acc[i][j] = z4;

  const int loff = l16 * 32 + ((g ^ (l16 & 3)) * 8);  // lane part of swizzled read addr
  const int aRowB = wm * 128;

  for (int t = 0; t < NT; ++t) {
    const unsigned short* As = lds0 + (t & 3) * 16384;
    const unsigned short* Bs = As + 8192;
    // ---- P0 ----
    asm volatile("s_waitcnt vmcnt(8)" ::: "memory");
    __builtin_amdgcn_s_barrier();
    __builtin_amdgcn_sched_barrier(0);
    if (t + 3 < NT) STAGE_A(t + 3);
    short8 bf[4], af[4];
#pragma unroll
    for (int ni = 0; ni < 4; ++ni)
      bf[ni] = *(const short8*)(Bs + (wn * 64 + ni * 16) * 32 + loff);
#pragma unroll
    for (int mi = 0; mi < 4; ++mi)
      af[mi] = *(const short8*)(As + (aRowB + mi * 16) * 32 + loff);
    __builtin_amdgcn_s_setprio(1);
#pragma unroll
    for (int mi = 0; mi < 4; ++mi)
#pragma unroll
      for (int ni = 0; ni < 4; ++ni)
        acc[mi][ni] = __builtin_amdgcn_mfma_f32_16x16x32_bf16(af[mi], bf[ni], acc[mi][ni], 0, 0, 0);
    __builtin_amdgcn_s_setprio(0);
    // ---- P1 ----
    __builtin_amdgcn_s_barrier();
    __builtin_amdgcn_sched_barrier(0);
    if (t + 3 < NT) STAGE_B(t + 3);
#pragma unroll
    for (int mi = 0; mi < 4; ++mi)
      af[mi] = *(const short8*)(As + (aRowB + 64 + mi * 16) * 32 + loff);
    __builtin_amdgcn_s_setprio(1);
#pragma unroll
    for (int mi = 0; mi < 4; ++mi)
#pragma unroll
      for (int ni = 0; ni < 4; ++ni)
        acc[4 + mi][ni] = __builtin_amdgcn_mfma_f32_16x16x32_bf16(af[mi], bf[ni], acc[4 + mi][ni], 0, 0, 0);
    __builtin_amdgcn_s_setprio(0);
  }

  if constexpr (EPI == 0) {
    unsigned short* C = p.C + (long)bz * p.sCb;
#pragma unroll
    for (int mi = 0; mi < 8; ++mi) {
#pragma unroll
      for (int ni = 0; ni < 4; ++ni) {
        const int col = n0 + wn * 64 + ni * 16 + l16;
#pragma unroll
        for (int r4 = 0; r4 < 4; ++r4) {
          const int row = m0 + wm * 128 + mi * 16 + g * 4 + r4;
          C[(long)row * p.ldc + col] = f2b(acc[mi][ni][r4]);
        }
      }
    }
  } else if constexpr (EPI == 1) {
    float* C = p.Cp + (long)bz * p.sCb;
#pragma unroll
    for (int mi = 0; mi < 8; ++mi) {
#pragma unroll
      for (int ni = 0; ni < 4; ++ni) {
        const int col = n0 + wn * 64 + ni * 16 + l16;
#pragma unroll
        for (int r4 = 0; r4 < 4; ++r4) {
          const int row = m0 + wm * 128 + mi * 16 + g * 4 + r4;
          C[(long)row * p.ldc + col] = acc[mi][ni][r4];
        }
      }
    }
  } else if constexpr (EPI == 2) {   // QKV lo scatter: co in [0,3072), pix in [0,1024)
    const int b = bz >> 2, tt = bz & 3;
#pragma unroll
    for (int mi = 0; mi < 8; ++mi) {
#pragma unroll
      for (int r4 = 0; r4 < 4; ++r4) {
        const int co = m0 + wm * 128 + mi * 16 + g * 4 + r4;
        const int sel = co >> 10;
        const int ch = co & 1023;
        const float bv = p.bias[co];
#pragma unroll
        for (int ni = 0; ni < 4; ++ni) {
          const int pix = n0 + wn * 64 + ni * 16 + l16;
          const int y = pix >> 5, x = pix & 31;
          float v = acc[mi][ni][r4] + bv;
          if (ch < 512) {                       // cfg0: 4x4 patches, d=8192
            if (sel == 0) v *= 0.011048543456039806f;   // 1/sqrt(8192)
            const int nseq = (tt * 8 + (y >> 2)) * 8 + (x >> 2);
            const int f = (ch * 4 + (y & 3)) * 4 + (x & 3);
            const unsigned short hv = f2b(v);
            if (sel == 0)      p.Q0[((long)(b * 512 + nseq)) * 8192 + f] = hv;
            else if (sel == 1) p.K0[((long)(b * 512 + nseq)) * 8192 + f] = hv;
            else               p.V0t[((long)(b * 8192 + f)) * 512 + nseq] = hv;
          } else {                              // cfg1: 2x2 patches, d=2048
            if (sel == 0) v *= 0.02209708691207961f;    // 1/sqrt(2048)
            const int c2 = ch - 512;
            const int nseq = (tt * 16 + (y >> 1)) * 16 + (x >> 1);
            const int f = (c2 * 2 + (y & 1)) * 2 + (x & 1);
            const unsigned short hv = f2b(v);
            if (sel == 0)      p.Q1[((long)(b * 2048 + nseq)) * 2048 + f] = hv;
            else if (sel == 1) p.K1[((long)(b * 2048 + nseq)) * 2048 + f] = hv;
            else               p.V1t[((long)(b * 2048 + f)) * 2048 + nseq] = hv;
          }
        }
      }
    }
  } else if constexpr (EPI == 3) {   // QKV hi scatter: co in [0,768), pix in [0,4096)
    const int b = bz >> 2, tt = bz & 3;
#pragma unroll
    for (int mi = 0; mi < 8; ++mi) {
#pragma unroll
      for (int r4 = 0; r4 < 4; ++r4) {
        const int co = m0 + wm * 128 + mi * 16 + g * 4 + r4;
        const int sel = co >> 8;
        const int ch = co & 255;
        const float bv = p.bias[co];
#pragma unroll
        for (int ni = 0; ni < 4; ++ni) {
          const int pix = n0 + wn * 64 + ni * 16 + l16;
          const int y = pix >> 6, x = pix & 63;
          float v = acc[mi][ni][r4] + bv;
          if (ch < 128) {                       // cfg0: 8x8 patches
            if (sel == 0) v *= 0.011048543456039806f;
            const int nseq = 256 + (tt * 8 + (y >> 3)) * 8 + (x >> 3);
            const int f = (ch * 8 + (y & 7)) * 8 + (x & 7);
            const unsigned short hv = f2b(v);
            if (sel == 0)      p.Q0[((long)(b * 512 + nseq)) * 8192 + f] = hv;
            else if (sel == 1) p.K0[((long)(b * 512 + nseq)) * 8192 + f] = hv;
            else               p.V0t[((long)(b * 8192 + f)) * 512 + nseq] = hv;
          } else {                              // cfg1: 4x4 patches
            if (sel == 0) v *= 0.02209708691207961f;
            const int c2 = ch - 128;
            const int nseq = 1024 + (tt * 16 + (y >> 2)) * 16 + (x >> 2);
            const int f = (c2 * 4 + (y & 3)) * 4 + (x & 3);
            const unsigned short hv = f2b(v);
            if (sel == 0)      p.Q1[((long)(b * 2048 + nseq)) * 2048 + f] = hv;
            else if (sel == 1) p.K1[((long)(b * 2048 + nseq)) * 2048 + f] = hv;
            else               p.V1t[((long)(b * 2048 + f)) * 2048 + nseq] = hv;
          }
        }
      }
    }
  }
}

// ---------------------------------------------------------------------------
// 3x3 conv as im2col GEMM on the 256-tile pipeline. M=256 (all co), N=256 px.
// K = 9*CC tap-major (CC = CIN/KS); padded NHWC input; same ring schedule.
// ---------------------------------------------------------------------------
template<int H, int W, int CIN, int KS, bool PARTIAL>
__global__ __launch_bounds__(512) void conv256(const unsigned short* __restrict__ Cinp,
                                               const unsigned short* __restrict__ Wt,
                                               const float* __restrict__ bias,
                                               float* __restrict__ out,
                                               float* __restrict__ P0,
                                               float* __restrict__ P1) {
  constexpr int HP = H + 2, WP = W + 2;
  constexpr int CC = CIN / KS;
  constexpr int NT = 9 * CC / 32;
  __shared__ __align__(16) unsigned short LDS[65536];
  const int tid = threadIdx.x;
  const int wv = tid >> 6, lane = tid & 63;
  const int wm = wv >> 2, wn = wv & 3;
  const int g = lane >> 4, l16 = lane & 15;
  const int bz = blockIdx.z;
  const int bt = bz / KS, ks = bz % KS;
  const int n0 = blockIdx.x * 256;

  const int r0 = tid >> 2;
  const int cs = (tid & 3) ^ (r0 & 3);
  const unsigned short* wA0 = Wt + (long)r0 * CIN + ks * CC + cs * 8;
  const unsigned short* wA1 = wA0 + (long)128 * CIN;
  const int p0 = n0 + r0, p1 = p0 + 128;
  const int y0p = p0 / W, x0p = p0 % W;
  const int y1p = p1 / W, x1p = p1 % W;
  const unsigned short* cB = Cinp + (long)bt * HP * WP * CIN + ks * CC + cs * 8;
  const unsigned short* pB0 = cB + ((long)y0p * WP + x0p) * CIN;
  const unsigned short* pB1 = cB + ((long)y1p * WP + x1p) * CIN;
  unsigned short* const lds0 = (unsigned short*)LDS;
  const int wbase = wv * 512;

  auto STAGE_A = [&](int t) {
    unsigned short* d = lds0 + (t & 3) * 16384;
    const int tap = t >> 3, tc = (t & 7) * 32;
    const long off = (long)tap * (256L * CIN) + tc;
    glds16(wA0 + off, d + wbase);
    glds16(wA1 + off, d + 4096 + wbase);
  };
  auto STAGE_B = [&](int t) {
    unsigned short* d = lds0 + (t & 3) * 16384 + 8192;
    const int tap = t >> 3, tc = (t & 7) * 32;
    const int ky = tap / 3, kx = tap - ky * 3;
    const long off = ((long)ky * WP + kx) * CIN + tc;
    glds16(pB0 + off, d + wbase);
    glds16(pB1 + off, d + 4096 + wbase);
  };

  STAGE_A(0); STAGE_B(0); STAGE_A(1); STAGE_B(1); STAGE_A(2); STAGE_B(2);

  floatx4 acc[8][4];
  const floatx4 z4 = {0.f, 0.f, 0.f, 0.f};
#pragma unroll
  for (int i = 0; i < 8; ++i)
#pragma unroll
    for (int j = 0; j < 4; ++j) acc[i][j] = z4;

  const int loff = l16 * 32 + ((g ^ (l16 & 3)) * 8);
  const int aRowB = wm * 128;

  for (int t = 0; t < NT; ++t) {
    const unsigned short* As = lds0 + (t & 3) * 16384;
    const unsigned short* Bs = As + 8192;
    asm volatile("s_waitcnt vmcnt(8)" ::: "memory");
    __builtin_amdgcn_s_barrier();
    __builtin_amdgcn_sched_barrier(0);
    if (t + 3 < NT) STAGE_A(t + 3);
    short8 bf[4], af[4];
#pragma unroll
    for (int ni = 0; ni < 4; ++ni)
      bf[ni] = *(const short8*)(Bs + (wn * 64 + ni * 16) * 32 + loff);
#pragma unroll
    for (int mi = 0; mi < 4; ++mi)
      af[mi] = *(const short8*)(As + (aRowB + mi * 16) * 32 + loff);
    __builtin_amdgcn_s_setprio(1);
#pragma unroll
    for (int mi = 0; mi < 4; ++mi)
#pragma unroll
      for (int ni = 0; ni < 4; ++ni)
        acc[mi][ni] = __builtin_amdgcn_mfma_f32_16x16x32_bf16(af[mi], bf[ni], acc[mi][ni], 0, 0, 0);
    __builtin_amdgcn_s_setprio(0);
    __builtin_amdgcn_s_barrier();
    __builtin_amdgcn_sched_barrier(0);
    if (t + 3 < NT) STAGE_B(t + 3);
#pragma unroll
    for (int mi = 0; mi < 4; ++mi)
      af[mi] = *(const short8*)(As + (aRowB + 64 + mi * 16) * 32 + loff);
    __builtin_amdgcn_s_setprio(1);
#pragma unroll
    for (int mi = 0; mi < 4; ++mi)
#pragma unroll
      for (int ni = 0; ni < 4; ++ni)
        acc[4 + mi][ni] = __builtin_amdgcn_mfma_f32_16x16x32_bf16(af[mi], bf[ni], acc[4 + mi][ni], 0, 0, 0);
    __builtin_amdgcn_s_setprio(0);
  }

  if constexpr (!PARTIAL) {
#pragma unroll
    for (int mi = 0; mi < 8; ++mi) {
#pragma unroll
      for (int ni = 0; ni < 4; ++ni) {
        const int pn = n0 + wn * 64 + ni * 16 + l16;
        const int y = pn / W, x = pn % W;
#pragma unroll
        for (int r4 = 0; r4 < 4; ++r4) {
          const int co = wm * 128 + mi * 16 + g * 4 + r4;
          float v = acc[mi][ni][r4] + bias[co];
          v = v > 0.f ? v : 0.2f * v;
          out[(((long)bt * 256 + co) * H + y) * W + x] = v;
        }
      }
    }
  } else {
    float* pout = (ks < 2 ? P0 : P1) + (long)(ks & 1) * (16L * 256 * H * W);
#pragma unroll
    for (int mi = 0; mi < 8; ++mi) {
#pragma unroll
      for (int ni = 0; ni < 4; ++ni) {
        const int pn = n0 + wn * 64 + ni * 16 + l16;
        const int y = pn / W, x = pn % W;
#pragma unroll
        for (int r4 = 0; r4 < 4; ++r4) {
          const int co = wm * 128 + mi * 16 + g * 4 + r4;
          pout[(((long)bt * 256 + co) * H + y) * W + x] = acc[mi][ni][r4];
        }
      }
    }
  }
}

// ---------------------------------------------------------------------------
// Row softmax in-place on bf16 rows of length L. One wave per row.
// ---------------------------------------------------------------------------
template<int L>
__global__ __launch_bounds__(256) void softmax_rows(unsigned short* S) {
  const int w = threadIdx.x >> 6, lane = threadIdx.x & 63;
  const long row = (long)blockIdx.x * 4 + w;
  unsigned short* R = S + row * L;
  constexpr int NC = L / 64;
  float v[NC];
  float m = -1e30f;
#pragma unroll
  for (int i = 0; i < NC; ++i) { v[i] = b2f(R[i * 64 + lane]); m = fmaxf(m, v[i]); }
#pragma unroll
  for (int off = 32; off; off >>= 1) m = fmaxf(m, __shfl_xor(m, off, 64));
  float s = 0.f;
#pragma unroll
  for (int i = 0; i < NC; ++i) { v[i] = __expf(v[i] - m); s += v[i]; }
#pragma unroll
  for (int off = 32; off; off >>= 1) s += __shfl_xor(s, off, 64);
  const float inv = 1.0f / s;
#pragma unroll
  for (int i = 0; i < NC; ++i) R[i * 64 + lane] = f2b(v[i] * inv);
}

// ---------------------------------------------------------------------------
// S0: sum 8 fp32 split-K slabs -> softmax -> bf16 [b][512][512]
// ---------------------------------------------------------------------------
__global__ __launch_bounds__(256) void softmax_red8(const float* __restrict__ P,
                                                    unsigned short* __restrict__ S) {
  const int w = threadIdx.x >> 6, lane = threadIdx.x & 63;
  const int rowg = blockIdx.x * 4 + w;
  const int b = rowg >> 9, n = rowg & 511;
  const float* base = P + ((long)b * 8) * 262144 + (long)n * 512 + lane;
  float v[8];
#pragma unroll
  for (int i = 0; i < 8; ++i) {
    float s = 0.f;
#pragma unroll
    for (int ks = 0; ks < 8; ++ks) s += base[(long)ks * 262144 + i * 64];
    v[i] = s;
  }
  float m = -1e30f;
#pragma unroll
  for (int i = 0; i < 8; ++i) m = fmaxf(m, v[i]);
#pragma unroll
  for (int off = 32; off; off >>= 1) m = fmaxf(m, __shfl_xor(m, off, 64));
  float s = 0.f;
#pragma unroll
  for (int i = 0; i < 8; ++i) { v[i] = __expf(v[i] - m); s += v[i]; }
#pragma unroll
  for (int off = 32; off; off >>= 1) s += __shfl_xor(s, off, 64);
  const float inv = 1.0f / s;
  unsigned short* R = S + (long)rowg * 512;
#pragma unroll
  for (int i = 0; i < 8; ++i) R[i * 64 + lane] = f2b(v[i] * inv);
}

// ---------------------------------------------------------------------------
// x [16][256][NPIX] fp32 (NCHW) -> xt [16][NPIX][256] bf16 (pixel-major)
// ---------------------------------------------------------------------------
__global__ __launch_bounds__(256) void xt_kernel(const float* __restrict__ x,
                                                 unsigned short* __restrict__ xt, int NPIX) {
  __shared__ unsigned short tile[64 * 65];
  const int tid = threadIdx.x;
  const int bt = blockIdx.z, ch0 = blockIdx.y * 64;
  const long pix0 = (long)blockIdx.x * 64;
  const float* src = x + ((long)bt * 256 + ch0) * NPIX + pix0;
#pragma unroll
  for (int i = 0; i < 16; ++i) {
    const int lin = i * 256 + tid;
    const int ch = lin >> 6, px = lin & 63;
    tile[ch * 65 + px] = f2b(src[(long)ch * NPIX + px]);
  }
  __syncthreads();
  unsigned short* dst = xt + ((long)bt * NPIX + pix0) * 256 + ch0;
#pragma unroll
  for (int i = 0; i < 16; ++i) {
    const int lin = i * 256 + tid;
    const int px = lin >> 6, ch = lin & 63;
    dst[(long)px * 256 + ch] = tile[ch * 65 + px];
  }
}

// ---------------------------------------------------------------------------
// Weight prep
// ---------------------------------------------------------------------------
__global__ void prep_qkv_w(const float* wq, const float* wk, const float* wv,
                           const float* bq, const float* bk, const float* bv,
                           unsigned short* Wcat, float* Bcat, int CO) {
  const int idx = blockIdx.x * 256 + threadIdx.x;
  const int n = 3 * CO * 256;
  if (idx < n) {
    const int sel = idx / (CO * 256);
    const int r = idx - sel * CO * 256;
    const float* wsel = sel == 0 ? wq : (sel == 1 ? wk : wv);
    Wcat[idx] = f2b(wsel[r]);
  }
  if (idx < 3 * CO) {
    const int sel = idx / CO;
    const int r = idx - sel * CO;
    const float* bsel = sel == 0 ? bq : (sel == 1 ? bk : bv);
    Bcat[idx] = bsel[r];
  }
}

__global__ void prep_conv_w(const float* wo, unsigned short* Wt, int CIN) {
  const int idx = blockIdx.x * 256 + threadIdx.x;
  const int n = 9 * 256 * CIN;
  if (idx < n) {
    const int t9 = idx / (256 * CIN);
    const int rem = idx - t9 * 256 * CIN;
    const int o = rem / CIN, i = rem - o * CIN;
    Wt[idx] = f2b(wo[((long)o * CIN + i) * 9 + t9]);   // [9][256][CIN]
  }
}

// ---------------------------------------------------------------------------
// Zero the 1-px halo border of a padded NHWC buffer [16][HP][WP][C]
// ---------------------------------------------------------------------------
__global__ __launch_bounds__(256) void zero_border(unsigned short* buf, int HP, int WP, int C) {
  const long i = (long)blockIdx.x * 256 + threadIdx.x;
  const int per_px = C >> 3;
  const int strip = 2 * WP + 2 * (HP - 2);
  const long tot = (long)16 * strip * per_px;
  if (i >= tot) return;
  const int c8 = (int)(i % per_px);
  const long r = i / per_px;
  const int s = (int)(r % strip);
  const int bt = (int)(r / strip);
  int y, x;
  if (s < WP) { y = 0; x = s; }
  else if (s < 2 * WP) { y = HP - 1; x = s - WP; }
  else if (s < 2 * WP + (HP - 2)) { y = s - 2 * WP + 1; x = 0; }
  else { y = s - 2 * WP - (HP - 2) + 1; x = WP - 1; }
  const short8 z = {0, 0, 0, 0, 0, 0, 0, 0};
  *(short8*)(buf + (((long)bt * HP + y) * WP + x) * C + c8 * 8) = z;
}

// ---------------------------------------------------------------------------
// Repack attention outputs Y (patch-major) -> padded NHWC conv inputs
// ---------------------------------------------------------------------------
__global__ __launch_bounds__(256) void repack_lo(const unsigned short* __restrict__ Y0,
                                                 const unsigned short* __restrict__ Y1,
                                                 unsigned short* __restrict__ out) {
  const int tid = threadIdx.x;
  const int blk = blockIdx.x;
  if (blk < 1024) {
    const int b = blk >> 8, n = blk & 255;
    const int t = n >> 6, oh = (n >> 3) & 7, ow = n & 7;
    const unsigned short* row = Y0 + ((long)(b * 512 + n)) * 8192;
    const int bt = b * 4 + t;
#pragma unroll
    for (int j = 0; j < 32; ++j) {
      const int idx = j * 256 + tid;
      const int pp = idx >> 9, ch = idx & 511;
      const int py = pp >> 2, px = pp & 3;
      out[(((long)bt * 34 + oh * 4 + py + 1) * 34 + ow * 4 + px + 1) * 1024 + ch] = row[ch * 16 + pp];
    }
  } else {
    const int q = blk - 1024;
    const int b = q >> 10, n = q & 1023;
    const int t = n >> 8, oh = (n >> 4) & 15, ow = n & 15;
    const unsigned short* row = Y1 + ((long)(b * 2048 + n)) * 2048;
    const int bt = b * 4 + t;
#pragma unroll
    for (int j = 0; j < 8; ++j) {
      const int idx = j * 256 + tid;
      const int pp = idx >> 9, ch = idx & 511;
      const int py = pp >> 1, px = pp & 1;
      out[(((long)bt * 34 + oh * 2 + py + 1) * 34 + ow * 2 + px + 1) * 1024 + 512 + ch] = row[ch * 4 + pp];
    }
  }
}

__global__ __launch_bounds__(256) void repack_hi(const unsigned short* __restrict__ Y0,
                                                 const unsigned short* __restrict__ Y1,
                                                 unsigned short* __restrict__ out) {
  const int tid = threadIdx.x;
  const int blk = blockIdx.x;
  if (blk < 1024) {
    const int b = blk >> 8, n = blk & 255;
    const int t = n >> 6, oh = (n >> 3) & 7, ow = n & 7;
    const unsigned short* row = Y0 + ((long)(b * 512 + 256 + n)) * 8192;
    const int bt = b * 4 + t;
#pragma unroll
    for (int j = 0; j < 32; ++j) {
      const int idx = j * 256 + tid;
      const int pp = idx >> 7, ch = idx & 127;
      const int py = pp >> 3, px = pp & 7;
      out[(((long)bt * 66 + oh * 8 + py + 1) * 66 + ow * 8 + px + 1) * 256 + ch] = row[ch * 64 + pp];
    }
  } else {
    const int q = blk - 1024;
    const int b = q >> 10, n = q & 1023;
    const int t = n >> 8, oh = (n >> 4) & 15, ow = n & 15;
    const unsigned short* row = Y1 + ((long)(b * 2048 + 1024 + n)) * 2048;
    const int bt = b * 4 + t;
#pragma unroll
    for (int j = 0; j < 8; ++j) {
      const int idx = j * 256 + tid;
      const int pp = idx >> 7, ch = idx & 127;
      const int py = pp >> 2, px = pp & 3;
      out[(((long)bt * 66 + oh * 4 + py + 1) * 66 + ow * 4 + px + 1) * 256 + 128 + ch] = row[ch * 16 + pp];
    }
  }
}

// ---------------------------------------------------------------------------
// Sum 4 conv partial slabs + bias + leaky-relu -> out
// ---------------------------------------------------------------------------
__global__ __launch_bounds__(256) void reduce_lrelu(const floatx4* __restrict__ P0,
                                                    const floatx4* __restrict__ P1,
                                                    const float* __restrict__ bias,
                                                    floatx4* __restrict__ out) {
  const long i = (long)blockIdx.x * 256 + threadIdx.x;
  constexpr long SL = 1048576;
  floatx4 a = P0[i], b = P0[SL + i], c = P1[i], d = P1[SL + i];
  const int co = ((int)(i >> 8)) & 255;
  const float bv = bias[co];
  floatx4 r;
#pragma unroll
  for (int j = 0; j < 4; ++j) {
    float v = a[j] + b[j] + c[j] + d[j] + bv;
    r[j] = v > 0.f ? v : 0.2f * v;
  }
  out[i] = r;
}

// ---------------------------------------------------------------------------
extern "C" void kernel_launch(void* const* d_in, const int* in_sizes, int n_in,
                              void* d_out, int out_size, void* d_ws, size_t ws_size,
                              hipStream_t stream) {
  (void)in_sizes; (void)n_in; (void)out_size; (void)ws_size;
  const float* x_lo = (const float*)d_in[0];
  const float* x_hi = (const float*)d_in[1];
  const float* wq_lo = (const float*)d_in[3];
  const float* bq_lo = (const float*)d_in[4];
  const float* wk_lo = (const float*)d_in[5];
  const float* bk_lo = (const float*)d_in[6];
  const float* wv_lo = (const float*)d_in[7];
  const float* bv_lo = (const float*)d_in[8];
  const float* wq_hi = (const float*)d_in[9];
  const float* bq_hi = (const float*)d_in[10];
  const float* wk_hi = (const float*)d_in[11];
  const float* bk_hi = (const float*)d_in[12];
  const float* wv_hi = (const float*)d_in[13];
  const float* bv_hi = (const float*)d_in[14];
  const float* wo_lo = (const float*)d_in[15];
  const float* bo_lo = (const float*)d_in[16];
  const float* wo_hi = (const float*)d_in[17];
  const float* bo_hi = (const float*)d_in[18];
  float* out = (float*)d_out;

  char* ws = (char*)d_ws;
  const long B0 = 33554432;
  unsigned short* Qp0 = (unsigned short*)(ws);            // later: Y0, then conv partials P0
  unsigned short* Kp0 = (unsigned short*)(ws + B0);       // later: S1, then CinP_lo
  unsigned short* V0t = (unsigned short*)(ws + 2 * B0);
  unsigned short* Qp1 = (unsigned short*)(ws + 3 * B0);   // later: Y1, then conv partials P1
  unsigned short* Kp1 = (unsigned short*)(ws + 4 * B0);   // later: CinP_hi
  unsigned short* V1t = (unsigned short*)(ws + 5 * B0);
  char* ptr = ws + 6 * B0;
  unsigned short* S0 = (unsigned short*)ptr;     ptr += 2097152;
  unsigned short* Xt_lo = (unsigned short*)ptr;  ptr += 8388608;
  unsigned short* Xt_hi = (unsigned short*)ptr;  ptr += 33554432;   // later: S0 fp32 partials
  unsigned short* Wcat_lo = (unsigned short*)ptr; ptr += 1572864;
  unsigned short* Wcat_hi = (unsigned short*)ptr; ptr += 393216;
  float* Bcat_lo = (float*)ptr;                  ptr += 12288;
  float* Bcat_hi = (float*)ptr;                  ptr += 3072;
  unsigned short* Wt_lo = (unsigned short*)ptr;  ptr += 4718592;
  unsigned short* Wt_hi = (unsigned short*)ptr;  ptr += 1179648;
  unsigned short* S1 = Kp0;
  unsigned short* Y0 = Qp0;
  unsigned short* Y1 = Qp1;
  unsigned short* CinP_lo = Kp0;
  unsigned short* CinP_hi = Kp1;
  float* S0p = (float*)Xt_hi;
  float* PC0 = (float*)Qp0;
  float* PC1 = (float*)Qp1;

  // --- weight/input prep ---
  prep_qkv_w<<<(3 * 1024 * 256 + 255) / 256, 256, 0, stream>>>(
      wq_lo, wk_lo, wv_lo, bq_lo, bk_lo, bv_lo, Wcat_lo, Bcat_lo, 1024);
  prep_qkv_w<<<(3 * 256 * 256 + 255) / 256, 256, 0, stream>>>(
      wq_hi, wk_hi, wv_hi, bq_hi, bk_hi, bv_hi, Wcat_hi, Bcat_hi, 256);
  prep_conv_w<<<(9 * 256 * 1024 + 255) / 256, 256, 0, stream>>>(wo_lo, Wt_lo, 1024);
  prep_conv_w<<<(9 * 256 * 256 + 255) / 256, 256, 0, stream>>>(wo_hi, Wt_hi, 256);
  xt_kernel<<<dim3(16, 4, 16), 256, 0, stream>>>(x_lo, Xt_lo, 1024);
  xt_kernel<<<dim3(64, 4, 16), 256, 0, stream>>>(x_hi, Xt_hi, 4096);

  // --- QKV projections (1x1 conv as TN-GEMM), scattered to patch layout ---
  {
    GemmP p{};
    p.A = Wcat_lo; p.B = Xt_lo; p.sAb = 0; p.sBb = 1024L * 256;
    p.lda = 256; p.ldb = 256; p.K = 256;
    p.bias = Bcat_lo;
    p.Q0 = Qp0; p.K0 = Kp0; p.V0t = V0t; p.Q1 = Qp1; p.K1 = Kp1; p.V1t = V1t;
    gemm256<2><<<dim3(4, 12, 16), 512, 0, stream>>>(p);
    p.A = Wcat_hi; p.B = Xt_hi; p.sBb = 4096L * 256; p.bias = Bcat_hi;
    gemm256<3><<<dim3(16, 3, 16), 512, 0, stream>>>(p);
  }

  // --- attention cfg0: n=512, d=8192 (split-K 8 + fused reduce softmax) ---
  {
    GemmP s{};
    s.A = Qp0; s.B = Kp0; s.sAb = 512L * 8192; s.sBb = 512L * 8192;
    s.lda = 8192; s.ldb = 8192; s.K = 8192;
    s.Cp = S0p; s.sCb = 512L * 512; s.ldc = 512;
    gemm256<1><<<dim3(2, 2, 32), 512, 0, stream>>>(s);
    softmax_red8<<<512, 256, 0, stream>>>(S0p, S0);
    GemmP pv{};
    pv.A = S0; pv.B = V0t; pv.sAb = 512L * 512; pv.sBb = 8192L * 512;
    pv.lda = 512; pv.ldb = 512; pv.K = 512;
    pv.C = Y0; pv.sCb = 512L * 8192; pv.ldc = 8192;
    gemm256<0><<<dim3(32, 2, 4), 512, 0, stream>>>(pv);
  }

  // --- attention cfg1: n=2048, d=2048 ---
  {
    GemmP s{};
    s.A = Qp1; s.B = Kp1; s.sAb = 2048L * 2048; s.sBb = 2048L * 2048;
    s.lda = 2048; s.ldb = 2048; s.K = 2048;
    s.C = S1; s.sCb = 2048L * 2048; s.ldc = 2048;
    gemm256<0><<<dim3(8, 8, 4), 512, 0, stream>>>(s);
    softmax_rows<2048><<<2048, 256, 0, stream>>>(S1);
    GemmP pv{};
    pv.A = S1; pv.B = V1t; pv.sAb = 2048L * 2048; pv.sBb = 2048L * 2048;
    pv.lda = 2048; pv.ldb = 2048; pv.K = 2048;
    pv.C = Y1; pv.sCb = 2048L * 2048; pv.ldc = 2048;
    gemm256<0><<<dim3(8, 8, 4), 512, 0, stream>>>(pv);
  }

  // --- halo zeroing + from_patches repack into padded NHWC conv inputs ---
  zero_border<<<1056, 256, 0, stream>>>(CinP_lo, 34, 34, 1024);
  zero_border<<<520, 256, 0, stream>>>(CinP_hi, 66, 66, 256);
  repack_lo<<<5120, 256, 0, stream>>>(Y0, Y1, CinP_lo);
  repack_hi<<<5120, 256, 0, stream>>>(Y0, Y1, CinP_hi);

  // --- 3x3 convs as im2col GEMM on the 256-tile pipeline ---
  conv256<32, 32, 1024, 4, true><<<dim3(4, 1, 64), 512, 0, stream>>>(
      CinP_lo, Wt_lo, bo_lo, out, PC0, PC1);
  reduce_lrelu<<<4096, 256, 0, stream>>>((const floatx4*)PC0, (const floatx4*)PC1, bo_lo,
                                         (floatx4*)out);
  conv256<64, 64, 256, 1, false><<<dim3(16, 1, 16), 512, 0, stream>>>(
      CinP_hi, Wt_hi, bo_hi, out + 4194304, nullptr, nullptr);
}

// Round 6
// 635.713 us; speedup vs baseline: 1.7260x; 1.1708x over previous
//
#include <hip/hip_runtime.h>
#include <hip/hip_bf16.h>
#include <stdint.h>

typedef __attribute__((ext_vector_type(8))) short short8;
typedef __attribute__((ext_vector_type(4))) short short4v;
typedef __attribute__((ext_vector_type(2))) short short2v;
typedef __attribute__((ext_vector_type(4))) float floatx4;

__device__ __forceinline__ unsigned short f2b(float f) {
  unsigned u = __builtin_bit_cast(unsigned, f);
  unsigned r = u + 0x7fffu + ((u >> 16) & 1u);
  return (unsigned short)(r >> 16);
}
__device__ __forceinline__ float b2f(unsigned short h) {
  unsigned u = ((unsigned)h) << 16;
  return __builtin_bit_cast(float, u);
}
__device__ __forceinline__ void glds16(const unsigned short* src, unsigned short* dst) {
  __builtin_amdgcn_global_load_lds((const __attribute__((address_space(1))) void*)src,
                                   (__attribute__((address_space(3))) void*)dst, 16, 0, 0);
}
// epilogue LDS swizzle: row r (0..255), o = byte offset in 512B row. Bijective
// per 16B chunk; spreads same-column accesses across banks.
__device__ __forceinline__ int swz(int r, int o) {
  return (r << 9) + (o ^ ((((o >> 7) & 3) ^ (r & 7)) << 4));
}

// ---------------------------------------------------------------------------
// 256x256-tile TN GEMM: C[M,N] = A[M,K]*B[N,K]^T, bf16 in, fp32 accum.
// 512 threads = 8 waves (2M x 4N); BK=32; 4-buffer LDS ring (128 KiB);
// counted vmcnt 8/4/0 (issuance-exact); s_barrier+sched_barrier; setprio.
// Epilogues (EPI 0/2/3) stage the 256x256 bf16 tile in LDS (ring is dead)
// and write destination-major 16B coalesced stores.
// EPI 1: split-K(8) fp32 partials (direct stores).
// ---------------------------------------------------------------------------
struct GemmP {
  const unsigned short* A;
  const unsigned short* B;
  long sAb, sBb;
  int lda, ldb, K;
  unsigned short* C; long sCb; int ldc;   // EPI 0
  float* Cp;                              // EPI 1
  const float* bias;                      // EPI 2/3
  unsigned short *Q0, *K0, *V0t, *Q1, *K1, *V1t;
};

template<int EPI>
__global__ __launch_bounds__(512) void gemm256(GemmP p) {
  __shared__ __align__(16) unsigned short LDS[65536];
  const int tid = threadIdx.x;
  const int wv = tid >> 6, lane = tid & 63;
  const int wm = wv >> 2, wn = wv & 3;
  const int g = lane >> 4, l16 = lane & 15;
  const int bz = blockIdx.z;
  const int m0 = blockIdx.y * 256, n0 = blockIdx.x * 256;

  int bb = bz, koff = 0, Keff = p.K;
  if constexpr (EPI == 1) { bb = bz >> 3; koff = (bz & 7) * (p.K >> 3); Keff = p.K >> 3; }
  const unsigned short* Ab = p.A + (long)bb * p.sAb + (long)m0 * p.lda + koff;
  const unsigned short* Bb = p.B + (long)bb * p.sBb + (long)n0 * p.ldb + koff;
  const int NT = Keff >> 5;

  const int r0 = tid >> 2;
  const int cs = (tid & 3) ^ (r0 & 3);
  const unsigned short* aS0 = Ab + (long)r0 * p.lda + cs * 8;
  const unsigned short* aS1 = aS0 + (long)128 * p.lda;
  const unsigned short* bS0 = Bb + (long)r0 * p.ldb + cs * 8;
  const unsigned short* bS1 = bS0 + (long)128 * p.ldb;
  unsigned short* const lds0 = (unsigned short*)LDS;
  const int wbase = wv * 512;

  auto STAGE_A = [&](int t) {
    unsigned short* d = lds0 + (t & 3) * 16384;
    const long ko = (long)t * 32;
    glds16(aS0 + ko, d + wbase);
    glds16(aS1 + ko, d + 4096 + wbase);
  };
  auto STAGE_B = [&](int t) {
    unsigned short* d = lds0 + (t & 3) * 16384 + 8192;
    const long ko = (long)t * 32;
    glds16(bS0 + ko, d + wbase);
    glds16(bS1 + ko, d + 4096 + wbase);
  };

  STAGE_A(0); STAGE_B(0); STAGE_A(1); STAGE_B(1); STAGE_A(2); STAGE_B(2);

  floatx4 acc[8][4];
  const floatx4 z4 = {0.f, 0.f, 0.f, 0.f};
#pragma unroll
  for (int i = 0; i < 8; ++i)
#pragma unroll
    for (int j = 0; j < 4; ++j) acc[i][j] = z4;

  const int loff = l16 * 32 + ((g ^ (l16 & 3)) * 8);
  const int aRowB = wm * 128;

  for (int t = 0; t < NT; ++t) {
    const unsigned short* As = lds0 + (t & 3) * 16384;
    const unsigned short* Bs = As + 8192;
    // ---- P0 ----  (tail-exact counted wait: loads newer than tile t = 8/4/0)
    if (t < NT - 2)        asm volatile("s_waitcnt vmcnt(8)" ::: "memory");
    else if (t == NT - 2)  asm volatile("s_waitcnt vmcnt(4)" ::: "memory");
    else                   asm volatile("s_waitcnt vmcnt(0)" ::: "memory");
    __builtin_amdgcn_s_barrier();
    __builtin_amdgcn_sched_barrier(0);
    if (t + 3 < NT) STAGE_A(t + 3);
    short8 bf[4], af[4];
#pragma unroll
    for (int ni = 0; ni < 4; ++ni)
      bf[ni] = *(const short8*)(Bs + (wn * 64 + ni * 16) * 32 + loff);
#pragma unroll
    for (int mi = 0; mi < 4; ++mi)
      af[mi] = *(const short8*)(As + (aRowB + mi * 16) * 32 + loff);
    __builtin_amdgcn_s_setprio(1);
#pragma unroll
    for (int mi = 0; mi < 4; ++mi)
#pragma unroll
      for (int ni = 0; ni < 4; ++ni)
        acc[mi][ni] = __builtin_amdgcn_mfma_f32_16x16x32_bf16(af[mi], bf[ni], acc[mi][ni], 0, 0, 0);
    __builtin_amdgcn_s_setprio(0);
    // ---- P1 ----
    __builtin_amdgcn_s_barrier();
    __builtin_amdgcn_sched_barrier(0);
    if (t + 3 < NT) STAGE_B(t + 3);
#pragma unroll
    for (int mi = 0; mi < 4; ++mi)
      af[mi] = *(const short8*)(As + (aRowB + 64 + mi * 16) * 32 + loff);
    __builtin_amdgcn_s_setprio(1);
#pragma unroll
    for (int mi = 0; mi < 4; ++mi)
#pragma unroll
      for (int ni = 0; ni < 4; ++ni)
        acc[4 + mi][ni] = __builtin_amdgcn_mfma_f32_16x16x32_bf16(af[mi], bf[ni], acc[4 + mi][ni], 0, 0, 0);
    __builtin_amdgcn_s_setprio(0);
  }

  if constexpr (EPI == 1) {          // direct fp32 partial store (64B-coalesced)
    float* C = p.Cp + (long)bz * p.sCb;
#pragma unroll
    for (int mi = 0; mi < 8; ++mi) {
#pragma unroll
      for (int ni = 0; ni < 4; ++ni) {
        const int col = n0 + wn * 64 + ni * 16 + l16;
#pragma unroll
        for (int r4 = 0; r4 < 4; ++r4) {
          const int row = m0 + wm * 128 + mi * 16 + g * 4 + r4;
          C[(long)row * p.ldc + col] = acc[mi][ni][r4];
        }
      }
    }
  } else {
    // ------- staged epilogue: acc (+bias/scale) -> LDS tile [256co][256pix] -------
    __syncthreads();                 // all waves done with the ring
    char* shb = (char*)LDS;
    const int sel = (EPI == 2) ? (m0 >> 10) : (m0 >> 8);
#pragma unroll
    for (int mi = 0; mi < 8; ++mi) {
#pragma unroll
      for (int ni = 0; ni < 4; ++ni) {
        const int c = wn * 64 + ni * 16 + l16;
#pragma unroll
        for (int r4 = 0; r4 < 4; ++r4) {
          const int rr = wm * 128 + mi * 16 + g * 4 + r4;
          float v = acc[mi][ni][r4];
          if constexpr (EPI == 2 || EPI == 3) {
            v += p.bias[m0 + rr];
            if (sel == 0) {
              float sc;
              if constexpr (EPI == 2) sc = ((m0 & 1023) < 512) ? 0.011048543456039806f
                                                               : 0.02209708691207961f;
              else                    sc = (rr < 128) ? 0.011048543456039806f
                                                      : 0.02209708691207961f;
              v *= sc;
            }
          }
          *(unsigned short*)(shb + swz(rr, c * 2)) = f2b(v);
        }
      }
    }
    __syncthreads();

    if constexpr (EPI == 0) {
      unsigned short* C = p.C + (long)bz * p.sCb;
#pragma unroll
      for (int j = 0; j < 16; ++j) {
        const int e = j * 512 + tid;
        const int r = e >> 5, ck = e & 31;
        short8 v = *(const short8*)(shb + swz(r, ck * 16));
        *(short8*)(C + (long)(m0 + r) * p.ldc + n0 + ck * 8) = v;
      }
    } else if constexpr (EPI == 2) {    // ---- QKV lo ----
      const int chb = m0 & 1023;
      const bool cfg0 = chb < 512;
      const int b = bz >> 2, tt = bz & 3;
      const int k0 = n0 >> 8;
      // FIX (R5 bug): destination buffer must follow the cfg, not always cfg0's.
      unsigned short* dst = cfg0 ? (sel == 0 ? p.Q0 : sel == 1 ? p.K0 : p.V0t)
                                 : (sel == 0 ? p.Q1 : sel == 1 ? p.K1 : p.V1t);
      if (sel != 2) {
        if (cfg0) {                      // 4x4 patches, d=8192
          const long base = (long)(b * 512) * 8192;
#pragma unroll
          for (int j = 0; j < 16; ++j) {
            const int e = j * 512 + tid;
            const int pi = e >> 9, idx2 = e & 511;
            const int ch = idx2 >> 1, hf = idx2 & 1;
            const int oyL = pi >> 3, ox = pi & 7;
            const int nseq = (tt * 8 + 2 * k0 + oyL) * 8 + ox;
            const int yl = oyL * 4 + hf * 2;
            short4v a = *(const short4v*)(shb + swz(ch, (yl * 32 + ox * 4) * 2));
            short4v b2 = *(const short4v*)(shb + swz(ch, ((yl + 1) * 32 + ox * 4) * 2));
            short8 v = {a[0], a[1], a[2], a[3], b2[0], b2[1], b2[2], b2[3]};
            *(short8*)(dst + base + (long)nseq * 8192 + (chb + ch) * 16 + hf * 8) = v;
          }
        } else {                         // 2x2 patches, d=2048
          const int c2lo = chb - 512;
          const long base = (long)(b * 2048) * 2048;
#pragma unroll
          for (int j = 0; j < 16; ++j) {
            const int e = j * 512 + tid;
            const int pi = e >> 7, cp = e & 127;
            const int oyL = pi >> 4, ox = pi & 15;
            const int nseq = (tt * 16 + 4 * k0 + oyL) * 16 + ox;
            short8 v;
#pragma unroll
            for (int rr = 0; rr < 2; ++rr) {
#pragma unroll
              for (int k = 0; k < 2; ++k) {
                short2v pr = *(const short2v*)(shb +
                    swz(cp * 2 + rr, ((oyL * 2 + k) * 32 + ox * 2) * 2));
                v[rr * 4 + k * 2] = pr[0];
                v[rr * 4 + k * 2 + 1] = pr[1];
              }
            }
            *(short8*)(dst + base + (long)nseq * 2048 + (c2lo + cp * 2) * 4) = v;
          }
        }
      } else {                           // V transposed [f][nseq]
        if (cfg0) {
          const long base = (long)(b * 8192) * 512;
#pragma unroll
          for (int j = 0; j < 16; ++j) {
            const int e = j * 512 + tid;
            const int oyL = e >> 12, fu = e & 4095;
            const int ch = fu >> 4, pp = fu & 15;
            const int py = pp >> 2, px = pp & 3;
            const int yl = oyL * 4 + py;
            short8 v;
#pragma unroll
            for (int ox = 0; ox < 8; ++ox)
              v[ox] = *(const unsigned short*)(shb + swz(ch, (yl * 32 + ox * 4 + px) * 2));
            const long f = (long)(chb + ch) * 16 + pp;
            *(short8*)(dst + base + f * 512 + (tt * 8 + 2 * k0 + oyL) * 8) = v;
          }
        } else {
          const int c2lo = chb - 512;
          const long base = (long)(b * 2048) * 2048;
#pragma unroll
          for (int j = 0; j < 16; ++j) {
            const int e = j * 512 + tid;
            const int he = e & 1, oyL = (e >> 1) & 3, fu = e >> 3;
            const int c2 = fu >> 2, pp = fu & 3;
            const int py = pp >> 1, px = pp & 1;
            const int yl = oyL * 2 + py;
            short8 v;
#pragma unroll
            for (int i = 0; i < 8; ++i) {
              const int ox = he * 8 + i;
              v[i] = *(const unsigned short*)(shb + swz(c2, (yl * 32 + ox * 2 + px) * 2));
            }
            const long f = (long)(c2lo + c2) * 4 + pp;
            *(short8*)(dst + base + f * 2048 + (tt * 16 + 4 * k0 + oyL) * 16 + he * 8) = v;
          }
        }
      }
    } else if constexpr (EPI == 3) {    // ---- QKV hi: rows 0..127 cfg0, 128..255 cfg1 ----
      const int b = bz >> 2, tt = bz & 3;
      const int k0 = n0 >> 8;
      const int oyA = k0 >> 1, pyb = (k0 & 1) * 4;
      unsigned short* dstA = sel == 0 ? p.Q0 : sel == 1 ? p.K0 : p.V0t;
      unsigned short* dstB = sel == 0 ? p.Q1 : sel == 1 ? p.K1 : p.V1t;
      if (sel != 2) {
#pragma unroll
        for (int j = 0; j < 16; ++j) {
          const int e = j * 512 + tid;
          if (e < 4096) {                // cfg0: 8x8 patches
            const int ox = e >> 9, cy = e & 511;
            const int ch = cy >> 2, yl = cy & 3;
            const int nseq = 256 + (tt * 8 + oyA) * 8 + ox;
            short8 v = *(const short8*)(shb + swz(ch, (yl * 64 + ox * 8) * 2));
            *(short8*)(dstA + ((long)(b * 512 + nseq)) * 8192 + ch * 64 + (pyb + yl) * 8) = v;
          } else {                       // cfg1: 4x4 patches
            const int ee = e - 4096;
            const int ox = ee >> 8, cc = ee & 255;
            const int c2 = cc >> 1, hf = cc & 1;
            const int nseq = 1024 + (tt * 16 + k0) * 16 + ox;
            short8 v;
#pragma unroll
            for (int k = 0; k < 2; ++k) {
              short4v a = *(const short4v*)(shb +
                  swz(128 + c2, ((hf * 2 + k) * 64 + ox * 4) * 2));
              v[k * 4] = a[0]; v[k * 4 + 1] = a[1]; v[k * 4 + 2] = a[2]; v[k * 4 + 3] = a[3];
            }
            *(short8*)(dstB + ((long)(b * 2048 + nseq)) * 2048 + c2 * 16 + hf * 8) = v;
          }
        }
      } else {
#pragma unroll
        for (int j = 0; j < 16; ++j) {
          const int e = j * 512 + tid;
          if (e < 4096) {                // cfg0 V
            const int ch = e >> 5, yl = (e >> 3) & 3, px = e & 7;
            short8 v;
#pragma unroll
            for (int ox = 0; ox < 8; ++ox)
              v[ox] = *(const unsigned short*)(shb + swz(ch, (yl * 64 + ox * 8 + px) * 2));
            const long f = (long)ch * 64 + (pyb + yl) * 8 + px;
            *(short8*)(dstA + ((long)b * 8192 + f) * 512 + 256 + (tt * 8 + oyA) * 8) = v;
          } else {                       // cfg1 V
            const int ee = e - 4096;
            const int he = ee & 1, fu = ee >> 1;
            const int c2 = fu >> 4, pp = fu & 15;
            const int py = pp >> 2, px = pp & 3;
            short8 v;
#pragma unroll
            for (int i = 0; i < 8; ++i) {
              const int x = (he * 8 + i) * 4 + px;
              v[i] = *(const unsigned short*)(shb + swz(128 + c2, (py * 64 + x) * 2));
            }
            const long f = (long)c2 * 16 + pp;
            *(short8*)(dstB + ((long)b * 2048 + f) * 2048 + 1024 + (tt * 16 + k0) * 16 + he * 8) = v;
          }
        }
      }
    }
  }
}

// ---------------------------------------------------------------------------
// 3x3 conv as im2col GEMM on the 256-tile pipeline (tail-exact waits).
// ---------------------------------------------------------------------------
template<int H, int W, int CIN, int KS, bool PARTIAL>
__global__ __launch_bounds__(512) void conv256(const unsigned short* __restrict__ Cinp,
                                               const unsigned short* __restrict__ Wt,
                                               const float* __restrict__ bias,
                                               float* __restrict__ out,
                                               float* __restrict__ P0,
                                               float* __restrict__ P1) {
  constexpr int HP = H + 2, WP = W + 2;
  constexpr int CC = CIN / KS;
  constexpr int NT = 9 * CC / 32;
  __shared__ __align__(16) unsigned short LDS[65536];
  const int tid = threadIdx.x;
  const int wv = tid >> 6, lane = tid & 63;
  const int wm = wv >> 2, wn = wv & 3;
  const int g = lane >> 4, l16 = lane & 15;
  const int bz = blockIdx.z;
  const int bt = bz / KS, ks = bz % KS;
  const int n0 = blockIdx.x * 256;

  const int r0 = tid >> 2;
  const int cs = (tid & 3) ^ (r0 & 3);
  const unsigned short* wA0 = Wt + (long)r0 * CIN + ks * CC + cs * 8;
  const unsigned short* wA1 = wA0 + (long)128 * CIN;
  const int p0 = n0 + r0, p1 = p0 + 128;
  const int y0p = p0 / W, x0p = p0 % W;
  const int y1p = p1 / W, x1p = p1 % W;
  const unsigned short* cB = Cinp + (long)bt * HP * WP * CIN + ks * CC + cs * 8;
  const unsigned short* pB0 = cB + ((long)y0p * WP + x0p) * CIN;
  const unsigned short* pB1 = cB + ((long)y1p * WP + x1p) * CIN;
  unsigned short* const lds0 = (unsigned short*)LDS;
  const int wbase = wv * 512;

  auto STAGE_A = [&](int t) {
    unsigned short* d = lds0 + (t & 3) * 16384;
    const int tap = t >> 3, tc = (t & 7) * 32;
    const long off = (long)tap * (256L * CIN) + tc;
    glds16(wA0 + off, d + wbase);
    glds16(wA1 + off, d + 4096 + wbase);
  };
  auto STAGE_B = [&](int t) {
    unsigned short* d = lds0 + (t & 3) * 16384 + 8192;
    const int tap = t >> 3, tc = (t & 7) * 32;
    const int ky = tap / 3, kx = tap - ky * 3;
    const long off = ((long)ky * WP + kx) * CIN + tc;
    glds16(pB0 + off, d + wbase);
    glds16(pB1 + off, d + 4096 + wbase);
  };

  STAGE_A(0); STAGE_B(0); STAGE_A(1); STAGE_B(1); STAGE_A(2); STAGE_B(2);

  floatx4 acc[8][4];
  const floatx4 z4 = {0.f, 0.f, 0.f, 0.f};
#pragma unroll
  for (int i = 0; i < 8; ++i)
#pragma unroll
    for (int j = 0; j < 4; ++j) acc[i][j] = z4;

  const int loff = l16 * 32 + ((g ^ (l16 & 3)) * 8);
  const int aRowB = wm * 128;

  for (int t = 0; t < NT; ++t) {
    const unsigned short* As = lds0 + (t & 3) * 16384;
    const unsigned short* Bs = As + 8192;
    if (t < NT - 2)        asm volatile("s_waitcnt vmcnt(8)" ::: "memory");
    else if (t == NT - 2)  asm volatile("s_waitcnt vmcnt(4)" ::: "memory");
    else                   asm volatile("s_waitcnt vmcnt(0)" ::: "memory");
    __builtin_amdgcn_s_barrier();
    __builtin_amdgcn_sched_barrier(0);
    if (t + 3 < NT) STAGE_A(t + 3);
    short8 bf[4], af[4];
#pragma unroll
    for (int ni = 0; ni < 4; ++ni)
      bf[ni] = *(const short8*)(Bs + (wn * 64 + ni * 16) * 32 + loff);
#pragma unroll
    for (int mi = 0; mi < 4; ++mi)
      af[mi] = *(const short8*)(As + (aRowB + mi * 16) * 32 + loff);
    __builtin_amdgcn_s_setprio(1);
#pragma unroll
    for (int mi = 0; mi < 4; ++mi)
#pragma unroll
      for (int ni = 0; ni < 4; ++ni)
        acc[mi][ni] = __builtin_amdgcn_mfma_f32_16x16x32_bf16(af[mi], bf[ni], acc[mi][ni], 0, 0, 0);
    __builtin_amdgcn_s_setprio(0);
    __builtin_amdgcn_s_barrier();
    __builtin_amdgcn_sched_barrier(0);
    if (t + 3 < NT) STAGE_B(t + 3);
#pragma unroll
    for (int mi = 0; mi < 4; ++mi)
      af[mi] = *(const short8*)(As + (aRowB + 64 + mi * 16) * 32 + loff);
    __builtin_amdgcn_s_setprio(1);
#pragma unroll
    for (int mi = 0; mi < 4; ++mi)
#pragma unroll
      for (int ni = 0; ni < 4; ++ni)
        acc[4 + mi][ni] = __builtin_amdgcn_mfma_f32_16x16x32_bf16(af[mi], bf[ni], acc[4 + mi][ni], 0, 0, 0);
    __builtin_amdgcn_s_setprio(0);
  }

  if constexpr (!PARTIAL) {
#pragma unroll
    for (int mi = 0; mi < 8; ++mi) {
#pragma unroll
      for (int ni = 0; ni < 4; ++ni) {
        const int pn = n0 + wn * 64 + ni * 16 + l16;
        const int y = pn / W, x = pn % W;
#pragma unroll
        for (int r4 = 0; r4 < 4; ++r4) {
          const int co = wm * 128 + mi * 16 + g * 4 + r4;
          float v = acc[mi][ni][r4] + bias[co];
          v = v > 0.f ? v : 0.2f * v;
          out[(((long)bt * 256 + co) * H + y) * W + x] = v;
        }
      }
    }
  } else {
    float* pout = (ks < 2 ? P0 : P1) + (long)(ks & 1) * (16L * 256 * H * W);
#pragma unroll
    for (int mi = 0; mi < 8; ++mi) {
#pragma unroll
      for (int ni = 0; ni < 4; ++ni) {
        const int pn = n0 + wn * 64 + ni * 16 + l16;
        const int y = pn / W, x = pn % W;
#pragma unroll
        for (int r4 = 0; r4 < 4; ++r4) {
          const int co = wm * 128 + mi * 16 + g * 4 + r4;
          pout[(((long)bt * 256 + co) * H + y) * W + x] = acc[mi][ni][r4];
        }
      }
    }
  }
}

// ---------------------------------------------------------------------------
// Row softmax in-place on bf16 rows of length L. One wave per row.
// ---------------------------------------------------------------------------
template<int L>
__global__ __launch_bounds__(256) void softmax_rows(unsigned short* S) {
  const int w = threadIdx.x >> 6, lane = threadIdx.x & 63;
  const long row = (long)blockIdx.x * 4 + w;
  unsigned short* R = S + row * L;
  constexpr int NC = L / 64;
  float v[NC];
  float m = -1e30f;
#pragma unroll
  for (int i = 0; i < NC; ++i) { v[i] = b2f(R[i * 64 + lane]); m = fmaxf(m, v[i]); }
#pragma unroll
  for (int off = 32; off; off >>= 1) m = fmaxf(m, __shfl_xor(m, off, 64));
  float s = 0.f;
#pragma unroll
  for (int i = 0; i < NC; ++i) { v[i] = __expf(v[i] - m); s += v[i]; }
#pragma unroll
  for (int off = 32; off; off >>= 1) s += __shfl_xor(s, off, 64);
  const float inv = 1.0f / s;
#pragma unroll
  for (int i = 0; i < NC; ++i) R[i * 64 + lane] = f2b(v[i] * inv);
}

// ---------------------------------------------------------------------------
// S0: sum 8 fp32 split-K slabs -> softmax -> bf16 [b][512][512]
// ---------------------------------------------------------------------------
__global__ __launch_bounds__(256) void softmax_red8(const float* __restrict__ P,
                                                    unsigned short* __restrict__ S) {
  const int w = threadIdx.x >> 6, lane = threadIdx.x & 63;
  const int rowg = blockIdx.x * 4 + w;
  const int b = rowg >> 9, n = rowg & 511;
  const float* base = P + ((long)b * 8) * 262144 + (long)n * 512 + lane;
  float v[8];
#pragma unroll
  for (int i = 0; i < 8; ++i) {
    float s = 0.f;
#pragma unroll
    for (int ks = 0; ks < 8; ++ks) s += base[(long)ks * 262144 + i * 64];
    v[i] = s;
  }
  float m = -1e30f;
#pragma unroll
  for (int i = 0; i < 8; ++i) m = fmaxf(m, v[i]);
#pragma unroll
  for (int off = 32; off; off >>= 1) m = fmaxf(m, __shfl_xor(m, off, 64));
  float s = 0.f;
#pragma unroll
  for (int i = 0; i < 8; ++i) { v[i] = __expf(v[i] - m); s += v[i]; }
#pragma unroll
  for (int off = 32; off; off >>= 1) s += __shfl_xor(s, off, 64);
  const float inv = 1.0f / s;
  unsigned short* R = S + (long)rowg * 512;
#pragma unroll
  for (int i = 0; i < 8; ++i) R[i * 64 + lane] = f2b(v[i] * inv);
}

// ---------------------------------------------------------------------------
// x [16][256][NPIX] fp32 (NCHW) -> xt [16][NPIX][256] bf16 (pixel-major)
// ---------------------------------------------------------------------------
__global__ __launch_bounds__(256) void xt_kernel(const float* __restrict__ x,
                                                 unsigned short* __restrict__ xt, int NPIX) {
  __shared__ unsigned short tile[64 * 65];
  const int tid = threadIdx.x;
  const int bt = blockIdx.z, ch0 = blockIdx.y * 64;
  const long pix0 = (long)blockIdx.x * 64;
  const float* src = x + ((long)bt * 256 + ch0) * NPIX + pix0;
#pragma unroll
  for (int i = 0; i < 16; ++i) {
    const int lin = i * 256 + tid;
    const int ch = lin >> 6, px = lin & 63;
    tile[ch * 65 + px] = f2b(src[(long)ch * NPIX + px]);
  }
  __syncthreads();
  unsigned short* dst = xt + ((long)bt * NPIX + pix0) * 256 + ch0;
#pragma unroll
  for (int i = 0; i < 16; ++i) {
    const int lin = i * 256 + tid;
    const int px = lin >> 6, ch = lin & 63;
    dst[(long)px * 256 + ch] = tile[ch * 65 + px];
  }
}

// ---------------------------------------------------------------------------
// Weight prep
// ---------------------------------------------------------------------------
__global__ void prep_qkv_w(const float* wq, const float* wk, const float* wv,
                           const float* bq, const float* bk, const float* bv,
                           unsigned short* Wcat, float* Bcat, int CO) {
  const int idx = blockIdx.x * 256 + threadIdx.x;
  const int n = 3 * CO * 256;
  if (idx < n) {
    const int sel = idx / (CO * 256);
    const int r = idx - sel * CO * 256;
    const float* wsel = sel == 0 ? wq : (sel == 1 ? wk : wv);
    Wcat[idx] = f2b(wsel[r]);
  }
  if (idx < 3 * CO) {
    const int sel = idx / CO;
    const int r = idx - sel * CO;
    const float* bsel = sel == 0 ? bq : (sel == 1 ? bk : bv);
    Bcat[idx] = bsel[r];
  }
}

__global__ void prep_conv_w(const float* wo, unsigned short* Wt, int CIN) {
  const int idx = blockIdx.x * 256 + threadIdx.x;
  const int n = 9 * 256 * CIN;
  if (idx < n) {
    const int t9 = idx / (256 * CIN);
    const int rem = idx - t9 * 256 * CIN;
    const int o = rem / CIN, i = rem - o * CIN;
    Wt[idx] = f2b(wo[((long)o * CIN + i) * 9 + t9]);   // [9][256][CIN]
  }
}

// ---------------------------------------------------------------------------
// Zero the 1-px halo border of a padded NHWC buffer [16][HP][WP][C]
// ---------------------------------------------------------------------------
__global__ __launch_bounds__(256) void zero_border(unsigned short* buf, int HP, int WP, int C) {
  const long i = (long)blockIdx.x * 256 + threadIdx.x;
  const int per_px = C >> 3;
  const int strip = 2 * WP + 2 * (HP - 2);
  const long tot = (long)16 * strip * per_px;
  if (i >= tot) return;
  const int c8 = (int)(i % per_px);
  const long r = i / per_px;
  const int s = (int)(r % strip);
  const int bt = (int)(r / strip);
  int y, x;
  if (s < WP) { y = 0; x = s; }
  else if (s < 2 * WP) { y = HP - 1; x = s - WP; }
  else if (s < 2 * WP + (HP - 2)) { y = s - 2 * WP + 1; x = 0; }
  else { y = s - 2 * WP - (HP - 2) + 1; x = WP - 1; }
  const short8 z = {0, 0, 0, 0, 0, 0, 0, 0};
  *(short8*)(buf + (((long)bt * HP + y) * WP + x) * C + c8 * 8) = z;
}

// ---------------------------------------------------------------------------
// Repack attention outputs Y (patch-major) -> padded NHWC conv inputs
// ---------------------------------------------------------------------------
__global__ __launch_bounds__(256) void repack_lo(const unsigned short* __restrict__ Y0,
                                                 const unsigned short* __restrict__ Y1,
                                                 unsigned short* __restrict__ out) {
  const int tid = threadIdx.x;
  const int blk = blockIdx.x;
  if (blk < 1024) {
    const int b = blk >> 8, n = blk & 255;
    const int t = n >> 6, oh = (n >> 3) & 7, ow = n & 7;
    const unsigned short* row = Y0 + ((long)(b * 512 + n)) * 8192;
    const int bt = b * 4 + t;
#pragma unroll
    for (int j = 0; j < 32; ++j) {
      const int idx = j * 256 + tid;
      const int pp = idx >> 9, ch = idx & 511;
      const int py = pp >> 2, px = pp & 3;
      out[(((long)bt * 34 + oh * 4 + py + 1) * 34 + ow * 4 + px + 1) * 1024 + ch] = row[ch * 16 + pp];
    }
  } else {
    const int q = blk - 1024;
    const int b = q >> 10, n = q & 1023;
    const int t = n >> 8, oh = (n >> 4) & 15, ow = n & 15;
    const unsigned short* row = Y1 + ((long)(b * 2048 + n)) * 2048;
    const int bt = b * 4 + t;
#pragma unroll
    for (int j = 0; j < 8; ++j) {
      const int idx = j * 256 + tid;
      const int pp = idx >> 9, ch = idx & 511;
      const int py = pp >> 1, px = pp & 1;
      out[(((long)bt * 34 + oh * 2 + py + 1) * 34 + ow * 2 + px + 1) * 1024 + 512 + ch] = row[ch * 4 + pp];
    }
  }
}

__global__ __launch_bounds__(256) void repack_hi(const unsigned short* __restrict__ Y0,
                                                 const unsigned short* __restrict__ Y1,
                                                 unsigned short* __restrict__ out) {
  const int tid = threadIdx.x;
  const int blk = blockIdx.x;
  if (blk < 1024) {
    const int b = blk >> 8, n = blk & 255;
    const int t = n >> 6, oh = (n >> 3) & 7, ow = n & 7;
    const unsigned short* row = Y0 + ((long)(b * 512 + 256 + n)) * 8192;
    const int bt = b * 4 + t;
#pragma unroll
    for (int j = 0; j < 32; ++j) {
      const int idx = j * 256 + tid;
      const int pp = idx >> 7, ch = idx & 127;
      const int py = pp >> 3, px = pp & 7;
      out[(((long)bt * 66 + oh * 8 + py + 1) * 66 + ow * 8 + px + 1) * 256 + ch] = row[ch * 64 + pp];
    }
  } else {
    const int q = blk - 1024;
    const int b = q >> 10, n = q & 1023;
    const int t = n >> 8, oh = (n >> 4) & 15, ow = n & 15;
    const unsigned short* row = Y1 + ((long)(b * 2048 + 1024 + n)) * 2048;
    const int bt = b * 4 + t;
#pragma unroll
    for (int j = 0; j < 8; ++j) {
      const int idx = j * 256 + tid;
      const int pp = idx >> 7, ch = idx & 127;
      const int py = pp >> 2, px = pp & 3;
      out[(((long)bt * 66 + oh * 4 + py + 1) * 66 + ow * 4 + px + 1) * 256 + 128 + ch] = row[ch * 16 + pp];
    }
  }
}

// ---------------------------------------------------------------------------
// Sum 4 conv partial slabs + bias + leaky-relu -> out
// ---------------------------------------------------------------------------
__global__ __launch_bounds__(256) void reduce_lrelu(const floatx4* __restrict__ P0,
                                                    const floatx4* __restrict__ P1,
                                                    const float* __restrict__ bias,
                                                    floatx4* __restrict__ out) {
  const long i = (long)blockIdx.x * 256 + threadIdx.x;
  constexpr long SL = 1048576;
  floatx4 a = P0[i], b = P0[SL + i], c = P1[i], d = P1[SL + i];
  const int co = ((int)(i >> 8)) & 255;
  const float bv = bias[co];
  floatx4 r;
#pragma unroll
  for (int j = 0; j < 4; ++j) {
    float v = a[j] + b[j] + c[j] + d[j] + bv;
    r[j] = v > 0.f ? v : 0.2f * v;
  }
  out[i] = r;
}

// ---------------------------------------------------------------------------
extern "C" void kernel_launch(void* const* d_in, const int* in_sizes, int n_in,
                              void* d_out, int out_size, void* d_ws, size_t ws_size,
                              hipStream_t stream) {
  (void)in_sizes; (void)n_in; (void)out_size; (void)ws_size;
  const float* x_lo = (const float*)d_in[0];
  const float* x_hi = (const float*)d_in[1];
  const float* wq_lo = (const float*)d_in[3];
  const float* bq_lo = (const float*)d_in[4];
  const float* wk_lo = (const float*)d_in[5];
  const float* bk_lo = (const float*)d_in[6];
  const float* wv_lo = (const float*)d_in[7];
  const float* bv_lo = (const float*)d_in[8];
  const float* wq_hi = (const float*)d_in[9];
  const float* bq_hi = (const float*)d_in[10];
  const float* wk_hi = (const float*)d_in[11];
  const float* bk_hi = (const float*)d_in[12];
  const float* wv_hi = (const float*)d_in[13];
  const float* bv_hi = (const float*)d_in[14];
  const float* wo_lo = (const float*)d_in[15];
  const float* bo_lo = (const float*)d_in[16];
  const float* wo_hi = (const float*)d_in[17];
  const float* bo_hi = (const float*)d_in[18];
  float* out = (float*)d_out;

  char* ws = (char*)d_ws;
  const long B0 = 33554432;
  unsigned short* Qp0 = (unsigned short*)(ws);
  unsigned short* Kp0 = (unsigned short*)(ws + B0);
  unsigned short* V0t = (unsigned short*)(ws + 2 * B0);
  unsigned short* Qp1 = (unsigned short*)(ws + 3 * B0);
  unsigned short* Kp1 = (unsigned short*)(ws + 4 * B0);
  unsigned short* V1t = (unsigned short*)(ws + 5 * B0);
  char* ptr = ws + 6 * B0;
  unsigned short* S0 = (unsigned short*)ptr;     ptr += 2097152;
  unsigned short* Xt_lo = (unsigned short*)ptr;  ptr += 8388608;
  unsigned short* Xt_hi = (unsigned short*)ptr;  ptr += 33554432;
  unsigned short* Wcat_lo = (unsigned short*)ptr; ptr += 1572864;
  unsigned short* Wcat_hi = (unsigned short*)ptr; ptr += 393216;
  float* Bcat_lo = (float*)ptr;                  ptr += 12288;
  float* Bcat_hi = (float*)ptr;                  ptr += 3072;
  unsigned short* Wt_lo = (unsigned short*)ptr;  ptr += 4718592;
  unsigned short* Wt_hi = (unsigned short*)ptr;  ptr += 1179648;
  unsigned short* S1 = Kp0;
  unsigned short* Y0 = Qp0;
  unsigned short* Y1 = Qp1;
  unsigned short* CinP_lo = Kp0;
  unsigned short* CinP_hi = Kp1;
  float* S0p = (float*)Xt_hi;
  float* PC0 = (float*)Qp0;
  float* PC1 = (float*)Qp1;

  // --- weight/input prep ---
  prep_qkv_w<<<(3 * 1024 * 256 + 255) / 256, 256, 0, stream>>>(
      wq_lo, wk_lo, wv_lo, bq_lo, bk_lo, bv_lo, Wcat_lo, Bcat_lo, 1024);
  prep_qkv_w<<<(3 * 256 * 256 + 255) / 256, 256, 0, stream>>>(
      wq_hi, wk_hi, wv_hi, bq_hi, bk_hi, bv_hi, Wcat_hi, Bcat_hi, 256);
  prep_conv_w<<<(9 * 256 * 1024 + 255) / 256, 256, 0, stream>>>(wo_lo, Wt_lo, 1024);
  prep_conv_w<<<(9 * 256 * 256 + 255) / 256, 256, 0, stream>>>(wo_hi, Wt_hi, 256);
  xt_kernel<<<dim3(16, 4, 16), 256, 0, stream>>>(x_lo, Xt_lo, 1024);
  xt_kernel<<<dim3(64, 4, 16), 256, 0, stream>>>(x_hi, Xt_hi, 4096);

  // --- QKV projections (1x1 conv as TN-GEMM), staged coalesced scatter ---
  {
    GemmP p{};
    p.A = Wcat_lo; p.B = Xt_lo; p.sAb = 0; p.sBb = 1024L * 256;
    p.lda = 256; p.ldb = 256; p.K = 256;
    p.bias = Bcat_lo;
    p.Q0 = Qp0; p.K0 = Kp0; p.V0t = V0t; p.Q1 = Qp1; p.K1 = Kp1; p.V1t = V1t;
    gemm256<2><<<dim3(4, 12, 16), 512, 0, stream>>>(p);
    p.A = Wcat_hi; p.B = Xt_hi; p.sBb = 4096L * 256; p.bias = Bcat_hi;
    gemm256<3><<<dim3(16, 3, 16), 512, 0, stream>>>(p);
  }

  // --- attention cfg0: n=512, d=8192 (split-K 8 + fused reduce softmax) ---
  {
    GemmP s{};
    s.A = Qp0; s.B = Kp0; s.sAb = 512L * 8192; s.sBb = 512L * 8192;
    s.lda = 8192; s.ldb = 8192; s.K = 8192;
    s.Cp = S0p; s.sCb = 512L * 512; s.ldc = 512;
    gemm256<1><<<dim3(2, 2, 32), 512, 0, stream>>>(s);
    softmax_red8<<<512, 256, 0, stream>>>(S0p, S0);
    GemmP pv{};
    pv.A = S0; pv.B = V0t; pv.sAb = 512L * 512; pv.sBb = 8192L * 512;
    pv.lda = 512; pv.ldb = 512; pv.K = 512;
    pv.C = Y0; pv.sCb = 512L * 8192; pv.ldc = 8192;
    gemm256<0><<<dim3(32, 2, 4), 512, 0, stream>>>(pv);
  }

  // --- attention cfg1: n=2048, d=2048 ---
  {
    GemmP s{};
    s.A = Qp1; s.B = Kp1; s.sAb = 2048L * 2048; s.sBb = 2048L * 2048;
    s.lda = 2048; s.ldb = 2048; s.K = 2048;
    s.C = S1; s.sCb = 2048L * 2048; s.ldc = 2048;
    gemm256<0><<<dim3(8, 8, 4), 512, 0, stream>>>(s);
    softmax_rows<2048><<<2048, 256, 0, stream>>>(S1);
    GemmP pv{};
    pv.A = S1; pv.B = V1t; pv.sAb = 2048L * 2048; pv.sBb = 2048L * 2048;
    pv.lda = 2048; pv.ldb = 2048; pv.K = 2048;
    pv.C = Y1; pv.sCb = 2048L * 2048; pv.ldc = 2048;
    gemm256<0><<<dim3(8, 8, 4), 512, 0, stream>>>(pv);
  }

  // --- halo zeroing + from_patches repack into padded NHWC conv inputs ---
  zero_border<<<1056, 256, 0, stream>>>(CinP_lo, 34, 34, 1024);
  zero_border<<<520, 256, 0, stream>>>(CinP_hi, 66, 66, 256);
  repack_lo<<<5120, 256, 0, stream>>>(Y0, Y1, CinP_lo);
  repack_hi<<<5120, 256, 0, stream>>>(Y0, Y1, CinP_hi);

  // --- 3x3 convs as im2col GEMM on the 256-tile pipeline ---
  conv256<32, 32, 1024, 4, true><<<dim3(4, 1, 64), 512, 0, stream>>>(
      CinP_lo, Wt_lo, bo_lo, out, PC0, PC1);
  reduce_lrelu<<<4096, 256, 0, stream>>>((const floatx4*)PC0, (const floatx4*)PC1, bo_lo,
                                         (floatx4*)out);
  conv256<64, 64, 256, 1, false><<<dim3(16, 1, 16), 512, 0, stream>>>(
      CinP_hi, Wt_hi, bo_hi, out + 4194304, nullptr, nullptr);
}

// Round 7
// 613.872 us; speedup vs baseline: 1.7874x; 1.0356x over previous
//
#include <hip/hip_runtime.h>
#include <hip/hip_bf16.h>
#include <stdint.h>

typedef __attribute__((ext_vector_type(8))) short short8;
typedef __attribute__((ext_vector_type(4))) short short4v;
typedef __attribute__((ext_vector_type(2))) short short2v;
typedef __attribute__((ext_vector_type(4))) float floatx4;

__device__ __forceinline__ unsigned short f2b(float f) {
  unsigned u = __builtin_bit_cast(unsigned, f);
  unsigned r = u + 0x7fffu + ((u >> 16) & 1u);
  return (unsigned short)(r >> 16);
}
__device__ __forceinline__ float b2f(unsigned short h) {
  unsigned u = ((unsigned)h) << 16;
  return __builtin_bit_cast(float, u);
}
__device__ __forceinline__ void glds16(const unsigned short* src, unsigned short* dst) {
  __builtin_amdgcn_global_load_lds((const __attribute__((address_space(1))) void*)src,
                                   (__attribute__((address_space(3))) void*)dst, 16, 0, 0);
}
// epilogue LDS swizzle: row r (0..255), o = byte offset in 512B row. Bijective
// per 16B chunk; spreads same-column accesses across banks.
__device__ __forceinline__ int swz(int r, int o) {
  return (r << 9) + (o ^ ((((o >> 7) & 3) ^ (r & 7)) << 4));
}

// ---------------------------------------------------------------------------
// 256x256-tile TN GEMM: C[M,N] = A[M,K]*B[N,K]^T, bf16 in, fp32 accum.
// 512 threads = 8 waves (2M x 4N); BK=32; 4-buffer LDS ring (128 KiB);
// counted vmcnt 8/4/0; ONE barrier per K-tile (mid barrier proven redundant:
// stage(t+3) writes buf[(t-1)&3] whose last readers are fenced by this tile's
// start barrier); 12 ds_reads up front, 32 MFMA per barrier; setprio clusters.
// K-loop swizzle f(row)=(row>>1)&3 -> 2-way bank aliasing (free, m136).
// Epilogues (EPI 0/2/3) stage the 256x256 bf16 tile in LDS (ring is dead)
// and write destination-major 16B coalesced stores.
// EPI 1: split-K(8) fp32 partials (direct stores).
// ---------------------------------------------------------------------------
struct GemmP {
  const unsigned short* A;
  const unsigned short* B;
  long sAb, sBb;
  int lda, ldb, K;
  unsigned short* C; long sCb; int ldc;   // EPI 0
  float* Cp;                              // EPI 1
  const float* bias;                      // EPI 2/3
  unsigned short *Q0, *K0, *V0t, *Q1, *K1, *V1t;
};

template<int EPI>
__global__ __launch_bounds__(512) void gemm256(GemmP p) {
  __shared__ __align__(16) unsigned short LDS[65536];
  const int tid = threadIdx.x;
  const int wv = tid >> 6, lane = tid & 63;
  const int wm = wv >> 2, wn = wv & 3;
  const int g = lane >> 4, l16 = lane & 15;
  const int bz = blockIdx.z;
  const int m0 = blockIdx.y * 256, n0 = blockIdx.x * 256;

  int bb = bz, koff = 0, Keff = p.K;
  if constexpr (EPI == 1) { bb = bz >> 3; koff = (bz & 7) * (p.K >> 3); Keff = p.K >> 3; }
  const unsigned short* Ab = p.A + (long)bb * p.sAb + (long)m0 * p.lda + koff;
  const unsigned short* Bb = p.B + (long)bb * p.sBb + (long)n0 * p.ldb + koff;
  const int NT = Keff >> 5;

  const int r0 = tid >> 2;
  const int cs = (tid & 3) ^ ((r0 >> 1) & 3);   // period-16 involution vs 16-bank row base
  const unsigned short* aS0 = Ab + (long)r0 * p.lda + cs * 8;
  const unsigned short* aS1 = aS0 + (long)128 * p.lda;
  const unsigned short* bS0 = Bb + (long)r0 * p.ldb + cs * 8;
  const unsigned short* bS1 = bS0 + (long)128 * p.ldb;
  unsigned short* const lds0 = (unsigned short*)LDS;
  const int wbase = wv * 512;

  auto STAGE_A = [&](int t) {
    unsigned short* d = lds0 + (t & 3) * 16384;
    const long ko = (long)t * 32;
    glds16(aS0 + ko, d + wbase);
    glds16(aS1 + ko, d + 4096 + wbase);
  };
  auto STAGE_B = [&](int t) {
    unsigned short* d = lds0 + (t & 3) * 16384 + 8192;
    const long ko = (long)t * 32;
    glds16(bS0 + ko, d + wbase);
    glds16(bS1 + ko, d + 4096 + wbase);
  };

  STAGE_A(0); STAGE_B(0); STAGE_A(1); STAGE_B(1); STAGE_A(2); STAGE_B(2);

  floatx4 acc[8][4];
  const floatx4 z4 = {0.f, 0.f, 0.f, 0.f};
#pragma unroll
  for (int i = 0; i < 8; ++i)
#pragma unroll
    for (int j = 0; j < 4; ++j) acc[i][j] = z4;

  const int loff = l16 * 32 + ((g ^ ((l16 >> 1) & 3)) * 8);
  const int aRowB = wm * 128;

  for (int t = 0; t < NT; ++t) {
    const unsigned short* As = lds0 + (t & 3) * 16384;
    const unsigned short* Bs = As + 8192;
    if (t < NT - 2)        asm volatile("s_waitcnt vmcnt(8)" ::: "memory");
    else if (t == NT - 2)  asm volatile("s_waitcnt vmcnt(4)" ::: "memory");
    else                   asm volatile("s_waitcnt vmcnt(0)" ::: "memory");
    __builtin_amdgcn_s_barrier();
    __builtin_amdgcn_sched_barrier(0);
    if (t + 3 < NT) STAGE_A(t + 3);
    short8 bf[4], af[4], ag[4];
#pragma unroll
    for (int ni = 0; ni < 4; ++ni)
      bf[ni] = *(const short8*)(Bs + (wn * 64 + ni * 16) * 32 + loff);
#pragma unroll
    for (int mi = 0; mi < 4; ++mi)
      af[mi] = *(const short8*)(As + (aRowB + mi * 16) * 32 + loff);
#pragma unroll
    for (int mi = 0; mi < 4; ++mi)
      ag[mi] = *(const short8*)(As + (aRowB + 64 + mi * 16) * 32 + loff);
    __builtin_amdgcn_s_setprio(1);
#pragma unroll
    for (int mi = 0; mi < 4; ++mi)
#pragma unroll
      for (int ni = 0; ni < 4; ++ni)
        acc[mi][ni] = __builtin_amdgcn_mfma_f32_16x16x32_bf16(af[mi], bf[ni], acc[mi][ni], 0, 0, 0);
    __builtin_amdgcn_s_setprio(0);
    if (t + 3 < NT) STAGE_B(t + 3);
    __builtin_amdgcn_s_setprio(1);
#pragma unroll
    for (int mi = 0; mi < 4; ++mi)
#pragma unroll
      for (int ni = 0; ni < 4; ++ni)
        acc[4 + mi][ni] = __builtin_amdgcn_mfma_f32_16x16x32_bf16(ag[mi], bf[ni], acc[4 + mi][ni], 0, 0, 0);
    __builtin_amdgcn_s_setprio(0);
  }

  if constexpr (EPI == 1) {          // direct fp32 partial store (64B-coalesced)
    float* C = p.Cp + (long)bz * p.sCb;
#pragma unroll
    for (int mi = 0; mi < 8; ++mi) {
#pragma unroll
      for (int ni = 0; ni < 4; ++ni) {
        const int col = n0 + wn * 64 + ni * 16 + l16;
#pragma unroll
        for (int r4 = 0; r4 < 4; ++r4) {
          const int row = m0 + wm * 128 + mi * 16 + g * 4 + r4;
          C[(long)row * p.ldc + col] = acc[mi][ni][r4];
        }
      }
    }
  } else {
    // ------- staged epilogue: acc (+bias/scale) -> LDS tile [256co][256pix] -------
    __syncthreads();                 // all waves done with the ring
    char* shb = (char*)LDS;
    const int sel = (EPI == 2) ? (m0 >> 10) : (m0 >> 8);
#pragma unroll
    for (int mi = 0; mi < 8; ++mi) {
#pragma unroll
      for (int ni = 0; ni < 4; ++ni) {
        const int c = wn * 64 + ni * 16 + l16;
#pragma unroll
        for (int r4 = 0; r4 < 4; ++r4) {
          const int rr = wm * 128 + mi * 16 + g * 4 + r4;
          float v = acc[mi][ni][r4];
          if constexpr (EPI == 2 || EPI == 3) {
            v += p.bias[m0 + rr];
            if (sel == 0) {
              float sc;
              if constexpr (EPI == 2) sc = ((m0 & 1023) < 512) ? 0.011048543456039806f
                                                               : 0.02209708691207961f;
              else                    sc = (rr < 128) ? 0.011048543456039806f
                                                      : 0.02209708691207961f;
              v *= sc;
            }
          }
          *(unsigned short*)(shb + swz(rr, c * 2)) = f2b(v);
        }
      }
    }
    __syncthreads();

    if constexpr (EPI == 0) {
      unsigned short* C = p.C + (long)bz * p.sCb;
#pragma unroll
      for (int j = 0; j < 16; ++j) {
        const int e = j * 512 + tid;
        const int r = e >> 5, ck = e & 31;
        short8 v = *(const short8*)(shb + swz(r, ck * 16));
        *(short8*)(C + (long)(m0 + r) * p.ldc + n0 + ck * 8) = v;
      }
    } else if constexpr (EPI == 2) {    // ---- QKV lo ----
      const int chb = m0 & 1023;
      const bool cfg0 = chb < 512;
      const int b = bz >> 2, tt = bz & 3;
      const int k0 = n0 >> 8;
      unsigned short* dst = cfg0 ? (sel == 0 ? p.Q0 : sel == 1 ? p.K0 : p.V0t)
                                 : (sel == 0 ? p.Q1 : sel == 1 ? p.K1 : p.V1t);
      if (sel != 2) {
        if (cfg0) {                      // 4x4 patches, d=8192
          const long base = (long)(b * 512) * 8192;
#pragma unroll
          for (int j = 0; j < 16; ++j) {
            const int e = j * 512 + tid;
            const int pi = e >> 9, idx2 = e & 511;
            const int ch = idx2 >> 1, hf = idx2 & 1;
            const int oyL = pi >> 3, ox = pi & 7;
            const int nseq = (tt * 8 + 2 * k0 + oyL) * 8 + ox;
            const int yl = oyL * 4 + hf * 2;
            short4v a = *(const short4v*)(shb + swz(ch, (yl * 32 + ox * 4) * 2));
            short4v b2 = *(const short4v*)(shb + swz(ch, ((yl + 1) * 32 + ox * 4) * 2));
            short8 v = {a[0], a[1], a[2], a[3], b2[0], b2[1], b2[2], b2[3]};
            *(short8*)(dst + base + (long)nseq * 8192 + (chb + ch) * 16 + hf * 8) = v;
          }
        } else {                         // 2x2 patches, d=2048
          const int c2lo = chb - 512;
          const long base = (long)(b * 2048) * 2048;
#pragma unroll
          for (int j = 0; j < 16; ++j) {
            const int e = j * 512 + tid;
            const int pi = e >> 7, cp = e & 127;
            const int oyL = pi >> 4, ox = pi & 15;
            const int nseq = (tt * 16 + 4 * k0 + oyL) * 16 + ox;
            short8 v;
#pragma unroll
            for (int rr = 0; rr < 2; ++rr) {
#pragma unroll
              for (int k = 0; k < 2; ++k) {
                short2v pr = *(const short2v*)(shb +
                    swz(cp * 2 + rr, ((oyL * 2 + k) * 32 + ox * 2) * 2));
                v[rr * 4 + k * 2] = pr[0];
                v[rr * 4 + k * 2 + 1] = pr[1];
              }
            }
            *(short8*)(dst + base + (long)nseq * 2048 + (c2lo + cp * 2) * 4) = v;
          }
        }
      } else {                           // V transposed [f][nseq]
        if (cfg0) {
          const long base = (long)(b * 8192) * 512;
#pragma unroll
          for (int j = 0; j < 16; ++j) {
            const int e = j * 512 + tid;
            const int oyL = e >> 12, fu = e & 4095;
            const int ch = fu >> 4, pp = fu & 15;
            const int py = pp >> 2, px = pp & 3;
            const int yl = oyL * 4 + py;
            short8 v;
#pragma unroll
            for (int ox = 0; ox < 8; ++ox)
              v[ox] = *(const unsigned short*)(shb + swz(ch, (yl * 32 + ox * 4 + px) * 2));
            const long f = (long)(chb + ch) * 16 + pp;
            *(short8*)(dst + base + f * 512 + (tt * 8 + 2 * k0 + oyL) * 8) = v;
          }
        } else {
          const int c2lo = chb - 512;
          const long base = (long)(b * 2048) * 2048;
#pragma unroll
          for (int j = 0; j < 16; ++j) {
            const int e = j * 512 + tid;
            const int he = e & 1, oyL = (e >> 1) & 3, fu = e >> 3;
            const int c2 = fu >> 2, pp = fu & 3;
            const int py = pp >> 1, px = pp & 1;
            const int yl = oyL * 2 + py;
            short8 v;
#pragma unroll
            for (int i = 0; i < 8; ++i) {
              const int ox = he * 8 + i;
              v[i] = *(const unsigned short*)(shb + swz(c2, (yl * 32 + ox * 2 + px) * 2));
            }
            const long f = (long)(c2lo + c2) * 4 + pp;
            *(short8*)(dst + base + f * 2048 + (tt * 16 + 4 * k0 + oyL) * 16 + he * 8) = v;
          }
        }
      }
    } else if constexpr (EPI == 3) {    // ---- QKV hi: rows 0..127 cfg0, 128..255 cfg1 ----
      const int b = bz >> 2, tt = bz & 3;
      const int k0 = n0 >> 8;
      const int oyA = k0 >> 1, pyb = (k0 & 1) * 4;
      unsigned short* dstA = sel == 0 ? p.Q0 : sel == 1 ? p.K0 : p.V0t;
      unsigned short* dstB = sel == 0 ? p.Q1 : sel == 1 ? p.K1 : p.V1t;
      if (sel != 2) {
#pragma unroll
        for (int j = 0; j < 16; ++j) {
          const int e = j * 512 + tid;
          if (e < 4096) {                // cfg0: 8x8 patches
            const int ox = e >> 9, cy = e & 511;
            const int ch = cy >> 2, yl = cy & 3;
            const int nseq = 256 + (tt * 8 + oyA) * 8 + ox;
            short8 v = *(const short8*)(shb + swz(ch, (yl * 64 + ox * 8) * 2));
            *(short8*)(dstA + ((long)(b * 512 + nseq)) * 8192 + ch * 64 + (pyb + yl) * 8) = v;
          } else {                       // cfg1: 4x4 patches
            const int ee = e - 4096;
            const int ox = ee >> 8, cc = ee & 255;
            const int c2 = cc >> 1, hf = cc & 1;
            const int nseq = 1024 + (tt * 16 + k0) * 16 + ox;
            short8 v;
#pragma unroll
            for (int k = 0; k < 2; ++k) {
              short4v a = *(const short4v*)(shb +
                  swz(128 + c2, ((hf * 2 + k) * 64 + ox * 4) * 2));
              v[k * 4] = a[0]; v[k * 4 + 1] = a[1]; v[k * 4 + 2] = a[2]; v[k * 4 + 3] = a[3];
            }
            *(short8*)(dstB + ((long)(b * 2048 + nseq)) * 2048 + c2 * 16 + hf * 8) = v;
          }
        }
      } else {
#pragma unroll
        for (int j = 0; j < 16; ++j) {
          const int e = j * 512 + tid;
          if (e < 4096) {                // cfg0 V
            const int ch = e >> 5, yl = (e >> 3) & 3, px = e & 7;
            short8 v;
#pragma unroll
            for (int ox = 0; ox < 8; ++ox)
              v[ox] = *(const unsigned short*)(shb + swz(ch, (yl * 64 + ox * 8 + px) * 2));
            const long f = (long)ch * 64 + (pyb + yl) * 8 + px;
            *(short8*)(dstA + ((long)b * 8192 + f) * 512 + 256 + (tt * 8 + oyA) * 8) = v;
          } else {                       // cfg1 V
            const int ee = e - 4096;
            const int he = ee & 1, fu = ee >> 1;
            const int c2 = fu >> 4, pp = fu & 15;
            const int py = pp >> 2, px = pp & 3;
            short8 v;
#pragma unroll
            for (int i = 0; i < 8; ++i) {
              const int x = (he * 8 + i) * 4 + px;
              v[i] = *(const unsigned short*)(shb + swz(128 + c2, (py * 64 + x) * 2));
            }
            const long f = (long)c2 * 16 + pp;
            *(short8*)(dstB + ((long)b * 2048 + f) * 2048 + 1024 + (tt * 16 + k0) * 16 + he * 8) = v;
          }
        }
      }
    }
  }
}

// ---------------------------------------------------------------------------
// 3x3 conv as im2col GEMM on the 256-tile pipeline (same schedule).
// ---------------------------------------------------------------------------
template<int H, int W, int CIN, int KS, bool PARTIAL>
__global__ __launch_bounds__(512) void conv256(const unsigned short* __restrict__ Cinp,
                                               const unsigned short* __restrict__ Wt,
                                               const float* __restrict__ bias,
                                               float* __restrict__ out,
                                               float* __restrict__ P0,
                                               float* __restrict__ P1) {
  constexpr int HP = H + 2, WP = W + 2;
  constexpr int CC = CIN / KS;
  constexpr int NT = 9 * CC / 32;
  __shared__ __align__(16) unsigned short LDS[65536];
  const int tid = threadIdx.x;
  const int wv = tid >> 6, lane = tid & 63;
  const int wm = wv >> 2, wn = wv & 3;
  const int g = lane >> 4, l16 = lane & 15;
  const int bz = blockIdx.z;
  const int bt = bz / KS, ks = bz % KS;
  const int n0 = blockIdx.x * 256;

  const int r0 = tid >> 2;
  const int cs = (tid & 3) ^ ((r0 >> 1) & 3);
  const unsigned short* wA0 = Wt + (long)r0 * CIN + ks * CC + cs * 8;
  const unsigned short* wA1 = wA0 + (long)128 * CIN;
  const int p0 = n0 + r0, p1 = p0 + 128;
  const int y0p = p0 / W, x0p = p0 % W;
  const int y1p = p1 / W, x1p = p1 % W;
  const unsigned short* cB = Cinp + (long)bt * HP * WP * CIN + ks * CC + cs * 8;
  const unsigned short* pB0 = cB + ((long)y0p * WP + x0p) * CIN;
  const unsigned short* pB1 = cB + ((long)y1p * WP + x1p) * CIN;
  unsigned short* const lds0 = (unsigned short*)LDS;
  const int wbase = wv * 512;

  auto STAGE_A = [&](int t) {
    unsigned short* d = lds0 + (t & 3) * 16384;
    const int tap = t >> 3, tc = (t & 7) * 32;
    const long off = (long)tap * (256L * CIN) + tc;
    glds16(wA0 + off, d + wbase);
    glds16(wA1 + off, d + 4096 + wbase);
  };
  auto STAGE_B = [&](int t) {
    unsigned short* d = lds0 + (t & 3) * 16384 + 8192;
    const int tap = t >> 3, tc = (t & 7) * 32;
    const int ky = tap / 3, kx = tap - ky * 3;
    const long off = ((long)ky * WP + kx) * CIN + tc;
    glds16(pB0 + off, d + wbase);
    glds16(pB1 + off, d + 4096 + wbase);
  };

  STAGE_A(0); STAGE_B(0); STAGE_A(1); STAGE_B(1); STAGE_A(2); STAGE_B(2);

  floatx4 acc[8][4];
  const floatx4 z4 = {0.f, 0.f, 0.f, 0.f};
#pragma unroll
  for (int i = 0; i < 8; ++i)
#pragma unroll
    for (int j = 0; j < 4; ++j) acc[i][j] = z4;

  const int loff = l16 * 32 + ((g ^ ((l16 >> 1) & 3)) * 8);
  const int aRowB = wm * 128;

  for (int t = 0; t < NT; ++t) {
    const unsigned short* As = lds0 + (t & 3) * 16384;
    const unsigned short* Bs = As + 8192;
    if (t < NT - 2)        asm volatile("s_waitcnt vmcnt(8)" ::: "memory");
    else if (t == NT - 2)  asm volatile("s_waitcnt vmcnt(4)" ::: "memory");
    else                   asm volatile("s_waitcnt vmcnt(0)" ::: "memory");
    __builtin_amdgcn_s_barrier();
    __builtin_amdgcn_sched_barrier(0);
    if (t + 3 < NT) STAGE_A(t + 3);
    short8 bf[4], af[4], ag[4];
#pragma unroll
    for (int ni = 0; ni < 4; ++ni)
      bf[ni] = *(const short8*)(Bs + (wn * 64 + ni * 16) * 32 + loff);
#pragma unroll
    for (int mi = 0; mi < 4; ++mi)
      af[mi] = *(const short8*)(As + (aRowB + mi * 16) * 32 + loff);
#pragma unroll
    for (int mi = 0; mi < 4; ++mi)
      ag[mi] = *(const short8*)(As + (aRowB + 64 + mi * 16) * 32 + loff);
    __builtin_amdgcn_s_setprio(1);
#pragma unroll
    for (int mi = 0; mi < 4; ++mi)
#pragma unroll
      for (int ni = 0; ni < 4; ++ni)
        acc[mi][ni] = __builtin_amdgcn_mfma_f32_16x16x32_bf16(af[mi], bf[ni], acc[mi][ni], 0, 0, 0);
    __builtin_amdgcn_s_setprio(0);
    if (t + 3 < NT) STAGE_B(t + 3);
    __builtin_amdgcn_s_setprio(1);
#pragma unroll
    for (int mi = 0; mi < 4; ++mi)
#pragma unroll
      for (int ni = 0; ni < 4; ++ni)
        acc[4 + mi][ni] = __builtin_amdgcn_mfma_f32_16x16x32_bf16(ag[mi], bf[ni], acc[4 + mi][ni], 0, 0, 0);
    __builtin_amdgcn_s_setprio(0);
  }

  if constexpr (!PARTIAL) {
#pragma unroll
    for (int mi = 0; mi < 8; ++mi) {
#pragma unroll
      for (int ni = 0; ni < 4; ++ni) {
        const int pn = n0 + wn * 64 + ni * 16 + l16;
        const int y = pn / W, x = pn % W;
#pragma unroll
        for (int r4 = 0; r4 < 4; ++r4) {
          const int co = wm * 128 + mi * 16 + g * 4 + r4;
          float v = acc[mi][ni][r4] + bias[co];
          v = v > 0.f ? v : 0.2f * v;
          out[(((long)bt * 256 + co) * H + y) * W + x] = v;
        }
      }
    }
  } else {
    float* pout = (ks < 2 ? P0 : P1) + (long)(ks & 1) * (16L * 256 * H * W);
#pragma unroll
    for (int mi = 0; mi < 8; ++mi) {
#pragma unroll
      for (int ni = 0; ni < 4; ++ni) {
        const int pn = n0 + wn * 64 + ni * 16 + l16;
        const int y = pn / W, x = pn % W;
#pragma unroll
        for (int r4 = 0; r4 < 4; ++r4) {
          const int co = wm * 128 + mi * 16 + g * 4 + r4;
          pout[(((long)bt * 256 + co) * H + y) * W + x] = acc[mi][ni][r4];
        }
      }
    }
  }
}

// ---------------------------------------------------------------------------
// Row softmax in-place on bf16 rows of length L. One wave per row.
// ---------------------------------------------------------------------------
template<int L>
__global__ __launch_bounds__(256) void softmax_rows(unsigned short* S) {
  const int w = threadIdx.x >> 6, lane = threadIdx.x & 63;
  const long row = (long)blockIdx.x * 4 + w;
  unsigned short* R = S + row * L;
  constexpr int NC = L / 64;
  float v[NC];
  float m = -1e30f;
#pragma unroll
  for (int i = 0; i < NC; ++i) { v[i] = b2f(R[i * 64 + lane]); m = fmaxf(m, v[i]); }
#pragma unroll
  for (int off = 32; off; off >>= 1) m = fmaxf(m, __shfl_xor(m, off, 64));
  float s = 0.f;
#pragma unroll
  for (int i = 0; i < NC; ++i) { v[i] = __expf(v[i] - m); s += v[i]; }
#pragma unroll
  for (int off = 32; off; off >>= 1) s += __shfl_xor(s, off, 64);
  const float inv = 1.0f / s;
#pragma unroll
  for (int i = 0; i < NC; ++i) R[i * 64 + lane] = f2b(v[i] * inv);
}

// ---------------------------------------------------------------------------
// S0: sum 8 fp32 split-K slabs -> softmax -> bf16 [b][512][512]
// ---------------------------------------------------------------------------
__global__ __launch_bounds__(256) void softmax_red8(const float* __restrict__ P,
                                                    unsigned short* __restrict__ S) {
  const int w = threadIdx.x >> 6, lane = threadIdx.x & 63;
  const int rowg = blockIdx.x * 4 + w;
  const int b = rowg >> 9, n = rowg & 511;
  const float* base = P + ((long)b * 8) * 262144 + (long)n * 512 + lane;
  float v[8];
#pragma unroll
  for (int i = 0; i < 8; ++i) {
    float s = 0.f;
#pragma unroll
    for (int ks = 0; ks < 8; ++ks) s += base[(long)ks * 262144 + i * 64];
    v[i] = s;
  }
  float m = -1e30f;
#pragma unroll
  for (int i = 0; i < 8; ++i) m = fmaxf(m, v[i]);
#pragma unroll
  for (int off = 32; off; off >>= 1) m = fmaxf(m, __shfl_xor(m, off, 64));
  float s = 0.f;
#pragma unroll
  for (int i = 0; i < 8; ++i) { v[i] = __expf(v[i] - m); s += v[i]; }
#pragma unroll
  for (int off = 32; off; off >>= 1) s += __shfl_xor(s, off, 64);
  const float inv = 1.0f / s;
  unsigned short* R = S + (long)rowg * 512;
#pragma unroll
  for (int i = 0; i < 8; ++i) R[i * 64 + lane] = f2b(v[i] * inv);
}

// ---------------------------------------------------------------------------
// x [16][256][NPIX] fp32 (NCHW) -> xt [16][NPIX][256] bf16 (pixel-major)
// ---------------------------------------------------------------------------
__global__ __launch_bounds__(256) void xt_kernel(const float* __restrict__ x,
                                                 unsigned short* __restrict__ xt, int NPIX) {
  __shared__ unsigned short tile[64 * 65];
  const int tid = threadIdx.x;
  const int bt = blockIdx.z, ch0 = blockIdx.y * 64;
  const long pix0 = (long)blockIdx.x * 64;
  const float* src = x + ((long)bt * 256 + ch0) * NPIX + pix0;
#pragma unroll
  for (int i = 0; i < 16; ++i) {
    const int lin = i * 256 + tid;
    const int ch = lin >> 6, px = lin & 63;
    tile[ch * 65 + px] = f2b(src[(long)ch * NPIX + px]);
  }
  __syncthreads();
  unsigned short* dst = xt + ((long)bt * NPIX + pix0) * 256 + ch0;
#pragma unroll
  for (int i = 0; i < 16; ++i) {
    const int lin = i * 256 + tid;
    const int px = lin >> 6, ch = lin & 63;
    dst[(long)px * 256 + ch] = tile[ch * 65 + px];
  }
}

// ---------------------------------------------------------------------------
// Weight prep
// ---------------------------------------------------------------------------
__global__ void prep_qkv_w(const float* wq, const float* wk, const float* wv,
                           const float* bq, const float* bk, const float* bv,
                           unsigned short* Wcat, float* Bcat, int CO) {
  const int idx = blockIdx.x * 256 + threadIdx.x;
  const int n = 3 * CO * 256;
  if (idx < n) {
    const int sel = idx / (CO * 256);
    const int r = idx - sel * CO * 256;
    const float* wsel = sel == 0 ? wq : (sel == 1 ? wk : wv);
    Wcat[idx] = f2b(wsel[r]);
  }
  if (idx < 3 * CO) {
    const int sel = idx / CO;
    const int r = idx - sel * CO;
    const float* bsel = sel == 0 ? bq : (sel == 1 ? bk : bv);
    Bcat[idx] = bsel[r];
  }
}

__global__ void prep_conv_w(const float* wo, unsigned short* Wt, int CIN) {
  const int idx = blockIdx.x * 256 + threadIdx.x;
  const int n = 9 * 256 * CIN;
  if (idx < n) {
    const int t9 = idx / (256 * CIN);
    const int rem = idx - t9 * 256 * CIN;
    const int o = rem / CIN, i = rem - o * CIN;
    Wt[idx] = f2b(wo[((long)o * CIN + i) * 9 + t9]);   // [9][256][CIN]
  }
}

// ---------------------------------------------------------------------------
// Zero the 1-px halo border of a padded NHWC buffer [16][HP][WP][C]
// ---------------------------------------------------------------------------
__global__ __launch_bounds__(256) void zero_border(unsigned short* buf, int HP, int WP, int C) {
  const long i = (long)blockIdx.x * 256 + threadIdx.x;
  const int per_px = C >> 3;
  const int strip = 2 * WP + 2 * (HP - 2);
  const long tot = (long)16 * strip * per_px;
  if (i >= tot) return;
  const int c8 = (int)(i % per_px);
  const long r = i / per_px;
  const int s = (int)(r % strip);
  const int bt = (int)(r / strip);
  int y, x;
  if (s < WP) { y = 0; x = s; }
  else if (s < 2 * WP) { y = HP - 1; x = s - WP; }
  else if (s < 2 * WP + (HP - 2)) { y = s - 2 * WP + 1; x = 0; }
  else { y = s - 2 * WP - (HP - 2) + 1; x = WP - 1; }
  const short8 z = {0, 0, 0, 0, 0, 0, 0, 0};
  *(short8*)(buf + (((long)bt * HP + y) * WP + x) * C + c8 * 8) = z;
}

// ---------------------------------------------------------------------------
// Repack attention outputs Y (patch-major) -> padded NHWC conv inputs
// ---------------------------------------------------------------------------
__global__ __launch_bounds__(256) void repack_lo(const unsigned short* __restrict__ Y0,
                                                 const unsigned short* __restrict__ Y1,
                                                 unsigned short* __restrict__ out) {
  const int tid = threadIdx.x;
  const int blk = blockIdx.x;
  if (blk < 1024) {
    const int b = blk >> 8, n = blk & 255;
    const int t = n >> 6, oh = (n >> 3) & 7, ow = n & 7;
    const unsigned short* row = Y0 + ((long)(b * 512 + n)) * 8192;
    const int bt = b * 4 + t;
#pragma unroll
    for (int j = 0; j < 32; ++j) {
      const int idx = j * 256 + tid;
      const int pp = idx >> 9, ch = idx & 511;
      const int py = pp >> 2, px = pp & 3;
      out[(((long)bt * 34 + oh * 4 + py + 1) * 34 + ow * 4 + px + 1) * 1024 + ch] = row[ch * 16 + pp];
    }
  } else {
    const int q = blk - 1024;
    const int b = q >> 10, n = q & 1023;
    const int t = n >> 8, oh = (n >> 4) & 15, ow = n & 15;
    const unsigned short* row = Y1 + ((long)(b * 2048 + n)) * 2048;
    const int bt = b * 4 + t;
#pragma unroll
    for (int j = 0; j < 8; ++j) {
      const int idx = j * 256 + tid;
      const int pp = idx >> 9, ch = idx & 511;
      const int py = pp >> 1, px = pp & 1;
      out[(((long)bt * 34 + oh * 2 + py + 1) * 34 + ow * 2 + px + 1) * 1024 + 512 + ch] = row[ch * 4 + pp];
    }
  }
}

__global__ __launch_bounds__(256) void repack_hi(const unsigned short* __restrict__ Y0,
                                                 const unsigned short* __restrict__ Y1,
                                                 unsigned short* __restrict__ out) {
  const int tid = threadIdx.x;
  const int blk = blockIdx.x;
  if (blk < 1024) {
    const int b = blk >> 8, n = blk & 255;
    const int t = n >> 6, oh = (n >> 3) & 7, ow = n & 7;
    const unsigned short* row = Y0 + ((long)(b * 512 + 256 + n)) * 8192;
    const int bt = b * 4 + t;
#pragma unroll
    for (int j = 0; j < 32; ++j) {
      const int idx = j * 256 + tid;
      const int pp = idx >> 7, ch = idx & 127;
      const int py = pp >> 3, px = pp & 7;
      out[(((long)bt * 66 + oh * 8 + py + 1) * 66 + ow * 8 + px + 1) * 256 + ch] = row[ch * 64 + pp];
    }
  } else {
    const int q = blk - 1024;
    const int b = q >> 10, n = q & 1023;
    const int t = n >> 8, oh = (n >> 4) & 15, ow = n & 15;
    const unsigned short* row = Y1 + ((long)(b * 2048 + 1024 + n)) * 2048;
    const int bt = b * 4 + t;
#pragma unroll
    for (int j = 0; j < 8; ++j) {
      const int idx = j * 256 + tid;
      const int pp = idx >> 7, ch = idx & 127;
      const int py = pp >> 2, px = pp & 3;
      out[(((long)bt * 66 + oh * 4 + py + 1) * 66 + ow * 4 + px + 1) * 256 + 128 + ch] = row[ch * 16 + pp];
    }
  }
}

// ---------------------------------------------------------------------------
// Sum 4 conv partial slabs + bias + leaky-relu -> out
// ---------------------------------------------------------------------------
__global__ __launch_bounds__(256) void reduce_lrelu(const floatx4* __restrict__ P0,
                                                    const floatx4* __restrict__ P1,
                                                    const float* __restrict__ bias,
                                                    floatx4* __restrict__ out) {
  const long i = (long)blockIdx.x * 256 + threadIdx.x;
  constexpr long SL = 1048576;
  floatx4 a = P0[i], b = P0[SL + i], c = P1[i], d = P1[SL + i];
  const int co = ((int)(i >> 8)) & 255;
  const float bv = bias[co];
  floatx4 r;
#pragma unroll
  for (int j = 0; j < 4; ++j) {
    float v = a[j] + b[j] + c[j] + d[j] + bv;
    r[j] = v > 0.f ? v : 0.2f * v;
  }
  out[i] = r;
}

// ---------------------------------------------------------------------------
extern "C" void kernel_launch(void* const* d_in, const int* in_sizes, int n_in,
                              void* d_out, int out_size, void* d_ws, size_t ws_size,
                              hipStream_t stream) {
  (void)in_sizes; (void)n_in; (void)out_size; (void)ws_size;
  const float* x_lo = (const float*)d_in[0];
  const float* x_hi = (const float*)d_in[1];
  const float* wq_lo = (const float*)d_in[3];
  const float* bq_lo = (const float*)d_in[4];
  const float* wk_lo = (const float*)d_in[5];
  const float* bk_lo = (const float*)d_in[6];
  const float* wv_lo = (const float*)d_in[7];
  const float* bv_lo = (const float*)d_in[8];
  const float* wq_hi = (const float*)d_in[9];
  const float* bq_hi = (const float*)d_in[10];
  const float* wk_hi = (const float*)d_in[11];
  const float* bk_hi = (const float*)d_in[12];
  const float* wv_hi = (const float*)d_in[13];
  const float* bv_hi = (const float*)d_in[14];
  const float* wo_lo = (const float*)d_in[15];
  const float* bo_lo = (const float*)d_in[16];
  const float* wo_hi = (const float*)d_in[17];
  const float* bo_hi = (const float*)d_in[18];
  float* out = (float*)d_out;

  char* ws = (char*)d_ws;
  const long B0 = 33554432;
  unsigned short* Qp0 = (unsigned short*)(ws);
  unsigned short* Kp0 = (unsigned short*)(ws + B0);
  unsigned short* V0t = (unsigned short*)(ws + 2 * B0);
  unsigned short* Qp1 = (unsigned short*)(ws + 3 * B0);
  unsigned short* Kp1 = (unsigned short*)(ws + 4 * B0);
  unsigned short* V1t = (unsigned short*)(ws + 5 * B0);
  char* ptr = ws + 6 * B0;
  unsigned short* S0 = (unsigned short*)ptr;     ptr += 2097152;
  unsigned short* Xt_lo = (unsigned short*)ptr;  ptr += 8388608;
  unsigned short* Xt_hi = (unsigned short*)ptr;  ptr += 33554432;
  unsigned short* Wcat_lo = (unsigned short*)ptr; ptr += 1572864;
  unsigned short* Wcat_hi = (unsigned short*)ptr; ptr += 393216;
  float* Bcat_lo = (float*)ptr;                  ptr += 12288;
  float* Bcat_hi = (float*)ptr;                  ptr += 3072;
  unsigned short* Wt_lo = (unsigned short*)ptr;  ptr += 4718592;
  unsigned short* Wt_hi = (unsigned short*)ptr;  ptr += 1179648;
  unsigned short* S1 = Kp0;
  unsigned short* Y0 = Qp0;
  unsigned short* Y1 = Qp1;
  unsigned short* CinP_lo = Kp0;
  unsigned short* CinP_hi = Kp1;
  float* S0p = (float*)Xt_hi;
  float* PC0 = (float*)Qp0;
  float* PC1 = (float*)Qp1;

  // --- weight/input prep ---
  prep_qkv_w<<<(3 * 1024 * 256 + 255) / 256, 256, 0, stream>>>(
      wq_lo, wk_lo, wv_lo, bq_lo, bk_lo, bv_lo, Wcat_lo, Bcat_lo, 1024);
  prep_qkv_w<<<(3 * 256 * 256 + 255) / 256, 256, 0, stream>>>(
      wq_hi, wk_hi, wv_hi, bq_hi, bk_hi, bv_hi, Wcat_hi, Bcat_hi, 256);
  prep_conv_w<<<(9 * 256 * 1024 + 255) / 256, 256, 0, stream>>>(wo_lo, Wt_lo, 1024);
  prep_conv_w<<<(9 * 256 * 256 + 255) / 256, 256, 0, stream>>>(wo_hi, Wt_hi, 256);
  xt_kernel<<<dim3(16, 4, 16), 256, 0, stream>>>(x_lo, Xt_lo, 1024);
  xt_kernel<<<dim3(64, 4, 16), 256, 0, stream>>>(x_hi, Xt_hi, 4096);

  // --- QKV projections (1x1 conv as TN-GEMM), staged coalesced scatter ---
  {
    GemmP p{};
    p.A = Wcat_lo; p.B = Xt_lo; p.sAb = 0; p.sBb = 1024L * 256;
    p.lda = 256; p.ldb = 256; p.K = 256;
    p.bias = Bcat_lo;
    p.Q0 = Qp0; p.K0 = Kp0; p.V0t = V0t; p.Q1 = Qp1; p.K1 = Kp1; p.V1t = V1t;
    gemm256<2><<<dim3(4, 12, 16), 512, 0, stream>>>(p);
    p.A = Wcat_hi; p.B = Xt_hi; p.sBb = 4096L * 256; p.bias = Bcat_hi;
    gemm256<3><<<dim3(16, 3, 16), 512, 0, stream>>>(p);
  }

  // --- attention cfg0: n=512, d=8192 (split-K 8 + fused reduce softmax) ---
  {
    GemmP s{};
    s.A = Qp0; s.B = Kp0; s.sAb = 512L * 8192; s.sBb = 512L * 8192;
    s.lda = 8192; s.ldb = 8192; s.K = 8192;
    s.Cp = S0p; s.sCb = 512L * 512; s.ldc = 512;
    gemm256<1><<<dim3(2, 2, 32), 512, 0, stream>>>(s);
    softmax_red8<<<512, 256, 0, stream>>>(S0p, S0);
    GemmP pv{};
    pv.A = S0; pv.B = V0t; pv.sAb = 512L * 512; pv.sBb = 8192L * 512;
    pv.lda = 512; pv.ldb = 512; pv.K = 512;
    pv.C = Y0; pv.sCb = 512L * 8192; pv.ldc = 8192;
    gemm256<0><<<dim3(32, 2, 4), 512, 0, stream>>>(pv);
  }

  // --- attention cfg1: n=2048, d=2048 ---
  {
    GemmP s{};
    s.A = Qp1; s.B = Kp1; s.sAb = 2048L * 2048; s.sBb = 2048L * 2048;
    s.lda = 2048; s.ldb = 2048; s.K = 2048;
    s.C = S1; s.sCb = 2048L * 2048; s.ldc = 2048;
    gemm256<0><<<dim3(8, 8, 4), 512, 0, stream>>>(s);
    softmax_rows<2048><<<2048, 256, 0, stream>>>(S1);
    GemmP pv{};
    pv.A = S1; pv.B = V1t; pv.sAb = 2048L * 2048; pv.sBb = 2048L * 2048;
    pv.lda = 2048; pv.ldb = 2048; pv.K = 2048;
    pv.C = Y1; pv.sCb = 2048L * 2048; pv.ldc = 2048;
    gemm256<0><<<dim3(8, 8, 4), 512, 0, stream>>>(pv);
  }

  // --- halo zeroing + from_patches repack into padded NHWC conv inputs ---
  zero_border<<<1056, 256, 0, stream>>>(CinP_lo, 34, 34, 1024);
  zero_border<<<520, 256, 0, stream>>>(CinP_hi, 66, 66, 256);
  repack_lo<<<5120, 256, 0, stream>>>(Y0, Y1, CinP_lo);
  repack_hi<<<5120, 256, 0, stream>>>(Y0, Y1, CinP_hi);

  // --- 3x3 convs as im2col GEMM on the 256-tile pipeline ---
  conv256<32, 32, 1024, 4, true><<<dim3(4, 1, 64), 512, 0, stream>>>(
      CinP_lo, Wt_lo, bo_lo, out, PC0, PC1);
  reduce_lrelu<<<4096, 256, 0, stream>>>((const floatx4*)PC0, (const floatx4*)PC1, bo_lo,
                                         (floatx4*)out);
  conv256<64, 64, 256, 1, false><<<dim3(16, 1, 16), 512, 0, stream>>>(
      CinP_hi, Wt_hi, bo_hi, out + 4194304, nullptr, nullptr);
}

// Round 8
// 580.522 us; speedup vs baseline: 1.8901x; 1.0574x over previous
//
#include <hip/hip_runtime.h>
#include <hip/hip_bf16.h>
#include <stdint.h>

typedef __attribute__((ext_vector_type(8))) short short8;
typedef __attribute__((ext_vector_type(4))) short short4v;
typedef __attribute__((ext_vector_type(2))) short short2v;
typedef __attribute__((ext_vector_type(4))) float floatx4;

__device__ __forceinline__ unsigned short f2b(float f) {
  unsigned u = __builtin_bit_cast(unsigned, f);
  unsigned r = u + 0x7fffu + ((u >> 16) & 1u);
  return (unsigned short)(r >> 16);
}
__device__ __forceinline__ float b2f(unsigned short h) {
  unsigned u = ((unsigned)h) << 16;
  return __builtin_bit_cast(float, u);
}
__device__ __forceinline__ void glds16(const unsigned short* src, unsigned short* dst) {
  __builtin_amdgcn_global_load_lds((const __attribute__((address_space(1))) void*)src,
                                   (__attribute__((address_space(3))) void*)dst, 16, 0, 0);
}
// epilogue LDS swizzle: row r (0..255), o = byte offset in 512B row.
__device__ __forceinline__ int swz(int r, int o) {
  return (r << 9) + (o ^ ((((o >> 7) & 3) ^ (r & 7)) << 4));
}

// ---------------------------------------------------------------------------
// 256x256-tile TN GEMM core (unchanged from R7): 512 thr = 8 waves (2Mx4N);
// BK=32; 4-buffer LDS ring; counted vmcnt 8/4/0; 1 barrier/K-tile; setprio;
// K-loop swizzle f(row)=(row>>1)&3 (2-way aliasing = free).
// EPI 0: staged bf16 C. EPI 1: split-K(16) bf16 partials (direct stores).
// EPI 2/3: staged QKV lo/hi scatter.
// ---------------------------------------------------------------------------
struct GemmP {
  const unsigned short* A;
  const unsigned short* B;
  long sAb, sBb;
  int lda, ldb, K;
  unsigned short* C; long sCb; int ldc;
  const float* bias;
  unsigned short *Q0, *K0, *V0t, *Q1, *K1, *V1t;
};

template<int EPI>
__global__ __launch_bounds__(512) void gemm256(GemmP p) {
  __shared__ __align__(16) unsigned short LDS[65536];
  const int tid = threadIdx.x;
  const int wv = tid >> 6, lane = tid & 63;
  const int wm = wv >> 2, wn = wv & 3;
  const int g = lane >> 4, l16 = lane & 15;
  const int bz = blockIdx.z;
  const int m0 = blockIdx.y * 256, n0 = blockIdx.x * 256;

  int bb = bz, koff = 0, Keff = p.K;
  if constexpr (EPI == 1) { bb = bz >> 4; koff = (bz & 15) * (p.K >> 4); Keff = p.K >> 4; }
  const unsigned short* Ab = p.A + (long)bb * p.sAb + (long)m0 * p.lda + koff;
  const unsigned short* Bb = p.B + (long)bb * p.sBb + (long)n0 * p.ldb + koff;
  const int NT = Keff >> 5;

  const int r0 = tid >> 2;
  const int cs = (tid & 3) ^ ((r0 >> 1) & 3);
  const unsigned short* aS0 = Ab + (long)r0 * p.lda + cs * 8;
  const unsigned short* aS1 = aS0 + (long)128 * p.lda;
  const unsigned short* bS0 = Bb + (long)r0 * p.ldb + cs * 8;
  const unsigned short* bS1 = bS0 + (long)128 * p.ldb;
  unsigned short* const lds0 = (unsigned short*)LDS;
  const int wbase = wv * 512;

  auto STAGE_A = [&](int t) {
    unsigned short* d = lds0 + (t & 3) * 16384;
    const long ko = (long)t * 32;
    glds16(aS0 + ko, d + wbase);
    glds16(aS1 + ko, d + 4096 + wbase);
  };
  auto STAGE_B = [&](int t) {
    unsigned short* d = lds0 + (t & 3) * 16384 + 8192;
    const long ko = (long)t * 32;
    glds16(bS0 + ko, d + wbase);
    glds16(bS1 + ko, d + 4096 + wbase);
  };

  STAGE_A(0); STAGE_B(0); STAGE_A(1); STAGE_B(1); STAGE_A(2); STAGE_B(2);

  floatx4 acc[8][4];
  const floatx4 z4 = {0.f, 0.f, 0.f, 0.f};
#pragma unroll
  for (int i = 0; i < 8; ++i)
#pragma unroll
    for (int j = 0; j < 4; ++j) acc[i][j] = z4;

  const int loff = l16 * 32 + ((g ^ ((l16 >> 1) & 3)) * 8);
  const int aRowB = wm * 128;

  for (int t = 0; t < NT; ++t) {
    const unsigned short* As = lds0 + (t & 3) * 16384;
    const unsigned short* Bs = As + 8192;
    if (t < NT - 2)        asm volatile("s_waitcnt vmcnt(8)" ::: "memory");
    else if (t == NT - 2)  asm volatile("s_waitcnt vmcnt(4)" ::: "memory");
    else                   asm volatile("s_waitcnt vmcnt(0)" ::: "memory");
    __builtin_amdgcn_s_barrier();
    __builtin_amdgcn_sched_barrier(0);
    if (t + 3 < NT) STAGE_A(t + 3);
    short8 bf[4], af[4], ag[4];
#pragma unroll
    for (int ni = 0; ni < 4; ++ni)
      bf[ni] = *(const short8*)(Bs + (wn * 64 + ni * 16) * 32 + loff);
#pragma unroll
    for (int mi = 0; mi < 4; ++mi)
      af[mi] = *(const short8*)(As + (aRowB + mi * 16) * 32 + loff);
#pragma unroll
    for (int mi = 0; mi < 4; ++mi)
      ag[mi] = *(const short8*)(As + (aRowB + 64 + mi * 16) * 32 + loff);
    __builtin_amdgcn_s_setprio(1);
#pragma unroll
    for (int mi = 0; mi < 4; ++mi)
#pragma unroll
      for (int ni = 0; ni < 4; ++ni)
        acc[mi][ni] = __builtin_amdgcn_mfma_f32_16x16x32_bf16(af[mi], bf[ni], acc[mi][ni], 0, 0, 0);
    __builtin_amdgcn_s_setprio(0);
    if (t + 3 < NT) STAGE_B(t + 3);
    __builtin_amdgcn_s_setprio(1);
#pragma unroll
    for (int mi = 0; mi < 4; ++mi)
#pragma unroll
      for (int ni = 0; ni < 4; ++ni)
        acc[4 + mi][ni] = __builtin_amdgcn_mfma_f32_16x16x32_bf16(ag[mi], bf[ni], acc[4 + mi][ni], 0, 0, 0);
    __builtin_amdgcn_s_setprio(0);
  }

  if constexpr (EPI == 1) {          // bf16 partial store, coalesced per lane-row
    unsigned short* C = p.C + (long)bz * p.sCb;
#pragma unroll
    for (int mi = 0; mi < 8; ++mi) {
#pragma unroll
      for (int ni = 0; ni < 4; ++ni) {
        const int col = n0 + wn * 64 + ni * 16 + l16;
#pragma unroll
        for (int r4 = 0; r4 < 4; ++r4) {
          const int row = m0 + wm * 128 + mi * 16 + g * 4 + r4;
          C[(long)row * p.ldc + col] = f2b(acc[mi][ni][r4]);
        }
      }
    }
  } else {
    // ------- staged epilogue: acc (+bias/scale) -> LDS tile [256co][256pix] -------
    __syncthreads();
    char* shb = (char*)LDS;
    const int sel = (EPI == 2) ? (m0 >> 10) : (m0 >> 8);
#pragma unroll
    for (int mi = 0; mi < 8; ++mi) {
#pragma unroll
      for (int ni = 0; ni < 4; ++ni) {
        const int c = wn * 64 + ni * 16 + l16;
#pragma unroll
        for (int r4 = 0; r4 < 4; ++r4) {
          const int rr = wm * 128 + mi * 16 + g * 4 + r4;
          float v = acc[mi][ni][r4];
          if constexpr (EPI == 2 || EPI == 3) {
            v += p.bias[m0 + rr];
            if (sel == 0) {
              float sc;
              if constexpr (EPI == 2) sc = ((m0 & 1023) < 512) ? 0.011048543456039806f
                                                               : 0.02209708691207961f;
              else                    sc = (rr < 128) ? 0.011048543456039806f
                                                      : 0.02209708691207961f;
              v *= sc;
            }
          }
          *(unsigned short*)(shb + swz(rr, c * 2)) = f2b(v);
        }
      }
    }
    __syncthreads();

    if constexpr (EPI == 0) {
      unsigned short* C = p.C + (long)bz * p.sCb;
#pragma unroll
      for (int j = 0; j < 16; ++j) {
        const int e = j * 512 + tid;
        const int r = e >> 5, ck = e & 31;
        short8 v = *(const short8*)(shb + swz(r, ck * 16));
        *(short8*)(C + (long)(m0 + r) * p.ldc + n0 + ck * 8) = v;
      }
    } else if constexpr (EPI == 2) {    // ---- QKV lo ----
      const int chb = m0 & 1023;
      const bool cfg0 = chb < 512;
      const int b = bz >> 2, tt = bz & 3;
      const int k0 = n0 >> 8;
      unsigned short* dst = cfg0 ? (sel == 0 ? p.Q0 : sel == 1 ? p.K0 : p.V0t)
                                 : (sel == 0 ? p.Q1 : sel == 1 ? p.K1 : p.V1t);
      if (sel != 2) {
        if (cfg0) {                      // 4x4 patches, d=8192
          const long base = (long)(b * 512) * 8192;
#pragma unroll
          for (int j = 0; j < 16; ++j) {
            const int e = j * 512 + tid;
            const int pi = e >> 9, idx2 = e & 511;
            const int ch = idx2 >> 1, hf = idx2 & 1;
            const int oyL = pi >> 3, ox = pi & 7;
            const int nseq = (tt * 8 + 2 * k0 + oyL) * 8 + ox;
            const int yl = oyL * 4 + hf * 2;
            short4v a = *(const short4v*)(shb + swz(ch, (yl * 32 + ox * 4) * 2));
            short4v b2 = *(const short4v*)(shb + swz(ch, ((yl + 1) * 32 + ox * 4) * 2));
            short8 v = {a[0], a[1], a[2], a[3], b2[0], b2[1], b2[2], b2[3]};
            *(short8*)(dst + base + (long)nseq * 8192 + (chb + ch) * 16 + hf * 8) = v;
          }
        } else {                         // 2x2 patches, d=2048
          const int c2lo = chb - 512;
          const long base = (long)(b * 2048) * 2048;
#pragma unroll
          for (int j = 0; j < 16; ++j) {
            const int e = j * 512 + tid;
            const int pi = e >> 7, cp = e & 127;
            const int oyL = pi >> 4, ox = pi & 15;
            const int nseq = (tt * 16 + 4 * k0 + oyL) * 16 + ox;
            short8 v;
#pragma unroll
            for (int rr = 0; rr < 2; ++rr) {
#pragma unroll
              for (int k = 0; k < 2; ++k) {
                short2v pr = *(const short2v*)(shb +
                    swz(cp * 2 + rr, ((oyL * 2 + k) * 32 + ox * 2) * 2));
                v[rr * 4 + k * 2] = pr[0];
                v[rr * 4 + k * 2 + 1] = pr[1];
              }
            }
            *(short8*)(dst + base + (long)nseq * 2048 + (c2lo + cp * 2) * 4) = v;
          }
        }
      } else {                           // V transposed [f][nseq]
        if (cfg0) {
          const long base = (long)(b * 8192) * 512;
#pragma unroll
          for (int j = 0; j < 16; ++j) {
            const int e = j * 512 + tid;
            const int oyL = e >> 12, fu = e & 4095;
            const int ch = fu >> 4, pp = fu & 15;
            const int py = pp >> 2, px = pp & 3;
            const int yl = oyL * 4 + py;
            short8 v;
#pragma unroll
            for (int ox = 0; ox < 8; ++ox)
              v[ox] = *(const unsigned short*)(shb + swz(ch, (yl * 32 + ox * 4 + px) * 2));
            const long f = (long)(chb + ch) * 16 + pp;
            *(short8*)(dst + base + f * 512 + (tt * 8 + 2 * k0 + oyL) * 8) = v;
          }
        } else {
          const int c2lo = chb - 512;
          const long base = (long)(b * 2048) * 2048;
#pragma unroll
          for (int j = 0; j < 16; ++j) {
            const int e = j * 512 + tid;
            const int he = e & 1, oyL = (e >> 1) & 3, fu = e >> 3;
            const int c2 = fu >> 2, pp = fu & 3;
            const int py = pp >> 1, px = pp & 1;
            const int yl = oyL * 2 + py;
            short8 v;
#pragma unroll
            for (int i = 0; i < 8; ++i) {
              const int ox = he * 8 + i;
              v[i] = *(const unsigned short*)(shb + swz(c2, (yl * 32 + ox * 2 + px) * 2));
            }
            const long f = (long)(c2lo + c2) * 4 + pp;
            *(short8*)(dst + base + f * 2048 + (tt * 16 + 4 * k0 + oyL) * 16 + he * 8) = v;
          }
        }
      }
    } else if constexpr (EPI == 3) {    // ---- QKV hi ----
      const int b = bz >> 2, tt = bz & 3;
      const int k0 = n0 >> 8;
      const int oyA = k0 >> 1, pyb = (k0 & 1) * 4;
      unsigned short* dstA = sel == 0 ? p.Q0 : sel == 1 ? p.K0 : p.V0t;
      unsigned short* dstB = sel == 0 ? p.Q1 : sel == 1 ? p.K1 : p.V1t;
      if (sel != 2) {
#pragma unroll
        for (int j = 0; j < 16; ++j) {
          const int e = j * 512 + tid;
          if (e < 4096) {                // cfg0: 8x8 patches
            const int ox = e >> 9, cy = e & 511;
            const int ch = cy >> 2, yl = cy & 3;
            const int nseq = 256 + (tt * 8 + oyA) * 8 + ox;
            short8 v = *(const short8*)(shb + swz(ch, (yl * 64 + ox * 8) * 2));
            *(short8*)(dstA + ((long)(b * 512 + nseq)) * 8192 + ch * 64 + (pyb + yl) * 8) = v;
          } else {                       // cfg1: 4x4 patches
            const int ee = e - 4096;
            const int ox = ee >> 8, cc = ee & 255;
            const int c2 = cc >> 1, hf = cc & 1;
            const int nseq = 1024 + (tt * 16 + k0) * 16 + ox;
            short8 v;
#pragma unroll
            for (int k = 0; k < 2; ++k) {
              short4v a = *(const short4v*)(shb +
                  swz(128 + c2, ((hf * 2 + k) * 64 + ox * 4) * 2));
              v[k * 4] = a[0]; v[k * 4 + 1] = a[1]; v[k * 4 + 2] = a[2]; v[k * 4 + 3] = a[3];
            }
            *(short8*)(dstB + ((long)(b * 2048 + nseq)) * 2048 + c2 * 16 + hf * 8) = v;
          }
        }
      } else {
#pragma unroll
        for (int j = 0; j < 16; ++j) {
          const int e = j * 512 + tid;
          if (e < 4096) {                // cfg0 V
            const int ch = e >> 5, yl = (e >> 3) & 3, px = e & 7;
            short8 v;
#pragma unroll
            for (int ox = 0; ox < 8; ++ox)
              v[ox] = *(const unsigned short*)(shb + swz(ch, (yl * 64 + ox * 8 + px) * 2));
            const long f = (long)ch * 64 + (pyb + yl) * 8 + px;
            *(short8*)(dstA + ((long)b * 8192 + f) * 512 + 256 + (tt * 8 + oyA) * 8) = v;
          } else {                       // cfg1 V
            const int ee = e - 4096;
            const int he = ee & 1, fu = ee >> 1;
            const int c2 = fu >> 4, pp = fu & 15;
            const int py = pp >> 2, px = pp & 3;
            short8 v;
#pragma unroll
            for (int i = 0; i < 8; ++i) {
              const int x = (he * 8 + i) * 4 + px;
              v[i] = *(const unsigned short*)(shb + swz(128 + c2, (py * 64 + x) * 2));
            }
            const long f = (long)c2 * 16 + pp;
            *(short8*)(dstB + ((long)b * 2048 + f) * 2048 + 1024 + (tt * 16 + k0) * 16 + he * 8) = v;
          }
        }
      }
    }
  }
}

// ---------------------------------------------------------------------------
// 3x3 conv as im2col GEMM (unchanged core).
// ---------------------------------------------------------------------------
template<int H, int W, int CIN, int KS, bool PARTIAL>
__global__ __launch_bounds__(512) void conv256(const unsigned short* __restrict__ Cinp,
                                               const unsigned short* __restrict__ Wt,
                                               const float* __restrict__ bias,
                                               float* __restrict__ out,
                                               float* __restrict__ P0,
                                               float* __restrict__ P1) {
  constexpr int HP = H + 2, WP = W + 2;
  constexpr int CC = CIN / KS;
  constexpr int NT = 9 * CC / 32;
  __shared__ __align__(16) unsigned short LDS[65536];
  const int tid = threadIdx.x;
  const int wv = tid >> 6, lane = tid & 63;
  const int wm = wv >> 2, wn = wv & 3;
  const int g = lane >> 4, l16 = lane & 15;
  const int bz = blockIdx.z;
  const int bt = bz / KS, ks = bz % KS;
  const int n0 = blockIdx.x * 256;

  const int r0 = tid >> 2;
  const int cs = (tid & 3) ^ ((r0 >> 1) & 3);
  const unsigned short* wA0 = Wt + (long)r0 * CIN + ks * CC + cs * 8;
  const unsigned short* wA1 = wA0 + (long)128 * CIN;
  const int p0 = n0 + r0, p1 = p0 + 128;
  const int y0p = p0 / W, x0p = p0 % W;
  const int y1p = p1 / W, x1p = p1 % W;
  const unsigned short* cB = Cinp + (long)bt * HP * WP * CIN + ks * CC + cs * 8;
  const unsigned short* pB0 = cB + ((long)y0p * WP + x0p) * CIN;
  const unsigned short* pB1 = cB + ((long)y1p * WP + x1p) * CIN;
  unsigned short* const lds0 = (unsigned short*)LDS;
  const int wbase = wv * 512;

  auto STAGE_A = [&](int t) {
    unsigned short* d = lds0 + (t & 3) * 16384;
    const int tap = t >> 3, tc = (t & 7) * 32;
    const long off = (long)tap * (256L * CIN) + tc;
    glds16(wA0 + off, d + wbase);
    glds16(wA1 + off, d + 4096 + wbase);
  };
  auto STAGE_B = [&](int t) {
    unsigned short* d = lds0 + (t & 3) * 16384 + 8192;
    const int tap = t >> 3, tc = (t & 7) * 32;
    const int ky = tap / 3, kx = tap - ky * 3;
    const long off = ((long)ky * WP + kx) * CIN + tc;
    glds16(pB0 + off, d + wbase);
    glds16(pB1 + off, d + 4096 + wbase);
  };

  STAGE_A(0); STAGE_B(0); STAGE_A(1); STAGE_B(1); STAGE_A(2); STAGE_B(2);

  floatx4 acc[8][4];
  const floatx4 z4 = {0.f, 0.f, 0.f, 0.f};
#pragma unroll
  for (int i = 0; i < 8; ++i)
#pragma unroll
    for (int j = 0; j < 4; ++j) acc[i][j] = z4;

  const int loff = l16 * 32 + ((g ^ ((l16 >> 1) & 3)) * 8);
  const int aRowB = wm * 128;

  for (int t = 0; t < NT; ++t) {
    const unsigned short* As = lds0 + (t & 3) * 16384;
    const unsigned short* Bs = As + 8192;
    if (t < NT - 2)        asm volatile("s_waitcnt vmcnt(8)" ::: "memory");
    else if (t == NT - 2)  asm volatile("s_waitcnt vmcnt(4)" ::: "memory");
    else                   asm volatile("s_waitcnt vmcnt(0)" ::: "memory");
    __builtin_amdgcn_s_barrier();
    __builtin_amdgcn_sched_barrier(0);
    if (t + 3 < NT) STAGE_A(t + 3);
    short8 bf[4], af[4], ag[4];
#pragma unroll
    for (int ni = 0; ni < 4; ++ni)
      bf[ni] = *(const short8*)(Bs + (wn * 64 + ni * 16) * 32 + loff);
#pragma unroll
    for (int mi = 0; mi < 4; ++mi)
      af[mi] = *(const short8*)(As + (aRowB + mi * 16) * 32 + loff);
#pragma unroll
    for (int mi = 0; mi < 4; ++mi)
      ag[mi] = *(const short8*)(As + (aRowB + 64 + mi * 16) * 32 + loff);
    __builtin_amdgcn_s_setprio(1);
#pragma unroll
    for (int mi = 0; mi < 4; ++mi)
#pragma unroll
      for (int ni = 0; ni < 4; ++ni)
        acc[mi][ni] = __builtin_amdgcn_mfma_f32_16x16x32_bf16(af[mi], bf[ni], acc[mi][ni], 0, 0, 0);
    __builtin_amdgcn_s_setprio(0);
    if (t + 3 < NT) STAGE_B(t + 3);
    __builtin_amdgcn_s_setprio(1);
#pragma unroll
    for (int mi = 0; mi < 4; ++mi)
#pragma unroll
      for (int ni = 0; ni < 4; ++ni)
        acc[4 + mi][ni] = __builtin_amdgcn_mfma_f32_16x16x32_bf16(ag[mi], bf[ni], acc[4 + mi][ni], 0, 0, 0);
    __builtin_amdgcn_s_setprio(0);
  }

  if constexpr (!PARTIAL) {
#pragma unroll
    for (int mi = 0; mi < 8; ++mi) {
#pragma unroll
      for (int ni = 0; ni < 4; ++ni) {
        const int pn = n0 + wn * 64 + ni * 16 + l16;
        const int y = pn / W, x = pn % W;
#pragma unroll
        for (int r4 = 0; r4 < 4; ++r4) {
          const int co = wm * 128 + mi * 16 + g * 4 + r4;
          float v = acc[mi][ni][r4] + bias[co];
          v = v > 0.f ? v : 0.2f * v;
          out[(((long)bt * 256 + co) * H + y) * W + x] = v;
        }
      }
    }
  } else {
    float* pout = (ks < 2 ? P0 : P1) + (long)(ks & 1) * (16L * 256 * H * W);
#pragma unroll
    for (int mi = 0; mi < 8; ++mi) {
#pragma unroll
      for (int ni = 0; ni < 4; ++ni) {
        const int pn = n0 + wn * 64 + ni * 16 + l16;
        const int y = pn / W, x = pn % W;
#pragma unroll
        for (int r4 = 0; r4 < 4; ++r4) {
          const int co = wm * 128 + mi * 16 + g * 4 + r4;
          pout[(((long)bt * 256 + co) * H + y) * W + x] = acc[mi][ni][r4];
        }
      }
    }
  }
}

// ---------------------------------------------------------------------------
// Row softmax in-place on bf16 rows of length L. One wave per row.
// ---------------------------------------------------------------------------
template<int L>
__global__ __launch_bounds__(256) void softmax_rows(unsigned short* S) {
  const int w = threadIdx.x >> 6, lane = threadIdx.x & 63;
  const long row = (long)blockIdx.x * 4 + w;
  unsigned short* R = S + row * L;
  constexpr int NC = L / 64;
  float v[NC];
  float m = -1e30f;
#pragma unroll
  for (int i = 0; i < NC; ++i) { v[i] = b2f(R[i * 64 + lane]); m = fmaxf(m, v[i]); }
#pragma unroll
  for (int off = 32; off; off >>= 1) m = fmaxf(m, __shfl_xor(m, off, 64));
  float s = 0.f;
#pragma unroll
  for (int i = 0; i < NC; ++i) { v[i] = __expf(v[i] - m); s += v[i]; }
#pragma unroll
  for (int off = 32; off; off >>= 1) s += __shfl_xor(s, off, 64);
  const float inv = 1.0f / s;
#pragma unroll
  for (int i = 0; i < NC; ++i) R[i * 64 + lane] = f2b(v[i] * inv);
}

// ---------------------------------------------------------------------------
// S0: sum 16 bf16 split-K slabs [b*16+ks][512][512] -> softmax -> bf16
// ---------------------------------------------------------------------------
__global__ __launch_bounds__(256) void softmax_red16(const unsigned short* __restrict__ P,
                                                     unsigned short* __restrict__ S) {
  const int w = threadIdx.x >> 6, lane = threadIdx.x & 63;
  const int rowg = blockIdx.x * 4 + w;
  const int b = rowg >> 9, n = rowg & 511;
  const unsigned short* base = P + ((long)b * 16) * 262144 + (long)n * 512 + lane;
  float v[8];
#pragma unroll
  for (int i = 0; i < 8; ++i) {
    float s = 0.f;
#pragma unroll
    for (int ks = 0; ks < 16; ++ks) s += b2f(base[(long)ks * 262144 + i * 64]);
    v[i] = s;
  }
  float m = -1e30f;
#pragma unroll
  for (int i = 0; i < 8; ++i) m = fmaxf(m, v[i]);
#pragma unroll
  for (int off = 32; off; off >>= 1) m = fmaxf(m, __shfl_xor(m, off, 64));
  float s = 0.f;
#pragma unroll
  for (int i = 0; i < 8; ++i) { v[i] = __expf(v[i] - m); s += v[i]; }
#pragma unroll
  for (int off = 32; off; off >>= 1) s += __shfl_xor(s, off, 64);
  const float inv = 1.0f / s;
  unsigned short* R = S + (long)rowg * 512;
#pragma unroll
  for (int i = 0; i < 8; ++i) R[i * 64 + lane] = f2b(v[i] * inv);
}

// ---------------------------------------------------------------------------
// x [16][256][NPIX] fp32 (NCHW) -> xt [16][NPIX][256] bf16 (pixel-major)
// ---------------------------------------------------------------------------
__global__ __launch_bounds__(256) void xt_kernel(const float* __restrict__ x,
                                                 unsigned short* __restrict__ xt, int NPIX) {
  __shared__ unsigned short tile[64 * 65];
  const int tid = threadIdx.x;
  const int bt = blockIdx.z, ch0 = blockIdx.y * 64;
  const long pix0 = (long)blockIdx.x * 64;
  const float* src = x + ((long)bt * 256 + ch0) * NPIX + pix0;
#pragma unroll
  for (int i = 0; i < 16; ++i) {
    const int lin = i * 256 + tid;
    const int ch = lin >> 6, px = lin & 63;
    tile[ch * 65 + px] = f2b(src[(long)ch * NPIX + px]);
  }
  __syncthreads();
  unsigned short* dst = xt + ((long)bt * NPIX + pix0) * 256 + ch0;
#pragma unroll
  for (int i = 0; i < 16; ++i) {
    const int lin = i * 256 + tid;
    const int px = lin >> 6, ch = lin & 63;
    dst[(long)px * 256 + ch] = tile[ch * 65 + px];
  }
}

// ---------------------------------------------------------------------------
// Weight prep
// ---------------------------------------------------------------------------
__global__ void prep_qkv_w(const float* wq, const float* wk, const float* wv,
                           const float* bq, const float* bk, const float* bv,
                           unsigned short* Wcat, float* Bcat, int CO) {
  const int idx = blockIdx.x * 256 + threadIdx.x;
  const int n = 3 * CO * 256;
  if (idx < n) {
    const int sel = idx / (CO * 256);
    const int r = idx - sel * CO * 256;
    const float* wsel = sel == 0 ? wq : (sel == 1 ? wk : wv);
    Wcat[idx] = f2b(wsel[r]);
  }
  if (idx < 3 * CO) {
    const int sel = idx / CO;
    const int r = idx - sel * CO;
    const float* bsel = sel == 0 ? bq : (sel == 1 ? bk : bv);
    Bcat[idx] = bsel[r];
  }
}

__global__ void prep_conv_w(const float* wo, unsigned short* Wt, int CIN) {
  const int idx = blockIdx.x * 256 + threadIdx.x;
  const int n = 9 * 256 * CIN;
  if (idx < n) {
    const int t9 = idx / (256 * CIN);
    const int rem = idx - t9 * 256 * CIN;
    const int o = rem / CIN, i = rem - o * CIN;
    Wt[idx] = f2b(wo[((long)o * CIN + i) * 9 + t9]);   // [9][256][CIN]
  }
}

// ---------------------------------------------------------------------------
// Zero the 1-px halo border of a padded NHWC buffer [16][HP][WP][C]
// ---------------------------------------------------------------------------
__global__ __launch_bounds__(256) void zero_border(unsigned short* buf, int HP, int WP, int C) {
  const long i = (long)blockIdx.x * 256 + threadIdx.x;
  const int per_px = C >> 3;
  const int strip = 2 * WP + 2 * (HP - 2);
  const long tot = (long)16 * strip * per_px;
  if (i >= tot) return;
  const int c8 = (int)(i % per_px);
  const long r = i / per_px;
  const int s = (int)(r % strip);
  const int bt = (int)(r / strip);
  int y, x;
  if (s < WP) { y = 0; x = s; }
  else if (s < 2 * WP) { y = HP - 1; x = s - WP; }
  else if (s < 2 * WP + (HP - 2)) { y = s - 2 * WP + 1; x = 0; }
  else { y = s - 2 * WP - (HP - 2) + 1; x = WP - 1; }
  const short8 z = {0, 0, 0, 0, 0, 0, 0, 0};
  *(short8*)(buf + (((long)bt * HP + y) * WP + x) * C + c8 * 8) = z;
}

// ---------------------------------------------------------------------------
// Repack Y0 rows (cfg0 attention output) -> padded NHWC conv inputs.
// Per row: coalesced load -> conflict-free LDS transpose -> coalesced stores.
// ---------------------------------------------------------------------------
__global__ __launch_bounds__(256) void repackY0(const unsigned short* __restrict__ Y0,
                                                unsigned short* __restrict__ CinLo,
                                                unsigned short* __restrict__ CinHi) {
  __shared__ __align__(16) unsigned short T[8704];
  const int r = blockIdx.x;            // 0..2047
  const int b = r >> 9, n = r & 511;
  const int tid = threadIdx.x;
  const int wv2 = tid >> 6, lane = tid & 63;
  const unsigned short* row = Y0 + (long)r * 8192;
  if (n < 256) {                       // lo: C=512, P=16 (4x4 patch)
#pragma unroll
    for (int q = 0; q < 4; ++q) {
      short8 v = *(const short8*)(row + tid * 32 + q * 8);
#pragma unroll
      for (int j = 0; j < 8; ++j) {
        const int f = tid * 32 + q * 8 + j;
        T[(f & 15) * 520 + (f >> 4)] = (unsigned short)v[j];
      }
    }
    __syncthreads();
    const int t = n >> 6, oh = (n >> 3) & 7, ow = n & 7;
    const int bt = b * 4 + t;
#pragma unroll
    for (int it = 0; it < 4; ++it) {
      const int pp = it * 4 + wv2;
      const int py = pp >> 2, px = pp & 3;
      short8 v = *(const short8*)(T + pp * 520 + lane * 8);
      *(short8*)(CinLo + (((long)bt * 34 + oh * 4 + py + 1) * 34 + ow * 4 + px + 1) * 1024
                 + lane * 8) = v;
    }
  } else {                             // hi: C=128, P=64 (8x8 patch)
    const int m = n - 256;
#pragma unroll
    for (int q = 0; q < 4; ++q) {
      short8 v = *(const short8*)(row + tid * 32 + q * 8);
#pragma unroll
      for (int j = 0; j < 8; ++j) {
        const int f = tid * 32 + q * 8 + j;
        T[(f & 63) * 136 + (f >> 6)] = (unsigned short)v[j];
      }
    }
    __syncthreads();
    const int t = m >> 6, oh = (m >> 3) & 7, ow = m & 7;
    const int bt = b * 4 + t;
#pragma unroll
    for (int it = 0; it < 4; ++it) {
      const int pp = it * 16 + wv2 * 4 + (lane >> 4);
      const int py = pp >> 3, px = pp & 7;
      short8 v = *(const short8*)(T + pp * 136 + (lane & 15) * 8);
      *(short8*)(CinHi + (((long)bt * 66 + oh * 8 + py + 1) * 66 + ow * 8 + px + 1) * 256
                 + (lane & 15) * 8) = v;
    }
  }
}

__global__ __launch_bounds__(256) void repackY1(const unsigned short* __restrict__ Y1,
                                                unsigned short* __restrict__ CinLo,
                                                unsigned short* __restrict__ CinHi) {
  __shared__ __align__(16) unsigned short T[2176];
  const int r = blockIdx.x;            // 0..8191
  const int b = r >> 11, n = r & 2047;
  const int tid = threadIdx.x;
  const int wv2 = tid >> 6, lane = tid & 63;
  const unsigned short* row = Y1 + (long)r * 2048;
  short8 v = *(const short8*)(row + tid * 8);
  if (n < 1024) {                      // lo: C=512, P=4 (2x2 patch)
#pragma unroll
    for (int j = 0; j < 8; ++j) {
      const int f = tid * 8 + j;
      T[(f & 3) * 520 + (f >> 2)] = (unsigned short)v[j];
    }
    __syncthreads();
    const int t = n >> 8, oh = (n >> 4) & 15, ow = n & 15;
    const int bt = b * 4 + t;
    const int pp = wv2, py = pp >> 1, px = pp & 1;
    short8 o = *(const short8*)(T + pp * 520 + lane * 8);
    *(short8*)(CinLo + (((long)bt * 34 + oh * 2 + py + 1) * 34 + ow * 2 + px + 1) * 1024
               + 512 + lane * 8) = o;
  } else {                             // hi: C=128, P=16 (4x4 patch)
    const int m = n - 1024;
#pragma unroll
    for (int j = 0; j < 8; ++j) {
      const int f = tid * 8 + j;
      T[(f & 15) * 136 + (f >> 4)] = (unsigned short)v[j];
    }
    __syncthreads();
    const int t = m >> 8, oh = (m >> 4) & 15, ow = m & 15;
    const int bt = b * 4 + t;
    const int pp = wv2 * 4 + (lane >> 4), py = pp >> 2, px = pp & 3;
    short8 o = *(const short8*)(T + pp * 136 + (lane & 15) * 8);
    *(short8*)(CinHi + (((long)bt * 66 + oh * 4 + py + 1) * 66 + ow * 4 + px + 1) * 256
               + 128 + (lane & 15) * 8) = o;
  }
}

// ---------------------------------------------------------------------------
// Sum 4 conv partial slabs + bias + leaky-relu -> out
// ---------------------------------------------------------------------------
__global__ __launch_bounds__(256) void reduce_lrelu(const floatx4* __restrict__ P0,
                                                    const floatx4* __restrict__ P1,
                                                    const float* __restrict__ bias,
                                                    floatx4* __restrict__ out) {
  const long i = (long)blockIdx.x * 256 + threadIdx.x;
  constexpr long SL = 1048576;
  floatx4 a = P0[i], b = P0[SL + i], c = P1[i], d = P1[SL + i];
  const int co = ((int)(i >> 8)) & 255;
  const float bv = bias[co];
  floatx4 r;
#pragma unroll
  for (int j = 0; j < 4; ++j) {
    float v = a[j] + b[j] + c[j] + d[j] + bv;
    r[j] = v > 0.f ? v : 0.2f * v;
  }
  out[i] = r;
}

// ---------------------------------------------------------------------------
extern "C" void kernel_launch(void* const* d_in, const int* in_sizes, int n_in,
                              void* d_out, int out_size, void* d_ws, size_t ws_size,
                              hipStream_t stream) {
  (void)in_sizes; (void)n_in; (void)out_size; (void)ws_size;
  const float* x_lo = (const float*)d_in[0];
  const float* x_hi = (const float*)d_in[1];
  const float* wq_lo = (const float*)d_in[3];
  const float* bq_lo = (const float*)d_in[4];
  const float* wk_lo = (const float*)d_in[5];
  const float* bk_lo = (const float*)d_in[6];
  const float* wv_lo = (const float*)d_in[7];
  const float* bv_lo = (const float*)d_in[8];
  const float* wq_hi = (const float*)d_in[9];
  const float* bq_hi = (const float*)d_in[10];
  const float* wk_hi = (const float*)d_in[11];
  const float* bk_hi = (const float*)d_in[12];
  const float* wv_hi = (const float*)d_in[13];
  const float* bv_hi = (const float*)d_in[14];
  const float* wo_lo = (const float*)d_in[15];
  const float* bo_lo = (const float*)d_in[16];
  const float* wo_hi = (const float*)d_in[17];
  const float* bo_hi = (const float*)d_in[18];
  float* out = (float*)d_out;

  char* ws = (char*)d_ws;
  const long B0 = 33554432;
  unsigned short* Qp0 = (unsigned short*)(ws);
  unsigned short* Kp0 = (unsigned short*)(ws + B0);
  unsigned short* V0t = (unsigned short*)(ws + 2 * B0);
  unsigned short* Qp1 = (unsigned short*)(ws + 3 * B0);
  unsigned short* Kp1 = (unsigned short*)(ws + 4 * B0);
  unsigned short* V1t = (unsigned short*)(ws + 5 * B0);
  char* ptr = ws + 6 * B0;
  unsigned short* S0 = (unsigned short*)ptr;     ptr += 2097152;
  unsigned short* Xt_lo = (unsigned short*)ptr;  ptr += 8388608;
  unsigned short* Xt_hi = (unsigned short*)ptr;  ptr += 33554432;
  unsigned short* Wcat_lo = (unsigned short*)ptr; ptr += 1572864;
  unsigned short* Wcat_hi = (unsigned short*)ptr; ptr += 393216;
  float* Bcat_lo = (float*)ptr;                  ptr += 12288;
  float* Bcat_hi = (float*)ptr;                  ptr += 3072;
  unsigned short* Wt_lo = (unsigned short*)ptr;  ptr += 4718592;
  unsigned short* Wt_hi = (unsigned short*)ptr;  ptr += 1179648;
  unsigned short* S1 = Kp0;
  unsigned short* Y0 = Qp0;
  unsigned short* Y1 = Qp1;
  unsigned short* CinP_lo = Kp0;
  unsigned short* CinP_hi = Kp1;
  unsigned short* S0p = Xt_hi;      // 64 bf16 slabs x 262144 = 33.5 MB
  float* PC0 = (float*)Qp0;
  float* PC1 = (float*)Qp1;

  // --- weight/input prep ---
  prep_qkv_w<<<(3 * 1024 * 256 + 255) / 256, 256, 0, stream>>>(
      wq_lo, wk_lo, wv_lo, bq_lo, bk_lo, bv_lo, Wcat_lo, Bcat_lo, 1024);
  prep_qkv_w<<<(3 * 256 * 256 + 255) / 256, 256, 0, stream>>>(
      wq_hi, wk_hi, wv_hi, bq_hi, bk_hi, bv_hi, Wcat_hi, Bcat_hi, 256);
  prep_conv_w<<<(9 * 256 * 1024 + 255) / 256, 256, 0, stream>>>(wo_lo, Wt_lo, 1024);
  prep_conv_w<<<(9 * 256 * 256 + 255) / 256, 256, 0, stream>>>(wo_hi, Wt_hi, 256);
  xt_kernel<<<dim3(16, 4, 16), 256, 0, stream>>>(x_lo, Xt_lo, 1024);
  xt_kernel<<<dim3(64, 4, 16), 256, 0, stream>>>(x_hi, Xt_hi, 4096);

  // --- QKV projections (1x1 conv as TN-GEMM), staged coalesced scatter ---
  {
    GemmP p{};
    p.A = Wcat_lo; p.B = Xt_lo; p.sAb = 0; p.sBb = 1024L * 256;
    p.lda = 256; p.ldb = 256; p.K = 256;
    p.bias = Bcat_lo;
    p.Q0 = Qp0; p.K0 = Kp0; p.V0t = V0t; p.Q1 = Qp1; p.K1 = Kp1; p.V1t = V1t;
    gemm256<2><<<dim3(4, 12, 16), 512, 0, stream>>>(p);
    p.A = Wcat_hi; p.B = Xt_hi; p.sBb = 4096L * 256; p.bias = Bcat_hi;
    gemm256<3><<<dim3(16, 3, 16), 512, 0, stream>>>(p);
  }

  // --- attention cfg0: n=512, d=8192 (split-K 16, bf16 partials) ---
  {
    GemmP s{};
    s.A = Qp0; s.B = Kp0; s.sAb = 512L * 8192; s.sBb = 512L * 8192;
    s.lda = 8192; s.ldb = 8192; s.K = 8192;
    s.C = S0p; s.sCb = 262144; s.ldc = 512;
    gemm256<1><<<dim3(2, 2, 64), 512, 0, stream>>>(s);
    softmax_red16<<<512, 256, 0, stream>>>(S0p, S0);
    GemmP pv{};
    pv.A = S0; pv.B = V0t; pv.sAb = 512L * 512; pv.sBb = 8192L * 512;
    pv.lda = 512; pv.ldb = 512; pv.K = 512;
    pv.C = Y0; pv.sCb = 512L * 8192; pv.ldc = 8192;
    gemm256<0><<<dim3(32, 2, 4), 512, 0, stream>>>(pv);
  }

  // --- attention cfg1: n=2048, d=2048 ---
  {
    GemmP s{};
    s.A = Qp1; s.B = Kp1; s.sAb = 2048L * 2048; s.sBb = 2048L * 2048;
    s.lda = 2048; s.ldb = 2048; s.K = 2048;
    s.C = S1; s.sCb = 2048L * 2048; s.ldc = 2048;
    gemm256<0><<<dim3(8, 8, 4), 512, 0, stream>>>(s);
    softmax_rows<2048><<<2048, 256, 0, stream>>>(S1);
    GemmP pv{};
    pv.A = S1; pv.B = V1t; pv.sAb = 2048L * 2048; pv.sBb = 2048L * 2048;
    pv.lda = 2048; pv.ldb = 2048; pv.K = 2048;
    pv.C = Y1; pv.sCb = 2048L * 2048; pv.ldc = 2048;
    gemm256<0><<<dim3(8, 8, 4), 512, 0, stream>>>(pv);
  }

  // --- halo zeroing + coalesced from_patches repack into padded NHWC ---
  zero_border<<<1056, 256, 0, stream>>>(CinP_lo, 34, 34, 1024);
  zero_border<<<520, 256, 0, stream>>>(CinP_hi, 66, 66, 256);
  repackY0<<<2048, 256, 0, stream>>>(Y0, CinP_lo, CinP_hi);
  repackY1<<<8192, 256, 0, stream>>>(Y1, CinP_lo, CinP_hi);

  // --- 3x3 convs as im2col GEMM on the 256-tile pipeline ---
  conv256<32, 32, 1024, 4, true><<<dim3(4, 1, 64), 512, 0, stream>>>(
      CinP_lo, Wt_lo, bo_lo, out, PC0, PC1);
  reduce_lrelu<<<4096, 256, 0, stream>>>((const floatx4*)PC0, (const floatx4*)PC1, bo_lo,
                                         (floatx4*)out);
  conv256<64, 64, 256, 1, false><<<dim3(16, 1, 16), 512, 0, stream>>>(
      CinP_hi, Wt_hi, bo_hi, out + 4194304, nullptr, nullptr);
}

// Round 9
// 554.728 us; speedup vs baseline: 1.9780x; 1.0465x over previous
//
#include <hip/hip_runtime.h>
#include <hip/hip_bf16.h>
#include <stdint.h>

typedef __attribute__((ext_vector_type(8))) short short8;
typedef __attribute__((ext_vector_type(4))) short short4v;
typedef __attribute__((ext_vector_type(2))) short short2v;
typedef __attribute__((ext_vector_type(4))) float floatx4;

__device__ __forceinline__ unsigned short f2b(float f) {
  unsigned u = __builtin_bit_cast(unsigned, f);
  unsigned r = u + 0x7fffu + ((u >> 16) & 1u);
  return (unsigned short)(r >> 16);
}
__device__ __forceinline__ float b2f(unsigned short h) {
  unsigned u = ((unsigned)h) << 16;
  return __builtin_bit_cast(float, u);
}
__device__ __forceinline__ void glds16(const unsigned short* src, unsigned short* dst) {
  __builtin_amdgcn_global_load_lds((const __attribute__((address_space(1))) void*)src,
                                   (__attribute__((address_space(3))) void*)dst, 16, 0, 0);
}
// epilogue LDS swizzle: row r (0..255), o = byte offset in 512B row.
__device__ __forceinline__ int swz(int r, int o) {
  return (r << 9) + (o ^ ((((o >> 7) & 3) ^ (r & 7)) << 4));
}
// T1: bijective XCD-contiguous work remap (requires nwg % 8 == 0).
// Dispatch id L runs on XCD L%8; give XCD k the contiguous work chunk
// [k*nwg/8, (k+1)*nwg/8) so neighbor tiles (sharing panels) hit one L2.
__device__ __forceinline__ void xcd_remap(int& bx, int& by, int& bz) {
  const int gx = gridDim.x, gy = gridDim.y;
  const int nwg = gx * gy * (int)gridDim.z;
  int lin = bx + gx * (by + gy * bz);
  lin = (lin & 7) * (nwg >> 3) + (lin >> 3);
  bx = lin % gx; const int r = lin / gx;
  by = r % gy; bz = r / gy;
}

// ---------------------------------------------------------------------------
// 256x256-tile TN GEMM core: 512 thr = 8 waves (2Mx4N); BK=32; 4-buffer ring;
// counted vmcnt 8/4/0; 1 barrier/K-tile; setprio; swizzle f(row)=(row>>1)&3.
// EPI 0: staged bf16 C. EPI 1: split-K(16) bf16 partials (direct stores).
// EPI 2/3: staged QKV lo/hi scatter.
// ---------------------------------------------------------------------------
struct GemmP {
  const unsigned short* A;
  const unsigned short* B;
  long sAb, sBb;
  int lda, ldb, K;
  unsigned short* C; long sCb; int ldc;
  const float* bias;
  unsigned short *Q0, *K0, *V0t, *Q1, *K1, *V1t;
};

template<int EPI>
__global__ __launch_bounds__(512) void gemm256(GemmP p) {
  __shared__ __align__(16) unsigned short LDS[65536];
  const int tid = threadIdx.x;
  const int wv = tid >> 6, lane = tid & 63;
  const int wm = wv >> 2, wn = wv & 3;
  const int g = lane >> 4, l16 = lane & 15;
  int bx = blockIdx.x, by = blockIdx.y, bz = blockIdx.z;
  xcd_remap(bx, by, bz);
  const int m0 = by * 256, n0 = bx * 256;

  int bb = bz, koff = 0, Keff = p.K;
  if constexpr (EPI == 1) { bb = bz >> 4; koff = (bz & 15) * (p.K >> 4); Keff = p.K >> 4; }
  const unsigned short* Ab = p.A + (long)bb * p.sAb + (long)m0 * p.lda + koff;
  const unsigned short* Bb = p.B + (long)bb * p.sBb + (long)n0 * p.ldb + koff;
  const int NT = Keff >> 5;

  const int r0 = tid >> 2;
  const int cs = (tid & 3) ^ ((r0 >> 1) & 3);
  const unsigned short* aS0 = Ab + (long)r0 * p.lda + cs * 8;
  const unsigned short* aS1 = aS0 + (long)128 * p.lda;
  const unsigned short* bS0 = Bb + (long)r0 * p.ldb + cs * 8;
  const unsigned short* bS1 = bS0 + (long)128 * p.ldb;
  unsigned short* const lds0 = (unsigned short*)LDS;
  const int wbase = wv * 512;

  auto STAGE_A = [&](int t) {
    unsigned short* d = lds0 + (t & 3) * 16384;
    const long ko = (long)t * 32;
    glds16(aS0 + ko, d + wbase);
    glds16(aS1 + ko, d + 4096 + wbase);
  };
  auto STAGE_B = [&](int t) {
    unsigned short* d = lds0 + (t & 3) * 16384 + 8192;
    const long ko = (long)t * 32;
    glds16(bS0 + ko, d + wbase);
    glds16(bS1 + ko, d + 4096 + wbase);
  };

  STAGE_A(0); STAGE_B(0); STAGE_A(1); STAGE_B(1); STAGE_A(2); STAGE_B(2);

  floatx4 acc[8][4];
  const floatx4 z4 = {0.f, 0.f, 0.f, 0.f};
#pragma unroll
  for (int i = 0; i < 8; ++i)
#pragma unroll
    for (int j = 0; j < 4; ++j) acc[i][j] = z4;

  const int loff = l16 * 32 + ((g ^ ((l16 >> 1) & 3)) * 8);
  const int aRowB = wm * 128;

  for (int t = 0; t < NT; ++t) {
    const unsigned short* As = lds0 + (t & 3) * 16384;
    const unsigned short* Bs = As + 8192;
    if (t < NT - 2)        asm volatile("s_waitcnt vmcnt(8)" ::: "memory");
    else if (t == NT - 2)  asm volatile("s_waitcnt vmcnt(4)" ::: "memory");
    else                   asm volatile("s_waitcnt vmcnt(0)" ::: "memory");
    __builtin_amdgcn_s_barrier();
    __builtin_amdgcn_sched_barrier(0);
    if (t + 3 < NT) STAGE_A(t + 3);
    short8 bf[4], af[4], ag[4];
#pragma unroll
    for (int ni = 0; ni < 4; ++ni)
      bf[ni] = *(const short8*)(Bs + (wn * 64 + ni * 16) * 32 + loff);
#pragma unroll
    for (int mi = 0; mi < 4; ++mi)
      af[mi] = *(const short8*)(As + (aRowB + mi * 16) * 32 + loff);
#pragma unroll
    for (int mi = 0; mi < 4; ++mi)
      ag[mi] = *(const short8*)(As + (aRowB + 64 + mi * 16) * 32 + loff);
    __builtin_amdgcn_s_setprio(1);
#pragma unroll
    for (int mi = 0; mi < 4; ++mi)
#pragma unroll
      for (int ni = 0; ni < 4; ++ni)
        acc[mi][ni] = __builtin_amdgcn_mfma_f32_16x16x32_bf16(af[mi], bf[ni], acc[mi][ni], 0, 0, 0);
    __builtin_amdgcn_s_setprio(0);
    if (t + 3 < NT) STAGE_B(t + 3);
    __builtin_amdgcn_s_setprio(1);
#pragma unroll
    for (int mi = 0; mi < 4; ++mi)
#pragma unroll
      for (int ni = 0; ni < 4; ++ni)
        acc[4 + mi][ni] = __builtin_amdgcn_mfma_f32_16x16x32_bf16(ag[mi], bf[ni], acc[4 + mi][ni], 0, 0, 0);
    __builtin_amdgcn_s_setprio(0);
  }

  if constexpr (EPI == 1) {          // bf16 partial store
    unsigned short* C = p.C + (long)bz * p.sCb;
#pragma unroll
    for (int mi = 0; mi < 8; ++mi) {
#pragma unroll
      for (int ni = 0; ni < 4; ++ni) {
        const int col = n0 + wn * 64 + ni * 16 + l16;
#pragma unroll
        for (int r4 = 0; r4 < 4; ++r4) {
          const int row = m0 + wm * 128 + mi * 16 + g * 4 + r4;
          C[(long)row * p.ldc + col] = f2b(acc[mi][ni][r4]);
        }
      }
    }
  } else {
    // ------- staged epilogue: acc (+bias/scale) -> LDS tile [256co][256pix] -------
    __syncthreads();
    char* shb = (char*)LDS;
    const int sel = (EPI == 2) ? (m0 >> 10) : (m0 >> 8);
#pragma unroll
    for (int mi = 0; mi < 8; ++mi) {
#pragma unroll
      for (int ni = 0; ni < 4; ++ni) {
        const int c = wn * 64 + ni * 16 + l16;
#pragma unroll
        for (int r4 = 0; r4 < 4; ++r4) {
          const int rr = wm * 128 + mi * 16 + g * 4 + r4;
          float v = acc[mi][ni][r4];
          if constexpr (EPI == 2 || EPI == 3) {
            v += p.bias[m0 + rr];
            if (sel == 0) {
              float sc;
              if constexpr (EPI == 2) sc = ((m0 & 1023) < 512) ? 0.011048543456039806f
                                                               : 0.02209708691207961f;
              else                    sc = (rr < 128) ? 0.011048543456039806f
                                                      : 0.02209708691207961f;
              v *= sc;
            }
          }
          *(unsigned short*)(shb + swz(rr, c * 2)) = f2b(v);
        }
      }
    }
    __syncthreads();

    if constexpr (EPI == 0) {
      unsigned short* C = p.C + (long)bz * p.sCb;
#pragma unroll
      for (int j = 0; j < 16; ++j) {
        const int e = j * 512 + tid;
        const int r = e >> 5, ck = e & 31;
        short8 v = *(const short8*)(shb + swz(r, ck * 16));
        *(short8*)(C + (long)(m0 + r) * p.ldc + n0 + ck * 8) = v;
      }
    } else if constexpr (EPI == 2) {    // ---- QKV lo ----
      const int chb = m0 & 1023;
      const bool cfg0 = chb < 512;
      const int b = bz >> 2, tt = bz & 3;
      const int k0 = n0 >> 8;
      unsigned short* dst = cfg0 ? (sel == 0 ? p.Q0 : sel == 1 ? p.K0 : p.V0t)
                                 : (sel == 0 ? p.Q1 : sel == 1 ? p.K1 : p.V1t);
      if (sel != 2) {
        if (cfg0) {                      // 4x4 patches, d=8192
          const long base = (long)(b * 512) * 8192;
#pragma unroll
          for (int j = 0; j < 16; ++j) {
            const int e = j * 512 + tid;
            const int pi = e >> 9, idx2 = e & 511;
            const int ch = idx2 >> 1, hf = idx2 & 1;
            const int oyL = pi >> 3, ox = pi & 7;
            const int nseq = (tt * 8 + 2 * k0 + oyL) * 8 + ox;
            const int yl = oyL * 4 + hf * 2;
            short4v a = *(const short4v*)(shb + swz(ch, (yl * 32 + ox * 4) * 2));
            short4v b2 = *(const short4v*)(shb + swz(ch, ((yl + 1) * 32 + ox * 4) * 2));
            short8 v = {a[0], a[1], a[2], a[3], b2[0], b2[1], b2[2], b2[3]};
            *(short8*)(dst + base + (long)nseq * 8192 + (chb + ch) * 16 + hf * 8) = v;
          }
        } else {                         // 2x2 patches, d=2048
          const int c2lo = chb - 512;
          const long base = (long)(b * 2048) * 2048;
#pragma unroll
          for (int j = 0; j < 16; ++j) {
            const int e = j * 512 + tid;
            const int pi = e >> 7, cp = e & 127;
            const int oyL = pi >> 4, ox = pi & 15;
            const int nseq = (tt * 16 + 4 * k0 + oyL) * 16 + ox;
            short8 v;
#pragma unroll
            for (int rr = 0; rr < 2; ++rr) {
#pragma unroll
              for (int k = 0; k < 2; ++k) {
                short2v pr = *(const short2v*)(shb +
                    swz(cp * 2 + rr, ((oyL * 2 + k) * 32 + ox * 2) * 2));
                v[rr * 4 + k * 2] = pr[0];
                v[rr * 4 + k * 2 + 1] = pr[1];
              }
            }
            *(short8*)(dst + base + (long)nseq * 2048 + (c2lo + cp * 2) * 4) = v;
          }
        }
      } else {                           // V transposed [f][nseq]
        if (cfg0) {
          const long base = (long)(b * 8192) * 512;
#pragma unroll
          for (int j = 0; j < 16; ++j) {
            const int e = j * 512 + tid;
            const int oyL = e >> 12, fu = e & 4095;
            const int ch = fu >> 4, pp = fu & 15;
            const int py = pp >> 2, px = pp & 3;
            const int yl = oyL * 4 + py;
            short8 v;
#pragma unroll
            for (int ox = 0; ox < 8; ++ox)
              v[ox] = *(const unsigned short*)(shb + swz(ch, (yl * 32 + ox * 4 + px) * 2));
            const long f = (long)(chb + ch) * 16 + pp;
            *(short8*)(dst + base + f * 512 + (tt * 8 + 2 * k0 + oyL) * 8) = v;
          }
        } else {
          const int c2lo = chb - 512;
          const long base = (long)(b * 2048) * 2048;
#pragma unroll
          for (int j = 0; j < 16; ++j) {
            const int e = j * 512 + tid;
            const int he = e & 1, oyL = (e >> 1) & 3, fu = e >> 3;
            const int c2 = fu >> 2, pp = fu & 3;
            const int py = pp >> 1, px = pp & 1;
            const int yl = oyL * 2 + py;
            short8 v;
#pragma unroll
            for (int i = 0; i < 8; ++i) {
              const int ox = he * 8 + i;
              v[i] = *(const unsigned short*)(shb + swz(c2, (yl * 32 + ox * 2 + px) * 2));
            }
            const long f = (long)(c2lo + c2) * 4 + pp;
            *(short8*)(dst + base + f * 2048 + (tt * 16 + 4 * k0 + oyL) * 16 + he * 8) = v;
          }
        }
      }
    } else if constexpr (EPI == 3) {    // ---- QKV hi ----
      const int b = bz >> 2, tt = bz & 3;
      const int k0 = n0 >> 8;
      const int oyA = k0 >> 1, pyb = (k0 & 1) * 4;
      unsigned short* dstA = sel == 0 ? p.Q0 : sel == 1 ? p.K0 : p.V0t;
      unsigned short* dstB = sel == 0 ? p.Q1 : sel == 1 ? p.K1 : p.V1t;
      if (sel != 2) {
#pragma unroll
        for (int j = 0; j < 16; ++j) {
          const int e = j * 512 + tid;
          if (e < 4096) {                // cfg0: 8x8 patches
            const int ox = e >> 9, cy = e & 511;
            const int ch = cy >> 2, yl = cy & 3;
            const int nseq = 256 + (tt * 8 + oyA) * 8 + ox;
            short8 v = *(const short8*)(shb + swz(ch, (yl * 64 + ox * 8) * 2));
            *(short8*)(dstA + ((long)(b * 512 + nseq)) * 8192 + ch * 64 + (pyb + yl) * 8) = v;
          } else {                       // cfg1: 4x4 patches
            const int ee = e - 4096;
            const int ox = ee >> 8, cc = ee & 255;
            const int c2 = cc >> 1, hf = cc & 1;
            const int nseq = 1024 + (tt * 16 + k0) * 16 + ox;
            short8 v;
#pragma unroll
            for (int k = 0; k < 2; ++k) {
              short4v a = *(const short4v*)(shb +
                  swz(128 + c2, ((hf * 2 + k) * 64 + ox * 4) * 2));
              v[k * 4] = a[0]; v[k * 4 + 1] = a[1]; v[k * 4 + 2] = a[2]; v[k * 4 + 3] = a[3];
            }
            *(short8*)(dstB + ((long)(b * 2048 + nseq)) * 2048 + c2 * 16 + hf * 8) = v;
          }
        }
      } else {
#pragma unroll
        for (int j = 0; j < 16; ++j) {
          const int e = j * 512 + tid;
          if (e < 4096) {                // cfg0 V
            const int ch = e >> 5, yl = (e >> 3) & 3, px = e & 7;
            short8 v;
#pragma unroll
            for (int ox = 0; ox < 8; ++ox)
              v[ox] = *(const unsigned short*)(shb + swz(ch, (yl * 64 + ox * 8 + px) * 2));
            const long f = (long)ch * 64 + (pyb + yl) * 8 + px;
            *(short8*)(dstA + ((long)b * 8192 + f) * 512 + 256 + (tt * 8 + oyA) * 8) = v;
          } else {                       // cfg1 V
            const int ee = e - 4096;
            const int he = ee & 1, fu = ee >> 1;
            const int c2 = fu >> 4, pp = fu & 15;
            const int py = pp >> 2, px = pp & 3;
            short8 v;
#pragma unroll
            for (int i = 0; i < 8; ++i) {
              const int x = (he * 8 + i) * 4 + px;
              v[i] = *(const unsigned short*)(shb + swz(128 + c2, (py * 64 + x) * 2));
            }
            const long f = (long)c2 * 16 + pp;
            *(short8*)(dstB + ((long)b * 2048 + f) * 2048 + 1024 + (tt * 16 + k0) * 16 + he * 8) = v;
          }
        }
      }
    }
  }
}

// ---------------------------------------------------------------------------
// 3x3 conv as im2col GEMM (same core). PARTIAL: bf16 partial slabs.
// ---------------------------------------------------------------------------
template<int H, int W, int CIN, int KS, bool PARTIAL>
__global__ __launch_bounds__(512) void conv256(const unsigned short* __restrict__ Cinp,
                                               const unsigned short* __restrict__ Wt,
                                               const float* __restrict__ bias,
                                               float* __restrict__ out,
                                               unsigned short* __restrict__ P0,
                                               unsigned short* __restrict__ P1) {
  constexpr int HP = H + 2, WP = W + 2;
  constexpr int CC = CIN / KS;
  constexpr int NT = 9 * CC / 32;
  __shared__ __align__(16) unsigned short LDS[65536];
  const int tid = threadIdx.x;
  const int wv = tid >> 6, lane = tid & 63;
  const int wm = wv >> 2, wn = wv & 3;
  const int g = lane >> 4, l16 = lane & 15;
  int bx = blockIdx.x, by = blockIdx.y, bz = blockIdx.z;
  xcd_remap(bx, by, bz);
  const int bt = bz / KS, ks = bz % KS;
  const int n0 = bx * 256;

  const int r0 = tid >> 2;
  const int cs = (tid & 3) ^ ((r0 >> 1) & 3);
  const unsigned short* wA0 = Wt + (long)r0 * CIN + ks * CC + cs * 8;
  const unsigned short* wA1 = wA0 + (long)128 * CIN;
  const int p0 = n0 + r0, p1 = p0 + 128;
  const int y0p = p0 / W, x0p = p0 % W;
  const int y1p = p1 / W, x1p = p1 % W;
  const unsigned short* cB = Cinp + (long)bt * HP * WP * CIN + ks * CC + cs * 8;
  const unsigned short* pB0 = cB + ((long)y0p * WP + x0p) * CIN;
  const unsigned short* pB1 = cB + ((long)y1p * WP + x1p) * CIN;
  unsigned short* const lds0 = (unsigned short*)LDS;
  const int wbase = wv * 512;

  auto STAGE_A = [&](int t) {
    unsigned short* d = lds0 + (t & 3) * 16384;
    const int tap = t >> 3, tc = (t & 7) * 32;
    const long off = (long)tap * (256L * CIN) + tc;
    glds16(wA0 + off, d + wbase);
    glds16(wA1 + off, d + 4096 + wbase);
  };
  auto STAGE_B = [&](int t) {
    unsigned short* d = lds0 + (t & 3) * 16384 + 8192;
    const int tap = t >> 3, tc = (t & 7) * 32;
    const int ky = tap / 3, kx = tap - ky * 3;
    const long off = ((long)ky * WP + kx) * CIN + tc;
    glds16(pB0 + off, d + wbase);
    glds16(pB1 + off, d + 4096 + wbase);
  };

  STAGE_A(0); STAGE_B(0); STAGE_A(1); STAGE_B(1); STAGE_A(2); STAGE_B(2);

  floatx4 acc[8][4];
  const floatx4 z4 = {0.f, 0.f, 0.f, 0.f};
#pragma unroll
  for (int i = 0; i < 8; ++i)
#pragma unroll
    for (int j = 0; j < 4; ++j) acc[i][j] = z4;

  const int loff = l16 * 32 + ((g ^ ((l16 >> 1) & 3)) * 8);
  const int aRowB = wm * 128;

  for (int t = 0; t < NT; ++t) {
    const unsigned short* As = lds0 + (t & 3) * 16384;
    const unsigned short* Bs = As + 8192;
    if (t < NT - 2)        asm volatile("s_waitcnt vmcnt(8)" ::: "memory");
    else if (t == NT - 2)  asm volatile("s_waitcnt vmcnt(4)" ::: "memory");
    else                   asm volatile("s_waitcnt vmcnt(0)" ::: "memory");
    __builtin_amdgcn_s_barrier();
    __builtin_amdgcn_sched_barrier(0);
    if (t + 3 < NT) STAGE_A(t + 3);
    short8 bf[4], af[4], ag[4];
#pragma unroll
    for (int ni = 0; ni < 4; ++ni)
      bf[ni] = *(const short8*)(Bs + (wn * 64 + ni * 16) * 32 + loff);
#pragma unroll
    for (int mi = 0; mi < 4; ++mi)
      af[mi] = *(const short8*)(As + (aRowB + mi * 16) * 32 + loff);
#pragma unroll
    for (int mi = 0; mi < 4; ++mi)
      ag[mi] = *(const short8*)(As + (aRowB + 64 + mi * 16) * 32 + loff);
    __builtin_amdgcn_s_setprio(1);
#pragma unroll
    for (int mi = 0; mi < 4; ++mi)
#pragma unroll
      for (int ni = 0; ni < 4; ++ni)
        acc[mi][ni] = __builtin_amdgcn_mfma_f32_16x16x32_bf16(af[mi], bf[ni], acc[mi][ni], 0, 0, 0);
    __builtin_amdgcn_s_setprio(0);
    if (t + 3 < NT) STAGE_B(t + 3);
    __builtin_amdgcn_s_setprio(1);
#pragma unroll
    for (int mi = 0; mi < 4; ++mi)
#pragma unroll
      for (int ni = 0; ni < 4; ++ni)
        acc[4 + mi][ni] = __builtin_amdgcn_mfma_f32_16x16x32_bf16(ag[mi], bf[ni], acc[4 + mi][ni], 0, 0, 0);
    __builtin_amdgcn_s_setprio(0);
  }

  if constexpr (!PARTIAL) {
#pragma unroll
    for (int mi = 0; mi < 8; ++mi) {
#pragma unroll
      for (int ni = 0; ni < 4; ++ni) {
        const int pn = n0 + wn * 64 + ni * 16 + l16;
        const int y = pn / W, x = pn % W;
#pragma unroll
        for (int r4 = 0; r4 < 4; ++r4) {
          const int co = wm * 128 + mi * 16 + g * 4 + r4;
          float v = acc[mi][ni][r4] + bias[co];
          v = v > 0.f ? v : 0.2f * v;
          out[(((long)bt * 256 + co) * H + y) * W + x] = v;
        }
      }
    }
  } else {
    unsigned short* pout = (ks < 2 ? P0 : P1) + (long)(ks & 1) * (16L * 256 * H * W);
#pragma unroll
    for (int mi = 0; mi < 8; ++mi) {
#pragma unroll
      for (int ni = 0; ni < 4; ++ni) {
        const int pn = n0 + wn * 64 + ni * 16 + l16;
        const int y = pn / W, x = pn % W;
#pragma unroll
        for (int r4 = 0; r4 < 4; ++r4) {
          const int co = wm * 128 + mi * 16 + g * 4 + r4;
          pout[(((long)bt * 256 + co) * H + y) * W + x] = f2b(acc[mi][ni][r4]);
        }
      }
    }
  }
}

// ---------------------------------------------------------------------------
// Row softmax in-place on bf16 rows of length L. One wave per row.
// ---------------------------------------------------------------------------
template<int L>
__global__ __launch_bounds__(256) void softmax_rows(unsigned short* S) {
  const int w = threadIdx.x >> 6, lane = threadIdx.x & 63;
  const long row = (long)blockIdx.x * 4 + w;
  unsigned short* R = S + row * L;
  constexpr int NC = L / 64;
  float v[NC];
  float m = -1e30f;
#pragma unroll
  for (int i = 0; i < NC; ++i) { v[i] = b2f(R[i * 64 + lane]); m = fmaxf(m, v[i]); }
#pragma unroll
  for (int off = 32; off; off >>= 1) m = fmaxf(m, __shfl_xor(m, off, 64));
  float s = 0.f;
#pragma unroll
  for (int i = 0; i < NC; ++i) { v[i] = __expf(v[i] - m); s += v[i]; }
#pragma unroll
  for (int off = 32; off; off >>= 1) s += __shfl_xor(s, off, 64);
  const float inv = 1.0f / s;
#pragma unroll
  for (int i = 0; i < NC; ++i) R[i * 64 + lane] = f2b(v[i] * inv);
}

// ---------------------------------------------------------------------------
// S0: sum 16 bf16 split-K slabs [b*16+ks][512][512] -> softmax -> bf16
// ---------------------------------------------------------------------------
__global__ __launch_bounds__(256) void softmax_red16(const unsigned short* __restrict__ P,
                                                     unsigned short* __restrict__ S) {
  const int w = threadIdx.x >> 6, lane = threadIdx.x & 63;
  const int rowg = blockIdx.x * 4 + w;
  const int b = rowg >> 9, n = rowg & 511;
  const unsigned short* base = P + ((long)b * 16) * 262144 + (long)n * 512 + lane;
  float v[8];
#pragma unroll
  for (int i = 0; i < 8; ++i) {
    float s = 0.f;
#pragma unroll
    for (int ks = 0; ks < 16; ++ks) s += b2f(base[(long)ks * 262144 + i * 64]);
    v[i] = s;
  }
  float m = -1e30f;
#pragma unroll
  for (int i = 0; i < 8; ++i) m = fmaxf(m, v[i]);
#pragma unroll
  for (int off = 32; off; off >>= 1) m = fmaxf(m, __shfl_xor(m, off, 64));
  float s = 0.f;
#pragma unroll
  for (int i = 0; i < 8; ++i) { v[i] = __expf(v[i] - m); s += v[i]; }
#pragma unroll
  for (int off = 32; off; off >>= 1) s += __shfl_xor(s, off, 64);
  const float inv = 1.0f / s;
  unsigned short* R = S + (long)rowg * 512;
#pragma unroll
  for (int i = 0; i < 8; ++i) R[i * 64 + lane] = f2b(v[i] * inv);
}

// ---------------------------------------------------------------------------
// x [16][256][NPIX] fp32 (NCHW) -> xt [16][NPIX][256] bf16 (pixel-major)
// ---------------------------------------------------------------------------
__global__ __launch_bounds__(256) void xt_kernel(const float* __restrict__ x,
                                                 unsigned short* __restrict__ xt, int NPIX) {
  __shared__ unsigned short tile[64 * 65];
  const int tid = threadIdx.x;
  const int bt = blockIdx.z, ch0 = blockIdx.y * 64;
  const long pix0 = (long)blockIdx.x * 64;
  const float* src = x + ((long)bt * 256 + ch0) * NPIX + pix0;
#pragma unroll
  for (int i = 0; i < 16; ++i) {
    const int lin = i * 256 + tid;
    const int ch = lin >> 6, px = lin & 63;
    tile[ch * 65 + px] = f2b(src[(long)ch * NPIX + px]);
  }
  __syncthreads();
  unsigned short* dst = xt + ((long)bt * NPIX + pix0) * 256 + ch0;
#pragma unroll
  for (int i = 0; i < 16; ++i) {
    const int lin = i * 256 + tid;
    const int px = lin >> 6, ch = lin & 63;
    dst[(long)px * 256 + ch] = tile[ch * 65 + px];
  }
}

// ---------------------------------------------------------------------------
// Weight prep
// ---------------------------------------------------------------------------
__global__ void prep_qkv_w(const float* wq, const float* wk, const float* wv,
                           const float* bq, const float* bk, const float* bv,
                           unsigned short* Wcat, float* Bcat, int CO) {
  const int idx = blockIdx.x * 256 + threadIdx.x;
  const int n = 3 * CO * 256;
  if (idx < n) {
    const int sel = idx / (CO * 256);
    const int r = idx - sel * CO * 256;
    const float* wsel = sel == 0 ? wq : (sel == 1 ? wk : wv);
    Wcat[idx] = f2b(wsel[r]);
  }
  if (idx < 3 * CO) {
    const int sel = idx / CO;
    const int r = idx - sel * CO;
    const float* bsel = sel == 0 ? bq : (sel == 1 ? bk : bv);
    Bcat[idx] = bsel[r];
  }
}

__global__ void prep_conv_w(const float* wo, unsigned short* Wt, int CIN) {
  const int idx = blockIdx.x * 256 + threadIdx.x;
  const int n = 9 * 256 * CIN;
  if (idx < n) {
    const int t9 = idx / (256 * CIN);
    const int rem = idx - t9 * 256 * CIN;
    const int o = rem / CIN, i = rem - o * CIN;
    Wt[idx] = f2b(wo[((long)o * CIN + i) * 9 + t9]);   // [9][256][CIN]
  }
}

// ---------------------------------------------------------------------------
// Zero the 1-px halo border of a padded NHWC buffer [16][HP][WP][C]
// ---------------------------------------------------------------------------
__global__ __launch_bounds__(256) void zero_border(unsigned short* buf, int HP, int WP, int C) {
  const long i = (long)blockIdx.x * 256 + threadIdx.x;
  const int per_px = C >> 3;
  const int strip = 2 * WP + 2 * (HP - 2);
  const long tot = (long)16 * strip * per_px;
  if (i >= tot) return;
  const int c8 = (int)(i % per_px);
  const long r = i / per_px;
  const int s = (int)(r % strip);
  const int bt = (int)(r / strip);
  int y, x;
  if (s < WP) { y = 0; x = s; }
  else if (s < 2 * WP) { y = HP - 1; x = s - WP; }
  else if (s < 2 * WP + (HP - 2)) { y = s - 2 * WP + 1; x = 0; }
  else { y = s - 2 * WP - (HP - 2) + 1; x = WP - 1; }
  const short8 z = {0, 0, 0, 0, 0, 0, 0, 0};
  *(short8*)(buf + (((long)bt * HP + y) * WP + x) * C + c8 * 8) = z;
}

// ---------------------------------------------------------------------------
// Repack Y0 rows (cfg0 attention output) -> padded NHWC conv inputs.
// ---------------------------------------------------------------------------
__global__ __launch_bounds__(256) void repackY0(const unsigned short* __restrict__ Y0,
                                                unsigned short* __restrict__ CinLo,
                                                unsigned short* __restrict__ CinHi) {
  __shared__ __align__(16) unsigned short T[8704];
  const int r = blockIdx.x;            // 0..2047
  const int b = r >> 9, n = r & 511;
  const int tid = threadIdx.x;
  const int wv2 = tid >> 6, lane = tid & 63;
  const unsigned short* row = Y0 + (long)r * 8192;
  if (n < 256) {                       // lo: C=512, P=16 (4x4 patch)
#pragma unroll
    for (int q = 0; q < 4; ++q) {
      short8 v = *(const short8*)(row + tid * 32 + q * 8);
#pragma unroll
      for (int j = 0; j < 8; ++j) {
        const int f = tid * 32 + q * 8 + j;
        T[(f & 15) * 520 + (f >> 4)] = (unsigned short)v[j];
      }
    }
    __syncthreads();
    const int t = n >> 6, oh = (n >> 3) & 7, ow = n & 7;
    const int bt = b * 4 + t;
#pragma unroll
    for (int it = 0; it < 4; ++it) {
      const int pp = it * 4 + wv2;
      const int py = pp >> 2, px = pp & 3;
      short8 v = *(const short8*)(T + pp * 520 + lane * 8);
      *(short8*)(CinLo + (((long)bt * 34 + oh * 4 + py + 1) * 34 + ow * 4 + px + 1) * 1024
                 + lane * 8) = v;
    }
  } else {                             // hi: C=128, P=64 (8x8 patch)
    const int m = n - 256;
#pragma unroll
    for (int q = 0; q < 4; ++q) {
      short8 v = *(const short8*)(row + tid * 32 + q * 8);
#pragma unroll
      for (int j = 0; j < 8; ++j) {
        const int f = tid * 32 + q * 8 + j;
        T[(f & 63) * 136 + (f >> 6)] = (unsigned short)v[j];
      }
    }
    __syncthreads();
    const int t = m >> 6, oh = (m >> 3) & 7, ow = m & 7;
    const int bt = b * 4 + t;
#pragma unroll
    for (int it = 0; it < 4; ++it) {
      const int pp = it * 16 + wv2 * 4 + (lane >> 4);
      const int py = pp >> 3, px = pp & 7;
      short8 v = *(const short8*)(T + pp * 136 + (lane & 15) * 8);
      *(short8*)(CinHi + (((long)bt * 66 + oh * 8 + py + 1) * 66 + ow * 8 + px + 1) * 256
                 + (lane & 15) * 8) = v;
    }
  }
}

__global__ __launch_bounds__(256) void repackY1(const unsigned short* __restrict__ Y1,
                                                unsigned short* __restrict__ CinLo,
                                                unsigned short* __restrict__ CinHi) {
  __shared__ __align__(16) unsigned short T[2176];
  const int r = blockIdx.x;            // 0..8191
  const int b = r >> 11, n = r & 2047;
  const int tid = threadIdx.x;
  const int wv2 = tid >> 6, lane = tid & 63;
  const unsigned short* row = Y1 + (long)r * 2048;
  short8 v = *(const short8*)(row + tid * 8);
  if (n < 1024) {                      // lo: C=512, P=4 (2x2 patch)
#pragma unroll
    for (int j = 0; j < 8; ++j) {
      const int f = tid * 8 + j;
      T[(f & 3) * 520 + (f >> 2)] = (unsigned short)v[j];
    }
    __syncthreads();
    const int t = n >> 8, oh = (n >> 4) & 15, ow = n & 15;
    const int bt = b * 4 + t;
    const int pp = wv2, py = pp >> 1, px = pp & 1;
    short8 o = *(const short8*)(T + pp * 520 + lane * 8);
    *(short8*)(CinLo + (((long)bt * 34 + oh * 2 + py + 1) * 34 + ow * 2 + px + 1) * 1024
               + 512 + lane * 8) = o;
  } else {                             // hi: C=128, P=16 (4x4 patch)
    const int m = n - 1024;
#pragma unroll
    for (int j = 0; j < 8; ++j) {
      const int f = tid * 8 + j;
      T[(f & 15) * 136 + (f >> 4)] = (unsigned short)v[j];
    }
    __syncthreads();
    const int t = m >> 8, oh = (m >> 4) & 15, ow = m & 15;
    const int bt = b * 4 + t;
    const int pp = wv2 * 4 + (lane >> 4), py = pp >> 2, px = pp & 3;
    short8 o = *(const short8*)(T + pp * 136 + (lane & 15) * 8);
    *(short8*)(CinHi + (((long)bt * 66 + oh * 4 + py + 1) * 66 + ow * 4 + px + 1) * 256
               + 128 + (lane & 15) * 8) = o;
  }
}

// ---------------------------------------------------------------------------
// Sum 4 bf16 conv partial slabs (2 in P0, 2 in P1) + bias + leaky-relu -> out
// ---------------------------------------------------------------------------
__global__ __launch_bounds__(256) void reduce_lrelu(const unsigned short* __restrict__ P0,
                                                    const unsigned short* __restrict__ P1,
                                                    const float* __restrict__ bias,
                                                    float* __restrict__ out) {
  const long i = (long)blockIdx.x * 256 + threadIdx.x;   // 524288 threads, 8 elems each
  const long flat = i * 8;
  constexpr long SL = 4194304;
  short8 a = *(const short8*)(P0 + flat);
  short8 b = *(const short8*)(P0 + SL + flat);
  short8 c = *(const short8*)(P1 + flat);
  short8 d = *(const short8*)(P1 + SL + flat);
  const int co = ((int)(flat >> 10)) & 255;
  const float bv = bias[co];
  floatx4 r0, r1;
#pragma unroll
  for (int j = 0; j < 8; ++j) {
    float v = b2f((unsigned short)a[j]) + b2f((unsigned short)b[j]) +
              b2f((unsigned short)c[j]) + b2f((unsigned short)d[j]) + bv;
    v = v > 0.f ? v : 0.2f * v;
    if (j < 4) r0[j] = v; else r1[j - 4] = v;
  }
  *(floatx4*)(out + flat) = r0;
  *(floatx4*)(out + flat + 4) = r1;
}

// ---------------------------------------------------------------------------
extern "C" void kernel_launch(void* const* d_in, const int* in_sizes, int n_in,
                              void* d_out, int out_size, void* d_ws, size_t ws_size,
                              hipStream_t stream) {
  (void)in_sizes; (void)n_in; (void)out_size; (void)ws_size;
  const float* x_lo = (const float*)d_in[0];
  const float* x_hi = (const float*)d_in[1];
  const float* wq_lo = (const float*)d_in[3];
  const float* bq_lo = (const float*)d_in[4];
  const float* wk_lo = (const float*)d_in[5];
  const float* bk_lo = (const float*)d_in[6];
  const float* wv_lo = (const float*)d_in[7];
  const float* bv_lo = (const float*)d_in[8];
  const float* wq_hi = (const float*)d_in[9];
  const float* bq_hi = (const float*)d_in[10];
  const float* wk_hi = (const float*)d_in[11];
  const float* bk_hi = (const float*)d_in[12];
  const float* wv_hi = (const float*)d_in[13];
  const float* bv_hi = (const float*)d_in[14];
  const float* wo_lo = (const float*)d_in[15];
  const float* bo_lo = (const float*)d_in[16];
  const float* wo_hi = (const float*)d_in[17];
  const float* bo_hi = (const float*)d_in[18];
  float* out = (float*)d_out;

  char* ws = (char*)d_ws;
  const long B0 = 33554432;
  unsigned short* Qp0 = (unsigned short*)(ws);
  unsigned short* Kp0 = (unsigned short*)(ws + B0);
  unsigned short* V0t = (unsigned short*)(ws + 2 * B0);
  unsigned short* Qp1 = (unsigned short*)(ws + 3 * B0);
  unsigned short* Kp1 = (unsigned short*)(ws + 4 * B0);
  unsigned short* V1t = (unsigned short*)(ws + 5 * B0);
  char* ptr = ws + 6 * B0;
  unsigned short* S0 = (unsigned short*)ptr;     ptr += 2097152;
  unsigned short* Xt_lo = (unsigned short*)ptr;  ptr += 8388608;
  unsigned short* Xt_hi = (unsigned short*)ptr;  ptr += 33554432;
  unsigned short* Wcat_lo = (unsigned short*)ptr; ptr += 1572864;
  unsigned short* Wcat_hi = (unsigned short*)ptr; ptr += 393216;
  float* Bcat_lo = (float*)ptr;                  ptr += 12288;
  float* Bcat_hi = (float*)ptr;                  ptr += 3072;
  unsigned short* Wt_lo = (unsigned short*)ptr;  ptr += 4718592;
  unsigned short* Wt_hi = (unsigned short*)ptr;  ptr += 1179648;
  unsigned short* S1 = Kp0;
  unsigned short* Y0 = Qp0;
  unsigned short* Y1 = Qp1;
  unsigned short* CinP_lo = Kp0;
  unsigned short* CinP_hi = Kp1;
  unsigned short* S0p = Xt_hi;          // 64 bf16 slabs x 262144 = 33.5 MB
  unsigned short* PC0 = Qp0;            // conv_lo bf16 partial slabs 0,1 (16.8 MB)
  unsigned short* PC1 = Qp1;            // conv_lo bf16 partial slabs 2,3

  // --- weight/input prep ---
  prep_qkv_w<<<(3 * 1024 * 256 + 255) / 256, 256, 0, stream>>>(
      wq_lo, wk_lo, wv_lo, bq_lo, bk_lo, bv_lo, Wcat_lo, Bcat_lo, 1024);
  prep_qkv_w<<<(3 * 256 * 256 + 255) / 256, 256, 0, stream>>>(
      wq_hi, wk_hi, wv_hi, bq_hi, bk_hi, bv_hi, Wcat_hi, Bcat_hi, 256);
  prep_conv_w<<<(9 * 256 * 1024 + 255) / 256, 256, 0, stream>>>(wo_lo, Wt_lo, 1024);
  prep_conv_w<<<(9 * 256 * 256 + 255) / 256, 256, 0, stream>>>(wo_hi, Wt_hi, 256);
  xt_kernel<<<dim3(16, 4, 16), 256, 0, stream>>>(x_lo, Xt_lo, 1024);
  xt_kernel<<<dim3(64, 4, 16), 256, 0, stream>>>(x_hi, Xt_hi, 4096);

  // --- QKV projections (1x1 conv as TN-GEMM), staged coalesced scatter ---
  {
    GemmP p{};
    p.A = Wcat_lo; p.B = Xt_lo; p.sAb = 0; p.sBb = 1024L * 256;
    p.lda = 256; p.ldb = 256; p.K = 256;
    p.bias = Bcat_lo;
    p.Q0 = Qp0; p.K0 = Kp0; p.V0t = V0t; p.Q1 = Qp1; p.K1 = Kp1; p.V1t = V1t;
    gemm256<2><<<dim3(4, 12, 16), 512, 0, stream>>>(p);
    p.A = Wcat_hi; p.B = Xt_hi; p.sBb = 4096L * 256; p.bias = Bcat_hi;
    gemm256<3><<<dim3(16, 3, 16), 512, 0, stream>>>(p);
  }

  // --- attention cfg0: n=512, d=8192 (split-K 16, bf16 partials) ---
  {
    GemmP s{};
    s.A = Qp0; s.B = Kp0; s.sAb = 512L * 8192; s.sBb = 512L * 8192;
    s.lda = 8192; s.ldb = 8192; s.K = 8192;
    s.C = S0p; s.sCb = 262144; s.ldc = 512;
    gemm256<1><<<dim3(2, 2, 64), 512, 0, stream>>>(s);
    softmax_red16<<<512, 256, 0, stream>>>(S0p, S0);
    GemmP pv{};
    pv.A = S0; pv.B = V0t; pv.sAb = 512L * 512; pv.sBb = 8192L * 512;
    pv.lda = 512; pv.ldb = 512; pv.K = 512;
    pv.C = Y0; pv.sCb = 512L * 8192; pv.ldc = 8192;
    gemm256<0><<<dim3(32, 2, 4), 512, 0, stream>>>(pv);
  }

  // --- attention cfg1: n=2048, d=2048 ---
  {
    GemmP s{};
    s.A = Qp1; s.B = Kp1; s.sAb = 2048L * 2048; s.sBb = 2048L * 2048;
    s.lda = 2048; s.ldb = 2048; s.K = 2048;
    s.C = S1; s.sCb = 2048L * 2048; s.ldc = 2048;
    gemm256<0><<<dim3(8, 8, 4), 512, 0, stream>>>(s);
    softmax_rows<2048><<<2048, 256, 0, stream>>>(S1);
    GemmP pv{};
    pv.A = S1; pv.B = V1t; pv.sAb = 2048L * 2048; pv.sBb = 2048L * 2048;
    pv.lda = 2048; pv.ldb = 2048; pv.K = 2048;
    pv.C = Y1; pv.sCb = 2048L * 2048; pv.ldc = 2048;
    gemm256<0><<<dim3(8, 8, 4), 512, 0, stream>>>(pv);
  }

  // --- halo zeroing + coalesced from_patches repack into padded NHWC ---
  zero_border<<<1056, 256, 0, stream>>>(CinP_lo, 34, 34, 1024);
  zero_border<<<520, 256, 0, stream>>>(CinP_hi, 66, 66, 256);
  repackY0<<<2048, 256, 0, stream>>>(Y0, CinP_lo, CinP_hi);
  repackY1<<<8192, 256, 0, stream>>>(Y1, CinP_lo, CinP_hi);

  // --- 3x3 convs as im2col GEMM on the 256-tile pipeline ---
  conv256<32, 32, 1024, 4, true><<<dim3(4, 1, 64), 512, 0, stream>>>(
      CinP_lo, Wt_lo, bo_lo, out, PC0, PC1);
  reduce_lrelu<<<2048, 256, 0, stream>>>(PC0, PC1, bo_lo, out);
  conv256<64, 64, 256, 1, false><<<dim3(16, 1, 16), 512, 0, stream>>>(
      CinP_hi, Wt_hi, bo_hi, out + 4194304, nullptr, nullptr);
}

// Round 10
// 550.714 us; speedup vs baseline: 1.9924x; 1.0073x over previous
//
#include <hip/hip_runtime.h>
#include <hip/hip_bf16.h>
#include <stdint.h>

typedef __attribute__((ext_vector_type(8))) short short8;
typedef __attribute__((ext_vector_type(4))) short short4v;
typedef __attribute__((ext_vector_type(2))) short short2v;
typedef __attribute__((ext_vector_type(4))) float floatx4;

__device__ __forceinline__ unsigned short f2b(float f) {
  unsigned u = __builtin_bit_cast(unsigned, f);
  unsigned r = u + 0x7fffu + ((u >> 16) & 1u);
  return (unsigned short)(r >> 16);
}
__device__ __forceinline__ float b2f(unsigned short h) {
  unsigned u = ((unsigned)h) << 16;
  return __builtin_bit_cast(float, u);
}
__device__ __forceinline__ void glds16(const unsigned short* src, unsigned short* dst) {
  __builtin_amdgcn_global_load_lds((const __attribute__((address_space(1))) void*)src,
                                   (__attribute__((address_space(3))) void*)dst, 16, 0, 0);
}
// epilogue LDS swizzle: row r (0..255), o = byte offset in 512B row.
__device__ __forceinline__ int swz(int r, int o) {
  return (r << 9) + (o ^ ((((o >> 7) & 3) ^ (r & 7)) << 4));
}
// T1: bijective XCD-contiguous work remap (requires nwg % 8 == 0).
__device__ __forceinline__ void xcd_remap(int& bx, int& by, int& bz) {
  const int gx = gridDim.x, gy = gridDim.y;
  const int nwg = gx * gy * (int)gridDim.z;
  int lin = bx + gx * (by + gy * bz);
  lin = (lin & 7) * (nwg >> 3) + (lin >> 3);
  bx = lin % gx; const int r = lin / gx;
  by = r % gy; bz = r / gy;
}

// ---------------------------------------------------------------------------
// 256x256-tile TN GEMM core: 512 thr = 8 waves (2Mx4N); BK=32; 4-buffer ring;
// software-pipelined K-loop: vmcnt(4) ladder (tiles t,t+1 resident), next-tile
// af/bf prefetched during G2 -> G1 issues MFMA immediately post-barrier.
// 1 barrier/K-tile; setprio; stage-swizzle f(row)=(row>>1)&3 (2-way = free).
// EPI 0: staged bf16 C. EPI 1: split-K(16) bf16 partials. EPI 2/3: QKV scatter.
// ---------------------------------------------------------------------------
struct GemmP {
  const unsigned short* A;
  const unsigned short* B;
  long sAb, sBb;
  int lda, ldb, K;
  unsigned short* C; long sCb; int ldc;
  const float* bias;
  unsigned short *Q0, *K0, *V0t, *Q1, *K1, *V1t;
};

template<int EPI>
__global__ __launch_bounds__(512) void gemm256(GemmP p) {
  __shared__ __align__(16) unsigned short LDS[65536];
  const int tid = threadIdx.x;
  const int wv = tid >> 6, lane = tid & 63;
  const int wm = wv >> 2, wn = wv & 3;
  const int g = lane >> 4, l16 = lane & 15;
  int bx = blockIdx.x, by = blockIdx.y, bz = blockIdx.z;
  xcd_remap(bx, by, bz);
  const int m0 = by * 256, n0 = bx * 256;

  int bb = bz, koff = 0, Keff = p.K;
  if constexpr (EPI == 1) { bb = bz >> 4; koff = (bz & 15) * (p.K >> 4); Keff = p.K >> 4; }
  const unsigned short* Ab = p.A + (long)bb * p.sAb + (long)m0 * p.lda + koff;
  const unsigned short* Bb = p.B + (long)bb * p.sBb + (long)n0 * p.ldb + koff;
  const int NT = Keff >> 5;

  const int r0 = tid >> 2;
  const int cs = (tid & 3) ^ ((r0 >> 1) & 3);
  const unsigned short* aS0 = Ab + (long)r0 * p.lda + cs * 8;
  const unsigned short* aS1 = aS0 + (long)128 * p.lda;
  const unsigned short* bS0 = Bb + (long)r0 * p.ldb + cs * 8;
  const unsigned short* bS1 = bS0 + (long)128 * p.ldb;
  unsigned short* const lds0 = (unsigned short*)LDS;
  const int wbase = wv * 512;

  auto STAGE_A = [&](int t) {
    unsigned short* d = lds0 + (t & 3) * 16384;
    const long ko = (long)t * 32;
    glds16(aS0 + ko, d + wbase);
    glds16(aS1 + ko, d + 4096 + wbase);
  };
  auto STAGE_B = [&](int t) {
    unsigned short* d = lds0 + (t & 3) * 16384 + 8192;
    const long ko = (long)t * 32;
    glds16(bS0 + ko, d + wbase);
    glds16(bS1 + ko, d + 4096 + wbase);
  };

  STAGE_A(0); STAGE_B(0); STAGE_A(1); STAGE_B(1); STAGE_A(2); STAGE_B(2);

  floatx4 acc[8][4];
  const floatx4 z4 = {0.f, 0.f, 0.f, 0.f};
#pragma unroll
  for (int i = 0; i < 8; ++i)
#pragma unroll
    for (int j = 0; j < 4; ++j) acc[i][j] = z4;

  const int loff = l16 * 32 + ((g ^ ((l16 >> 1) & 3)) * 8);
  const int aRowB = wm * 128;

  // prologue: tile 0 visible, preload its af/bf
  asm volatile("s_waitcnt vmcnt(8)" ::: "memory");
  __builtin_amdgcn_s_barrier();
  short8 bf[4], af[4];
#pragma unroll
  for (int ni = 0; ni < 4; ++ni)
    bf[ni] = *(const short8*)(lds0 + 8192 + (wn * 64 + ni * 16) * 32 + loff);
#pragma unroll
  for (int mi = 0; mi < 4; ++mi)
    af[mi] = *(const short8*)(lds0 + (aRowB + mi * 16) * 32 + loff);

  for (int t = 0; t < NT; ++t) {
    const unsigned short* As = lds0 + (t & 3) * 16384;
    const unsigned short* AsN = lds0 + ((t + 1) & 3) * 16384;
    if (t < NT - 2) asm volatile("s_waitcnt vmcnt(4)" ::: "memory");
    else            asm volatile("s_waitcnt vmcnt(0)" ::: "memory");
    __builtin_amdgcn_s_barrier();
    __builtin_amdgcn_sched_barrier(0);
    if (t + 3 < NT) STAGE_A(t + 3);
    short8 ag[4];
#pragma unroll
    for (int mi = 0; mi < 4; ++mi)
      ag[mi] = *(const short8*)(As + (aRowB + 64 + mi * 16) * 32 + loff);
    __builtin_amdgcn_s_setprio(1);
#pragma unroll
    for (int mi = 0; mi < 4; ++mi)
#pragma unroll
      for (int ni = 0; ni < 4; ++ni)
        acc[mi][ni] = __builtin_amdgcn_mfma_f32_16x16x32_bf16(af[mi], bf[ni], acc[mi][ni], 0, 0, 0);
    __builtin_amdgcn_s_setprio(0);
    if (t + 3 < NT) STAGE_B(t + 3);
    short8 bfN[4], afN[4];
    if (t + 1 < NT) {
      const unsigned short* BsN = AsN + 8192;
#pragma unroll
      for (int ni = 0; ni < 4; ++ni)
        bfN[ni] = *(const short8*)(BsN + (wn * 64 + ni * 16) * 32 + loff);
#pragma unroll
      for (int mi = 0; mi < 4; ++mi)
        afN[mi] = *(const short8*)(AsN + (aRowB + mi * 16) * 32 + loff);
    }
    __builtin_amdgcn_s_setprio(1);
#pragma unroll
    for (int mi = 0; mi < 4; ++mi)
#pragma unroll
      for (int ni = 0; ni < 4; ++ni)
        acc[4 + mi][ni] = __builtin_amdgcn_mfma_f32_16x16x32_bf16(ag[mi], bf[ni], acc[4 + mi][ni], 0, 0, 0);
    __builtin_amdgcn_s_setprio(0);
    if (t + 1 < NT) {
#pragma unroll
      for (int i = 0; i < 4; ++i) { bf[i] = bfN[i]; af[i] = afN[i]; }
    }
  }

  if constexpr (EPI == 1) {          // bf16 partial store
    unsigned short* C = p.C + (long)bz * p.sCb;
#pragma unroll
    for (int mi = 0; mi < 8; ++mi) {
#pragma unroll
      for (int ni = 0; ni < 4; ++ni) {
        const int col = n0 + wn * 64 + ni * 16 + l16;
#pragma unroll
        for (int r4 = 0; r4 < 4; ++r4) {
          const int row = m0 + wm * 128 + mi * 16 + g * 4 + r4;
          C[(long)row * p.ldc + col] = f2b(acc[mi][ni][r4]);
        }
      }
    }
  } else {
    // ------- staged epilogue: acc (+bias/scale) -> LDS tile [256co][256pix] -------
    __syncthreads();
    char* shb = (char*)LDS;
    const int sel = (EPI == 2) ? (m0 >> 10) : (m0 >> 8);
#pragma unroll
    for (int mi = 0; mi < 8; ++mi) {
#pragma unroll
      for (int ni = 0; ni < 4; ++ni) {
        const int c = wn * 64 + ni * 16 + l16;
#pragma unroll
        for (int r4 = 0; r4 < 4; ++r4) {
          const int rr = wm * 128 + mi * 16 + g * 4 + r4;
          float v = acc[mi][ni][r4];
          if constexpr (EPI == 2 || EPI == 3) {
            v += p.bias[m0 + rr];
            if (sel == 0) {
              float sc;
              if constexpr (EPI == 2) sc = ((m0 & 1023) < 512) ? 0.011048543456039806f
                                                               : 0.02209708691207961f;
              else                    sc = (rr < 128) ? 0.011048543456039806f
                                                      : 0.02209708691207961f;
              v *= sc;
            }
          }
          *(unsigned short*)(shb + swz(rr, c * 2)) = f2b(v);
        }
      }
    }
    __syncthreads();

    if constexpr (EPI == 0) {
      unsigned short* C = p.C + (long)bz * p.sCb;
#pragma unroll
      for (int j = 0; j < 16; ++j) {
        const int e = j * 512 + tid;
        const int r = e >> 5, ck = e & 31;
        short8 v = *(const short8*)(shb + swz(r, ck * 16));
        *(short8*)(C + (long)(m0 + r) * p.ldc + n0 + ck * 8) = v;
      }
    } else if constexpr (EPI == 2) {    // ---- QKV lo ----
      const int chb = m0 & 1023;
      const bool cfg0 = chb < 512;
      const int b = bz >> 2, tt = bz & 3;
      const int k0 = n0 >> 8;
      unsigned short* dst = cfg0 ? (sel == 0 ? p.Q0 : sel == 1 ? p.K0 : p.V0t)
                                 : (sel == 0 ? p.Q1 : sel == 1 ? p.K1 : p.V1t);
      if (sel != 2) {
        if (cfg0) {                      // 4x4 patches, d=8192
          const long base = (long)(b * 512) * 8192;
#pragma unroll
          for (int j = 0; j < 16; ++j) {
            const int e = j * 512 + tid;
            const int pi = e >> 9, idx2 = e & 511;
            const int ch = idx2 >> 1, hf = idx2 & 1;
            const int oyL = pi >> 3, ox = pi & 7;
            const int nseq = (tt * 8 + 2 * k0 + oyL) * 8 + ox;
            const int yl = oyL * 4 + hf * 2;
            short4v a = *(const short4v*)(shb + swz(ch, (yl * 32 + ox * 4) * 2));
            short4v b2 = *(const short4v*)(shb + swz(ch, ((yl + 1) * 32 + ox * 4) * 2));
            short8 v = {a[0], a[1], a[2], a[3], b2[0], b2[1], b2[2], b2[3]};
            *(short8*)(dst + base + (long)nseq * 8192 + (chb + ch) * 16 + hf * 8) = v;
          }
        } else {                         // 2x2 patches, d=2048
          const int c2lo = chb - 512;
          const long base = (long)(b * 2048) * 2048;
#pragma unroll
          for (int j = 0; j < 16; ++j) {
            const int e = j * 512 + tid;
            const int pi = e >> 7, cp = e & 127;
            const int oyL = pi >> 4, ox = pi & 15;
            const int nseq = (tt * 16 + 4 * k0 + oyL) * 16 + ox;
            short8 v;
#pragma unroll
            for (int rr = 0; rr < 2; ++rr) {
#pragma unroll
              for (int k = 0; k < 2; ++k) {
                short2v pr = *(const short2v*)(shb +
                    swz(cp * 2 + rr, ((oyL * 2 + k) * 32 + ox * 2) * 2));
                v[rr * 4 + k * 2] = pr[0];
                v[rr * 4 + k * 2 + 1] = pr[1];
              }
            }
            *(short8*)(dst + base + (long)nseq * 2048 + (c2lo + cp * 2) * 4) = v;
          }
        }
      } else {                           // V transposed [f][nseq]
        if (cfg0) {
          const long base = (long)(b * 8192) * 512;
#pragma unroll
          for (int j = 0; j < 16; ++j) {
            const int e = j * 512 + tid;
            const int oyL = e >> 12, fu = e & 4095;
            const int ch = fu >> 4, pp = fu & 15;
            const int py = pp >> 2, px = pp & 3;
            const int yl = oyL * 4 + py;
            short8 v;
#pragma unroll
            for (int ox = 0; ox < 8; ++ox)
              v[ox] = *(const unsigned short*)(shb + swz(ch, (yl * 32 + ox * 4 + px) * 2));
            const long f = (long)(chb + ch) * 16 + pp;
            *(short8*)(dst + base + f * 512 + (tt * 8 + 2 * k0 + oyL) * 8) = v;
          }
        } else {
          const int c2lo = chb - 512;
          const long base = (long)(b * 2048) * 2048;
#pragma unroll
          for (int j = 0; j < 16; ++j) {
            const int e = j * 512 + tid;
            const int he = e & 1, oyL = (e >> 1) & 3, fu = e >> 3;
            const int c2 = fu >> 2, pp = fu & 3;
            const int py = pp >> 1, px = pp & 1;
            const int yl = oyL * 2 + py;
            short8 v;
#pragma unroll
            for (int i = 0; i < 8; ++i) {
              const int ox = he * 8 + i;
              v[i] = *(const unsigned short*)(shb + swz(c2, (yl * 32 + ox * 2 + px) * 2));
            }
            const long f = (long)(c2lo + c2) * 4 + pp;
            *(short8*)(dst + base + f * 2048 + (tt * 16 + 4 * k0 + oyL) * 16 + he * 8) = v;
          }
        }
      }
    } else if constexpr (EPI == 3) {    // ---- QKV hi ----
      const int b = bz >> 2, tt = bz & 3;
      const int k0 = n0 >> 8;
      const int oyA = k0 >> 1, pyb = (k0 & 1) * 4;
      unsigned short* dstA = sel == 0 ? p.Q0 : sel == 1 ? p.K0 : p.V0t;
      unsigned short* dstB = sel == 0 ? p.Q1 : sel == 1 ? p.K1 : p.V1t;
      if (sel != 2) {
#pragma unroll
        for (int j = 0; j < 16; ++j) {
          const int e = j * 512 + tid;
          if (e < 4096) {                // cfg0: 8x8 patches
            const int ox = e >> 9, cy = e & 511;
            const int ch = cy >> 2, yl = cy & 3;
            const int nseq = 256 + (tt * 8 + oyA) * 8 + ox;
            short8 v = *(const short8*)(shb + swz(ch, (yl * 64 + ox * 8) * 2));
            *(short8*)(dstA + ((long)(b * 512 + nseq)) * 8192 + ch * 64 + (pyb + yl) * 8) = v;
          } else {                       // cfg1: 4x4 patches
            const int ee = e - 4096;
            const int ox = ee >> 8, cc = ee & 255;
            const int c2 = cc >> 1, hf = cc & 1;
            const int nseq = 1024 + (tt * 16 + k0) * 16 + ox;
            short8 v;
#pragma unroll
            for (int k = 0; k < 2; ++k) {
              short4v a = *(const short4v*)(shb +
                  swz(128 + c2, ((hf * 2 + k) * 64 + ox * 4) * 2));
              v[k * 4] = a[0]; v[k * 4 + 1] = a[1]; v[k * 4 + 2] = a[2]; v[k * 4 + 3] = a[3];
            }
            *(short8*)(dstB + ((long)(b * 2048 + nseq)) * 2048 + c2 * 16 + hf * 8) = v;
          }
        }
      } else {
#pragma unroll
        for (int j = 0; j < 16; ++j) {
          const int e = j * 512 + tid;
          if (e < 4096) {                // cfg0 V
            const int ch = e >> 5, yl = (e >> 3) & 3, px = e & 7;
            short8 v;
#pragma unroll
            for (int ox = 0; ox < 8; ++ox)
              v[ox] = *(const unsigned short*)(shb + swz(ch, (yl * 64 + ox * 8 + px) * 2));
            const long f = (long)ch * 64 + (pyb + yl) * 8 + px;
            *(short8*)(dstA + ((long)b * 8192 + f) * 512 + 256 + (tt * 8 + oyA) * 8) = v;
          } else {                       // cfg1 V
            const int ee = e - 4096;
            const int he = ee & 1, fu = ee >> 1;
            const int c2 = fu >> 4, pp = fu & 15;
            const int py = pp >> 2, px = pp & 3;
            short8 v;
#pragma unroll
            for (int i = 0; i < 8; ++i) {
              const int x = (he * 8 + i) * 4 + px;
              v[i] = *(const unsigned short*)(shb + swz(128 + c2, (py * 64 + x) * 2));
            }
            const long f = (long)c2 * 16 + pp;
            *(short8*)(dstB + ((long)b * 2048 + f) * 2048 + 1024 + (tt * 16 + k0) * 16 + he * 8) = v;
          }
        }
      }
    }
  }
}

// ---------------------------------------------------------------------------
// 3x3 conv as im2col GEMM (same pipelined core). PARTIAL: bf16 partial slabs.
// ---------------------------------------------------------------------------
template<int H, int W, int CIN, int KS, bool PARTIAL>
__global__ __launch_bounds__(512) void conv256(const unsigned short* __restrict__ Cinp,
                                               const unsigned short* __restrict__ Wt,
                                               const float* __restrict__ bias,
                                               float* __restrict__ out,
                                               unsigned short* __restrict__ P0,
                                               unsigned short* __restrict__ P1) {
  constexpr int HP = H + 2, WP = W + 2;
  constexpr int CC = CIN / KS;
  constexpr int NT = 9 * CC / 32;
  __shared__ __align__(16) unsigned short LDS[65536];
  const int tid = threadIdx.x;
  const int wv = tid >> 6, lane = tid & 63;
  const int wm = wv >> 2, wn = wv & 3;
  const int g = lane >> 4, l16 = lane & 15;
  int bx = blockIdx.x, by = blockIdx.y, bz = blockIdx.z;
  xcd_remap(bx, by, bz);
  const int bt = bz / KS, ks = bz % KS;
  const int n0 = bx * 256;

  const int r0 = tid >> 2;
  const int cs = (tid & 3) ^ ((r0 >> 1) & 3);
  const unsigned short* wA0 = Wt + (long)r0 * CIN + ks * CC + cs * 8;
  const unsigned short* wA1 = wA0 + (long)128 * CIN;
  const int p0 = n0 + r0, p1 = p0 + 128;
  const int y0p = p0 / W, x0p = p0 % W;
  const int y1p = p1 / W, x1p = p1 % W;
  const unsigned short* cB = Cinp + (long)bt * HP * WP * CIN + ks * CC + cs * 8;
  const unsigned short* pB0 = cB + ((long)y0p * WP + x0p) * CIN;
  const unsigned short* pB1 = cB + ((long)y1p * WP + x1p) * CIN;
  unsigned short* const lds0 = (unsigned short*)LDS;
  const int wbase = wv * 512;

  auto STAGE_A = [&](int t) {
    unsigned short* d = lds0 + (t & 3) * 16384;
    const int tap = t >> 3, tc = (t & 7) * 32;
    const long off = (long)tap * (256L * CIN) + tc;
    glds16(wA0 + off, d + wbase);
    glds16(wA1 + off, d + 4096 + wbase);
  };
  auto STAGE_B = [&](int t) {
    unsigned short* d = lds0 + (t & 3) * 16384 + 8192;
    const int tap = t >> 3, tc = (t & 7) * 32;
    const int ky = tap / 3, kx = tap - ky * 3;
    const long off = ((long)ky * WP + kx) * CIN + tc;
    glds16(pB0 + off, d + wbase);
    glds16(pB1 + off, d + 4096 + wbase);
  };

  STAGE_A(0); STAGE_B(0); STAGE_A(1); STAGE_B(1); STAGE_A(2); STAGE_B(2);

  floatx4 acc[8][4];
  const floatx4 z4 = {0.f, 0.f, 0.f, 0.f};
#pragma unroll
  for (int i = 0; i < 8; ++i)
#pragma unroll
    for (int j = 0; j < 4; ++j) acc[i][j] = z4;

  const int loff = l16 * 32 + ((g ^ ((l16 >> 1) & 3)) * 8);
  const int aRowB = wm * 128;

  asm volatile("s_waitcnt vmcnt(8)" ::: "memory");
  __builtin_amdgcn_s_barrier();
  short8 bf[4], af[4];
#pragma unroll
  for (int ni = 0; ni < 4; ++ni)
    bf[ni] = *(const short8*)(lds0 + 8192 + (wn * 64 + ni * 16) * 32 + loff);
#pragma unroll
  for (int mi = 0; mi < 4; ++mi)
    af[mi] = *(const short8*)(lds0 + (aRowB + mi * 16) * 32 + loff);

  for (int t = 0; t < NT; ++t) {
    const unsigned short* As = lds0 + (t & 3) * 16384;
    const unsigned short* AsN = lds0 + ((t + 1) & 3) * 16384;
    if (t < NT - 2) asm volatile("s_waitcnt vmcnt(4)" ::: "memory");
    else            asm volatile("s_waitcnt vmcnt(0)" ::: "memory");
    __builtin_amdgcn_s_barrier();
    __builtin_amdgcn_sched_barrier(0);
    if (t + 3 < NT) STAGE_A(t + 3);
    short8 ag[4];
#pragma unroll
    for (int mi = 0; mi < 4; ++mi)
      ag[mi] = *(const short8*)(As + (aRowB + 64 + mi * 16) * 32 + loff);
    __builtin_amdgcn_s_setprio(1);
#pragma unroll
    for (int mi = 0; mi < 4; ++mi)
#pragma unroll
      for (int ni = 0; ni < 4; ++ni)
        acc[mi][ni] = __builtin_amdgcn_mfma_f32_16x16x32_bf16(af[mi], bf[ni], acc[mi][ni], 0, 0, 0);
    __builtin_amdgcn_s_setprio(0);
    if (t + 3 < NT) STAGE_B(t + 3);
    short8 bfN[4], afN[4];
    if (t + 1 < NT) {
      const unsigned short* BsN = AsN + 8192;
#pragma unroll
      for (int ni = 0; ni < 4; ++ni)
        bfN[ni] = *(const short8*)(BsN + (wn * 64 + ni * 16) * 32 + loff);
#pragma unroll
      for (int mi = 0; mi < 4; ++mi)
        afN[mi] = *(const short8*)(AsN + (aRowB + mi * 16) * 32 + loff);
    }
    __builtin_amdgcn_s_setprio(1);
#pragma unroll
    for (int mi = 0; mi < 4; ++mi)
#pragma unroll
      for (int ni = 0; ni < 4; ++ni)
        acc[4 + mi][ni] = __builtin_amdgcn_mfma_f32_16x16x32_bf16(ag[mi], bf[ni], acc[4 + mi][ni], 0, 0, 0);
    __builtin_amdgcn_s_setprio(0);
    if (t + 1 < NT) {
#pragma unroll
      for (int i = 0; i < 4; ++i) { bf[i] = bfN[i]; af[i] = afN[i]; }
    }
  }

  if constexpr (!PARTIAL) {
#pragma unroll
    for (int mi = 0; mi < 8; ++mi) {
#pragma unroll
      for (int ni = 0; ni < 4; ++ni) {
        const int pn = n0 + wn * 64 + ni * 16 + l16;
        const int y = pn / W, x = pn % W;
#pragma unroll
        for (int r4 = 0; r4 < 4; ++r4) {
          const int co = wm * 128 + mi * 16 + g * 4 + r4;
          float v = acc[mi][ni][r4] + bias[co];
          v = v > 0.f ? v : 0.2f * v;
          out[(((long)bt * 256 + co) * H + y) * W + x] = v;
        }
      }
    }
  } else {
    unsigned short* pout = (ks < 2 ? P0 : P1) + (long)(ks & 1) * (16L * 256 * H * W);
#pragma unroll
    for (int mi = 0; mi < 8; ++mi) {
#pragma unroll
      for (int ni = 0; ni < 4; ++ni) {
        const int pn = n0 + wn * 64 + ni * 16 + l16;
        const int y = pn / W, x = pn % W;
#pragma unroll
        for (int r4 = 0; r4 < 4; ++r4) {
          const int co = wm * 128 + mi * 16 + g * 4 + r4;
          pout[(((long)bt * 256 + co) * H + y) * W + x] = f2b(acc[mi][ni][r4]);
        }
      }
    }
  }
}

// ---------------------------------------------------------------------------
// Row softmax in-place on bf16 rows of length L. One wave per row.
// ---------------------------------------------------------------------------
template<int L>
__global__ __launch_bounds__(256) void softmax_rows(unsigned short* S) {
  const int w = threadIdx.x >> 6, lane = threadIdx.x & 63;
  const long row = (long)blockIdx.x * 4 + w;
  unsigned short* R = S + row * L;
  constexpr int NC = L / 64;
  float v[NC];
  float m = -1e30f;
#pragma unroll
  for (int i = 0; i < NC; ++i) { v[i] = b2f(R[i * 64 + lane]); m = fmaxf(m, v[i]); }
#pragma unroll
  for (int off = 32; off; off >>= 1) m = fmaxf(m, __shfl_xor(m, off, 64));
  float s = 0.f;
#pragma unroll
  for (int i = 0; i < NC; ++i) { v[i] = __expf(v[i] - m); s += v[i]; }
#pragma unroll
  for (int off = 32; off; off >>= 1) s += __shfl_xor(s, off, 64);
  const float inv = 1.0f / s;
#pragma unroll
  for (int i = 0; i < NC; ++i) R[i * 64 + lane] = f2b(v[i] * inv);
}

// ---------------------------------------------------------------------------
// S0: sum 16 bf16 split-K slabs [b*16+ks][512][512] -> softmax -> bf16
// ---------------------------------------------------------------------------
__global__ __launch_bounds__(256) void softmax_red16(const unsigned short* __restrict__ P,
                                                     unsigned short* __restrict__ S) {
  const int w = threadIdx.x >> 6, lane = threadIdx.x & 63;
  const int rowg = blockIdx.x * 4 + w;
  const int b = rowg >> 9, n = rowg & 511;
  const unsigned short* base = P + ((long)b * 16) * 262144 + (long)n * 512 + lane;
  float v[8];
#pragma unroll
  for (int i = 0; i < 8; ++i) {
    float s = 0.f;
#pragma unroll
    for (int ks = 0; ks < 16; ++ks) s += b2f(base[(long)ks * 262144 + i * 64]);
    v[i] = s;
  }
  float m = -1e30f;
#pragma unroll
  for (int i = 0; i < 8; ++i) m = fmaxf(m, v[i]);
#pragma unroll
  for (int off = 32; off; off >>= 1) m = fmaxf(m, __shfl_xor(m, off, 64));
  float s = 0.f;
#pragma unroll
  for (int i = 0; i < 8; ++i) { v[i] = __expf(v[i] - m); s += v[i]; }
#pragma unroll
  for (int off = 32; off; off >>= 1) s += __shfl_xor(s, off, 64);
  const float inv = 1.0f / s;
  unsigned short* R = S + (long)rowg * 512;
#pragma unroll
  for (int i = 0; i < 8; ++i) R[i * 64 + lane] = f2b(v[i] * inv);
}

// ---------------------------------------------------------------------------
// x [16][256][NPIX] fp32 (NCHW) -> xt [16][NPIX][256] bf16 (pixel-major)
// ---------------------------------------------------------------------------
__global__ __launch_bounds__(256) void xt_kernel(const float* __restrict__ x,
                                                 unsigned short* __restrict__ xt, int NPIX) {
  __shared__ unsigned short tile[64 * 65];
  const int tid = threadIdx.x;
  const int bt = blockIdx.z, ch0 = blockIdx.y * 64;
  const long pix0 = (long)blockIdx.x * 64;
  const float* src = x + ((long)bt * 256 + ch0) * NPIX + pix0;
#pragma unroll
  for (int i = 0; i < 16; ++i) {
    const int lin = i * 256 + tid;
    const int ch = lin >> 6, px = lin & 63;
    tile[ch * 65 + px] = f2b(src[(long)ch * NPIX + px]);
  }
  __syncthreads();
  unsigned short* dst = xt + ((long)bt * NPIX + pix0) * 256 + ch0;
#pragma unroll
  for (int i = 0; i < 16; ++i) {
    const int lin = i * 256 + tid;
    const int px = lin >> 6, ch = lin & 63;
    dst[(long)px * 256 + ch] = tile[ch * 65 + px];
  }
}

// ---------------------------------------------------------------------------
// Weight prep
// ---------------------------------------------------------------------------
__global__ void prep_qkv_w(const float* wq, const float* wk, const float* wv,
                           const float* bq, const float* bk, const float* bv,
                           unsigned short* Wcat, float* Bcat, int CO) {
  const int idx = blockIdx.x * 256 + threadIdx.x;
  const int n = 3 * CO * 256;
  if (idx < n) {
    const int sel = idx / (CO * 256);
    const int r = idx - sel * CO * 256;
    const float* wsel = sel == 0 ? wq : (sel == 1 ? wk : wv);
    Wcat[idx] = f2b(wsel[r]);
  }
  if (idx < 3 * CO) {
    const int sel = idx / CO;
    const int r = idx - sel * CO;
    const float* bsel = sel == 0 ? bq : (sel == 1 ? bk : bv);
    Bcat[idx] = bsel[r];
  }
}

__global__ void prep_conv_w(const float* wo, unsigned short* Wt, int CIN) {
  const int idx = blockIdx.x * 256 + threadIdx.x;
  const int n = 9 * 256 * CIN;
  if (idx < n) {
    const int t9 = idx / (256 * CIN);
    const int rem = idx - t9 * 256 * CIN;
    const int o = rem / CIN, i = rem - o * CIN;
    Wt[idx] = f2b(wo[((long)o * CIN + i) * 9 + t9]);   // [9][256][CIN]
  }
}

// ---------------------------------------------------------------------------
// Zero the 1-px halo border of a padded NHWC buffer [16][HP][WP][C]
// ---------------------------------------------------------------------------
__global__ __launch_bounds__(256) void zero_border(unsigned short* buf, int HP, int WP, int C) {
  const long i = (long)blockIdx.x * 256 + threadIdx.x;
  const int per_px = C >> 3;
  const int strip = 2 * WP + 2 * (HP - 2);
  const long tot = (long)16 * strip * per_px;
  if (i >= tot) return;
  const int c8 = (int)(i % per_px);
  const long r = i / per_px;
  const int s = (int)(r % strip);
  const int bt = (int)(r / strip);
  int y, x;
  if (s < WP) { y = 0; x = s; }
  else if (s < 2 * WP) { y = HP - 1; x = s - WP; }
  else if (s < 2 * WP + (HP - 2)) { y = s - 2 * WP + 1; x = 0; }
  else { y = s - 2 * WP - (HP - 2) + 1; x = WP - 1; }
  const short8 z = {0, 0, 0, 0, 0, 0, 0, 0};
  *(short8*)(buf + (((long)bt * HP + y) * WP + x) * C + c8 * 8) = z;
}

// ---------------------------------------------------------------------------
// Repack Y0 rows (cfg0 attention output) -> padded NHWC conv inputs.
// ---------------------------------------------------------------------------
__global__ __launch_bounds__(256) void repackY0(const unsigned short* __restrict__ Y0,
                                                unsigned short* __restrict__ CinLo,
                                                unsigned short* __restrict__ CinHi) {
  __shared__ __align__(16) unsigned short T[8704];
  const int r = blockIdx.x;            // 0..2047
  const int b = r >> 9, n = r & 511;
  const int tid = threadIdx.x;
  const int wv2 = tid >> 6, lane = tid & 63;
  const unsigned short* row = Y0 + (long)r * 8192;
  if (n < 256) {                       // lo: C=512, P=16 (4x4 patch)
#pragma unroll
    for (int q = 0; q < 4; ++q) {
      short8 v = *(const short8*)(row + tid * 32 + q * 8);
#pragma unroll
      for (int j = 0; j < 8; ++j) {
        const int f = tid * 32 + q * 8 + j;
        T[(f & 15) * 520 + (f >> 4)] = (unsigned short)v[j];
      }
    }
    __syncthreads();
    const int t = n >> 6, oh = (n >> 3) & 7, ow = n & 7;
    const int bt = b * 4 + t;
#pragma unroll
    for (int it = 0; it < 4; ++it) {
      const int pp = it * 4 + wv2;
      const int py = pp >> 2, px = pp & 3;
      short8 v = *(const short8*)(T + pp * 520 + lane * 8);
      *(short8*)(CinLo + (((long)bt * 34 + oh * 4 + py + 1) * 34 + ow * 4 + px + 1) * 1024
                 + lane * 8) = v;
    }
  } else {                             // hi: C=128, P=64 (8x8 patch)
    const int m = n - 256;
#pragma unroll
    for (int q = 0; q < 4; ++q) {
      short8 v = *(const short8*)(row + tid * 32 + q * 8);
#pragma unroll
      for (int j = 0; j < 8; ++j) {
        const int f = tid * 32 + q * 8 + j;
        T[(f & 63) * 136 + (f >> 6)] = (unsigned short)v[j];
      }
    }
    __syncthreads();
    const int t = m >> 6, oh = (m >> 3) & 7, ow = m & 7;
    const int bt = b * 4 + t;
#pragma unroll
    for (int it = 0; it < 4; ++it) {
      const int pp = it * 16 + wv2 * 4 + (lane >> 4);
      const int py = pp >> 3, px = pp & 7;
      short8 v = *(const short8*)(T + pp * 136 + (lane & 15) * 8);
      *(short8*)(CinHi + (((long)bt * 66 + oh * 8 + py + 1) * 66 + ow * 8 + px + 1) * 256
                 + (lane & 15) * 8) = v;
    }
  }
}

__global__ __launch_bounds__(256) void repackY1(const unsigned short* __restrict__ Y1,
                                                unsigned short* __restrict__ CinLo,
                                                unsigned short* __restrict__ CinHi) {
  __shared__ __align__(16) unsigned short T[2176];
  const int r = blockIdx.x;            // 0..8191
  const int b = r >> 11, n = r & 2047;
  const int tid = threadIdx.x;
  const int wv2 = tid >> 6, lane = tid & 63;
  const unsigned short* row = Y1 + (long)r * 2048;
  short8 v = *(const short8*)(row + tid * 8);
  if (n < 1024) {                      // lo: C=512, P=4 (2x2 patch)
#pragma unroll
    for (int j = 0; j < 8; ++j) {
      const int f = tid * 8 + j;
      T[(f & 3) * 520 + (f >> 2)] = (unsigned short)v[j];
    }
    __syncthreads();
    const int t = n >> 8, oh = (n >> 4) & 15, ow = n & 15;
    const int bt = b * 4 + t;
    const int pp = wv2, py = pp >> 1, px = pp & 1;
    short8 o = *(const short8*)(T + pp * 520 + lane * 8);
    *(short8*)(CinLo + (((long)bt * 34 + oh * 2 + py + 1) * 34 + ow * 2 + px + 1) * 1024
               + 512 + lane * 8) = o;
  } else {                             // hi: C=128, P=16 (4x4 patch)
    const int m = n - 1024;
#pragma unroll
    for (int j = 0; j < 8; ++j) {
      const int f = tid * 8 + j;
      T[(f & 15) * 136 + (f >> 4)] = (unsigned short)v[j];
    }
    __syncthreads();
    const int t = m >> 8, oh = (m >> 4) & 15, ow = m & 15;
    const int bt = b * 4 + t;
    const int pp = wv2 * 4 + (lane >> 4), py = pp >> 2, px = pp & 3;
    short8 o = *(const short8*)(T + pp * 136 + (lane & 15) * 8);
    *(short8*)(CinHi + (((long)bt * 66 + oh * 4 + py + 1) * 66 + ow * 4 + px + 1) * 256
               + 128 + (lane & 15) * 8) = o;
  }
}

// ---------------------------------------------------------------------------
// Sum 4 bf16 conv partial slabs (2 in P0, 2 in P1) + bias + leaky-relu -> out
// ---------------------------------------------------------------------------
__global__ __launch_bounds__(256) void reduce_lrelu(const unsigned short* __restrict__ P0,
                                                    const unsigned short* __restrict__ P1,
                                                    const float* __restrict__ bias,
                                                    float* __restrict__ out) {
  const long i = (long)blockIdx.x * 256 + threadIdx.x;   // 524288 threads, 8 elems each
  const long flat = i * 8;
  constexpr long SL = 4194304;
  short8 a = *(const short8*)(P0 + flat);
  short8 b = *(const short8*)(P0 + SL + flat);
  short8 c = *(const short8*)(P1 + flat);
  short8 d = *(const short8*)(P1 + SL + flat);
  const int co = ((int)(flat >> 10)) & 255;
  const float bv = bias[co];
  floatx4 r0, r1;
#pragma unroll
  for (int j = 0; j < 8; ++j) {
    float v = b2f((unsigned short)a[j]) + b2f((unsigned short)b[j]) +
              b2f((unsigned short)c[j]) + b2f((unsigned short)d[j]) + bv;
    v = v > 0.f ? v : 0.2f * v;
    if (j < 4) r0[j] = v; else r1[j - 4] = v;
  }
  *(floatx4*)(out + flat) = r0;
  *(floatx4*)(out + flat + 4) = r1;
}

// ---------------------------------------------------------------------------
extern "C" void kernel_launch(void* const* d_in, const int* in_sizes, int n_in,
                              void* d_out, int out_size, void* d_ws, size_t ws_size,
                              hipStream_t stream) {
  (void)in_sizes; (void)n_in; (void)out_size; (void)ws_size;
  const float* x_lo = (const float*)d_in[0];
  const float* x_hi = (const float*)d_in[1];
  const float* wq_lo = (const float*)d_in[3];
  const float* bq_lo = (const float*)d_in[4];
  const float* wk_lo = (const float*)d_in[5];
  const float* bk_lo = (const float*)d_in[6];
  const float* wv_lo = (const float*)d_in[7];
  const float* bv_lo = (const float*)d_in[8];
  const float* wq_hi = (const float*)d_in[9];
  const float* bq_hi = (const float*)d_in[10];
  const float* wk_hi = (const float*)d_in[11];
  const float* bk_hi = (const float*)d_in[12];
  const float* wv_hi = (const float*)d_in[13];
  const float* bv_hi = (const float*)d_in[14];
  const float* wo_lo = (const float*)d_in[15];
  const float* bo_lo = (const float*)d_in[16];
  const float* wo_hi = (const float*)d_in[17];
  const float* bo_hi = (const float*)d_in[18];
  float* out = (float*)d_out;

  char* ws = (char*)d_ws;
  const long B0 = 33554432;
  unsigned short* Qp0 = (unsigned short*)(ws);
  unsigned short* Kp0 = (unsigned short*)(ws + B0);
  unsigned short* V0t = (unsigned short*)(ws + 2 * B0);
  unsigned short* Qp1 = (unsigned short*)(ws + 3 * B0);
  unsigned short* Kp1 = (unsigned short*)(ws + 4 * B0);
  unsigned short* V1t = (unsigned short*)(ws + 5 * B0);
  char* ptr = ws + 6 * B0;
  unsigned short* S0 = (unsigned short*)ptr;     ptr += 2097152;
  unsigned short* Xt_lo = (unsigned short*)ptr;  ptr += 8388608;
  unsigned short* Xt_hi = (unsigned short*)ptr;  ptr += 33554432;
  unsigned short* Wcat_lo = (unsigned short*)ptr; ptr += 1572864;
  unsigned short* Wcat_hi = (unsigned short*)ptr; ptr += 393216;
  float* Bcat_lo = (float*)ptr;                  ptr += 12288;
  float* Bcat_hi = (float*)ptr;                  ptr += 3072;
  unsigned short* Wt_lo = (unsigned short*)ptr;  ptr += 4718592;
  unsigned short* Wt_hi = (unsigned short*)ptr;  ptr += 1179648;
  unsigned short* S1 = Kp0;
  unsigned short* Y0 = Qp0;
  unsigned short* Y1 = Qp1;
  unsigned short* CinP_lo = Kp0;
  unsigned short* CinP_hi = Kp1;
  unsigned short* S0p = Xt_hi;          // 64 bf16 slabs x 262144 = 33.5 MB
  unsigned short* PC0 = Qp0;            // conv_lo bf16 partial slabs 0,1
  unsigned short* PC1 = Qp1;            // conv_lo bf16 partial slabs 2,3

  // --- weight/input prep ---
  prep_qkv_w<<<(3 * 1024 * 256 + 255) / 256, 256, 0, stream>>>(
      wq_lo, wk_lo, wv_lo, bq_lo, bk_lo, bv_lo, Wcat_lo, Bcat_lo, 1024);
  prep_qkv_w<<<(3 * 256 * 256 + 255) / 256, 256, 0, stream>>>(
      wq_hi, wk_hi, wv_hi, bq_hi, bk_hi, bv_hi, Wcat_hi, Bcat_hi, 256);
  prep_conv_w<<<(9 * 256 * 1024 + 255) / 256, 256, 0, stream>>>(wo_lo, Wt_lo, 1024);
  prep_conv_w<<<(9 * 256 * 256 + 255) / 256, 256, 0, stream>>>(wo_hi, Wt_hi, 256);
  xt_kernel<<<dim3(16, 4, 16), 256, 0, stream>>>(x_lo, Xt_lo, 1024);
  xt_kernel<<<dim3(64, 4, 16), 256, 0, stream>>>(x_hi, Xt_hi, 4096);

  // --- QKV projections (1x1 conv as TN-GEMM), staged coalesced scatter ---
  {
    GemmP p{};
    p.A = Wcat_lo; p.B = Xt_lo; p.sAb = 0; p.sBb = 1024L * 256;
    p.lda = 256; p.ldb = 256; p.K = 256;
    p.bias = Bcat_lo;
    p.Q0 = Qp0; p.K0 = Kp0; p.V0t = V0t; p.Q1 = Qp1; p.K1 = Kp1; p.V1t = V1t;
    gemm256<2><<<dim3(4, 12, 16), 512, 0, stream>>>(p);
    p.A = Wcat_hi; p.B = Xt_hi; p.sBb = 4096L * 256; p.bias = Bcat_hi;
    gemm256<3><<<dim3(16, 3, 16), 512, 0, stream>>>(p);
  }

  // --- attention cfg0: n=512, d=8192 (split-K 16, bf16 partials) ---
  {
    GemmP s{};
    s.A = Qp0; s.B = Kp0; s.sAb = 512L * 8192; s.sBb = 512L * 8192;
    s.lda = 8192; s.ldb = 8192; s.K = 8192;
    s.C = S0p; s.sCb = 262144; s.ldc = 512;
    gemm256<1><<<dim3(2, 2, 64), 512, 0, stream>>>(s);
    softmax_red16<<<512, 256, 0, stream>>>(S0p, S0);
    GemmP pv{};
    pv.A = S0; pv.B = V0t; pv.sAb = 512L * 512; pv.sBb = 8192L * 512;
    pv.lda = 512; pv.ldb = 512; pv.K = 512;
    pv.C = Y0; pv.sCb = 512L * 8192; pv.ldc = 8192;
    gemm256<0><<<dim3(32, 2, 4), 512, 0, stream>>>(pv);
  }

  // --- attention cfg1: n=2048, d=2048 ---
  {
    GemmP s{};
    s.A = Qp1; s.B = Kp1; s.sAb = 2048L * 2048; s.sBb = 2048L * 2048;
    s.lda = 2048; s.ldb = 2048; s.K = 2048;
    s.C = S1; s.sCb = 2048L * 2048; s.ldc = 2048;
    gemm256<0><<<dim3(8, 8, 4), 512, 0, stream>>>(s);
    softmax_rows<2048><<<2048, 256, 0, stream>>>(S1);
    GemmP pv{};
    pv.A = S1; pv.B = V1t; pv.sAb = 2048L * 2048; pv.sBb = 2048L * 2048;
    pv.lda = 2048; pv.ldb = 2048; pv.K = 2048;
    pv.C = Y1; pv.sCb = 2048L * 2048; pv.ldc = 2048;
    gemm256<0><<<dim3(8, 8, 4), 512, 0, stream>>>(pv);
  }

  // --- halo zeroing + coalesced from_patches repack into padded NHWC ---
  zero_border<<<1056, 256, 0, stream>>>(CinP_lo, 34, 34, 1024);
  zero_border<<<520, 256, 0, stream>>>(CinP_hi, 66, 66, 256);
  repackY0<<<2048, 256, 0, stream>>>(Y0, CinP_lo, CinP_hi);
  repackY1<<<8192, 256, 0, stream>>>(Y1, CinP_lo, CinP_hi);

  // --- 3x3 convs as im2col GEMM on the 256-tile pipeline ---
  conv256<32, 32, 1024, 4, true><<<dim3(4, 1, 64), 512, 0, stream>>>(
      CinP_lo, Wt_lo, bo_lo, out, PC0, PC1);
  reduce_lrelu<<<2048, 256, 0, stream>>>(PC0, PC1, bo_lo, out);
  conv256<64, 64, 256, 1, false><<<dim3(16, 1, 16), 512, 0, stream>>>(
      CinP_hi, Wt_hi, bo_hi, out + 4194304, nullptr, nullptr);
}